// Round 1
// baseline (359.139 us; speedup 1.0000x reference)
//
#include <hip/hip_runtime.h>

typedef __attribute__((ext_vector_type(4))) float f32x4;
typedef __attribute__((ext_vector_type(8))) short s16x8;

struct alignas(8) us4 { ushort x, y, z, w; };

__device__ __forceinline__ ushort f2bf(float f) {
  unsigned u = __builtin_bit_cast(unsigned, f);
  u += 0x7fffu + ((u >> 16) & 1u);
  return (ushort)(u >> 16);
}
__device__ __forceinline__ float bf2f(ushort h) {
  unsigned u = ((unsigned)h) << 16;
  return __builtin_bit_cast(float, u);
}

// ---------------- cast fp32 -> bf16 (vectorized) ----------------
__global__ __launch_bounds__(256) void cast_bf16_kernel(const float* __restrict__ in,
                                                        ushort* __restrict__ out, int n4) {
  int i = blockIdx.x * 256 + threadIdx.x;
  int stride = gridDim.x * 256;
  for (; i < n4; i += stride) {
    float4 v = reinterpret_cast<const float4*>(in)[i];
    us4 o;
    o.x = f2bf(v.x); o.y = f2bf(v.y); o.z = f2bf(v.z); o.w = f2bf(v.w);
    reinterpret_cast<us4*>(out)[i] = o;
  }
}

// ---------------- cast + transpose: in [R][C] f32 -> out [C][R] bf16 ----------------
__global__ __launch_bounds__(256) void cast_transpose_kernel(const float* __restrict__ in,
                                                             ushort* __restrict__ out,
                                                             int R, int C) {
  __shared__ float tile[32][33];
  int tx = threadIdx.x & 31, ty = threadIdx.x >> 5;
  int c0 = blockIdx.x * 32, r0 = blockIdx.y * 32;
#pragma unroll
  for (int i = 0; i < 4; ++i)
    tile[ty + i * 8][tx] = in[(size_t)(r0 + ty + i * 8) * C + c0 + tx];
  __syncthreads();
#pragma unroll
  for (int i = 0; i < 4; ++i)
    out[(size_t)(c0 + ty + i * 8) * R + r0 + tx] = f2bf(tile[tx][ty + i * 8]);
}

// ---------------- RoPE tables: cos/sin[t][j], j<64 ----------------
__global__ void rope_table_kernel(float* __restrict__ rc, float* __restrict__ rs) {
  int t = blockIdx.x, j = threadIdx.x;  // 64 threads
  // inv_freq = 10000^(-j/64) = exp(-j * ln(10000)/64)
  float inv = expf(-(float)j * (9.210340371976184f / 64.0f));
  float ang = (float)t * inv;
  float s, c;
  sincosf(ang, &s, &c);
  rc[t * 64 + j] = c;
  rs[t * 64 + j] = s;
}

// ---------------- fused per-head RMSNorm + RoPE ----------------
// one wave per (token, head) row of 128; lane l holds dims l and l+64
__global__ __launch_bounds__(256) void norm_rope_kernel(
    const ushort* __restrict__ qkv, const float* __restrict__ w,
    ushort* __restrict__ out, const float* __restrict__ rc, const float* __restrict__ rs,
    int nheads, int col_off, int out_stride) {
  int wv = threadIdx.x >> 6, lane = threadIdx.x & 63;
  int row = blockIdx.x * 4 + wv;
  int token = row / nheads, head = row % nheads;
  int t = token & 2047;  // token % S
  const ushort* p = qkv + (size_t)token * 3072 + col_off + head * 128;
  float x1 = bf2f(p[lane]), x2 = bf2f(p[lane + 64]);
  float ss = x1 * x1 + x2 * x2;
#pragma unroll
  for (int m = 32; m > 0; m >>= 1) ss += __shfl_xor(ss, m);
  float r = rsqrtf(ss * (1.0f / 128.0f) + 1e-6f);
  float xn1 = x1 * r * w[lane], xn2 = x2 * r * w[lane + 64];
  float c = rc[t * 64 + lane], s = rs[t * 64 + lane];
  ushort* o = out + (size_t)token * out_stride + head * 128;
  o[lane] = f2bf(xn1 * c - xn2 * s);
  o[lane + 64] = f2bf(xn2 * c + xn1 * s);
}

// ---------------- V transpose: QKV slab -> Vt[b][kv][d][s] ----------------
__global__ __launch_bounds__(256) void v_transpose_kernel(const ushort* __restrict__ qkv,
                                                          ushort* __restrict__ vt) {
  __shared__ ushort tile[64][136];
  int bx = blockIdx.x;
  int st = bx & 31, kvh = (bx >> 5) & 3, b = bx >> 7;
  int s0 = st * 64;
  int tid = threadIdx.x;
#pragma unroll
  for (int p = 0; p < 4; ++p) {
    int idx = p * 2048 + tid * 8;
    int s = idx >> 7, d = idx & 127;
    *(s16x8*)&tile[s][d] =
        *(const s16x8*)&qkv[(size_t)(b * 2048 + s0 + s) * 3072 + 2560 + kvh * 128 + d];
  }
  __syncthreads();
#pragma unroll
  for (int p = 0; p < 4; ++p) {
    int idx = p * 2048 + tid * 8;
    int d = idx >> 6, s = idx & 63;
    s16x8 v;
#pragma unroll
    for (int u = 0; u < 8; ++u) v[u] = (short)tile[s + u][d];
    *(s16x8*)&vt[(size_t)((b * 4 + kvh) * 128 + d) * 2048 + s0 + s] = v;
  }
}

// ---------------- bf16 MFMA GEMM: C[M][N] = A[M][K] * Bt[N][K]^T ----------------
template <bool OUTF32>
__global__ __launch_bounds__(256) void gemm_bt_kernel(const ushort* __restrict__ A,
                                                      const ushort* __restrict__ Bt,
                                                      void* __restrict__ Cp,
                                                      int M, int N, int K) {
  __shared__ ushort As[128][72];
  __shared__ ushort Bs[128][72];
  int tid = threadIdx.x;
  int lane = tid & 63, wv = tid >> 6;
  int wm = wv >> 1, wn = wv & 1;
  int lr = lane & 15, lg = lane >> 4;
  int m0 = blockIdx.y * 128, n0 = blockIdx.x * 128;
  f32x4 acc[4][4] = {};
  for (int k0 = 0; k0 < K; k0 += 64) {
    __syncthreads();
#pragma unroll
    for (int p = 0; p < 4; ++p) {
      int idx = p * 2048 + tid * 8;
      int row = idx >> 6, col = idx & 63;
      *(s16x8*)&As[row][col] = *(const s16x8*)&A[(size_t)(m0 + row) * K + k0 + col];
      *(s16x8*)&Bs[row][col] = *(const s16x8*)&Bt[(size_t)(n0 + row) * K + k0 + col];
    }
    __syncthreads();
#pragma unroll
    for (int ks = 0; ks < 2; ++ks) {
      s16x8 a[4], b[4];
#pragma unroll
      for (int i = 0; i < 4; ++i) a[i] = *(const s16x8*)&As[wm * 64 + i * 16 + lr][ks * 32 + lg * 8];
#pragma unroll
      for (int j = 0; j < 4; ++j) b[j] = *(const s16x8*)&Bs[wn * 64 + j * 16 + lr][ks * 32 + lg * 8];
#pragma unroll
      for (int i = 0; i < 4; ++i)
#pragma unroll
        for (int j = 0; j < 4; ++j)
          acc[i][j] = __builtin_amdgcn_mfma_f32_16x16x32_bf16(a[i], b[j], acc[i][j], 0, 0, 0);
    }
  }
#pragma unroll
  for (int i = 0; i < 4; ++i)
#pragma unroll
    for (int j = 0; j < 4; ++j) {
      int row = m0 + wm * 64 + i * 16 + lg * 4;
      int col = n0 + wn * 64 + j * 16 + lr;
#pragma unroll
      for (int r = 0; r < 4; ++r) {
        float v = acc[i][j][r];
        if (OUTF32)
          reinterpret_cast<float*>(Cp)[(size_t)(row + r) * N + col] = v;
        else
          reinterpret_cast<ushort*>(Cp)[(size_t)(row + r) * N + col] = f2bf(v);
      }
    }
}

// ---------------- causal GQA flash attention ----------------
// block: 64 q-rows, 4 waves x 16 q-rows; iterate 64-wide K/V tiles
__global__ __launch_bounds__(256) void attn_kernel(const ushort* __restrict__ Q,
                                                   const ushort* __restrict__ Kn,
                                                   const ushort* __restrict__ Vt,
                                                   ushort* __restrict__ AO) {
  __shared__ ushort Qs[64][136];
  __shared__ ushort Ks[64][136];
  __shared__ ushort Vs[128][72];
  __shared__ ushort Ps[4][16][72];
  int bx = blockIdx.x;
  int qt = bx & 31, h = (bx >> 5) & 15, b = bx >> 9;
  int kvh = h >> 2;
  int q0 = qt * 64;
  int tid = threadIdx.x, lane = tid & 63, w = tid >> 6;
  int lr = lane & 15, lg = lane >> 4;

#pragma unroll
  for (int p = 0; p < 4; ++p) {
    int idx = p * 2048 + tid * 8;
    int row = idx >> 7, d = idx & 127;
    *(s16x8*)&Qs[row][d] =
        *(const s16x8*)&Q[(size_t)(b * 2048 + q0 + row) * 2048 + h * 128 + d];
  }
  f32x4 O[8] = {};
  float mrow[4] = {-1e30f, -1e30f, -1e30f, -1e30f};
  float lrow[4] = {0.f, 0.f, 0.f, 0.f};

  for (int pt = 0; pt <= qt; ++pt) {
    int p0 = pt * 64;
    __syncthreads();
#pragma unroll
    for (int p = 0; p < 4; ++p) {
      int idx = p * 2048 + tid * 8;
      int row = idx >> 7, d = idx & 127;
      *(s16x8*)&Ks[row][d] =
          *(const s16x8*)&Kn[(size_t)(b * 2048 + p0 + row) * 512 + kvh * 128 + d];
      int vr = idx >> 6, vp = idx & 63;
      *(s16x8*)&Vs[vr][vp] =
          *(const s16x8*)&Vt[(size_t)((b * 4 + kvh) * 128 + vr) * 2048 + p0 + vp];
    }
    __syncthreads();

    f32x4 sacc[4] = {};
#pragma unroll
    for (int ks = 0; ks < 4; ++ks) {
      s16x8 aq = *(const s16x8*)&Qs[w * 16 + lr][ks * 32 + lg * 8];
#pragma unroll
      for (int fp = 0; fp < 4; ++fp) {
        s16x8 bk = *(const s16x8*)&Ks[fp * 16 + lr][ks * 32 + lg * 8];
        sacc[fp] = __builtin_amdgcn_mfma_f32_16x16x32_bf16(aq, bk, sacc[fp], 0, 0, 0);
      }
    }
    const float scale = 0.08838834764831845f;  // 1/sqrt(128)
    float pm[4] = {-1e30f, -1e30f, -1e30f, -1e30f};
#pragma unroll
    for (int fp = 0; fp < 4; ++fp)
#pragma unroll
      for (int r = 0; r < 4; ++r) {
        float s = sacc[fp][r] * scale;
        if (pt == qt) {
          int qg = q0 + w * 16 + lg * 4 + r;
          int pg = p0 + fp * 16 + lr;
          if (pg > qg) s = -1e30f;
        }
        sacc[fp][r] = s;
        pm[r] = fmaxf(pm[r], s);
      }
#pragma unroll
    for (int r = 0; r < 4; ++r) {
      pm[r] = fmaxf(pm[r], __shfl_xor(pm[r], 1));
      pm[r] = fmaxf(pm[r], __shfl_xor(pm[r], 2));
      pm[r] = fmaxf(pm[r], __shfl_xor(pm[r], 4));
      pm[r] = fmaxf(pm[r], __shfl_xor(pm[r], 8));
    }
    float fsc[4], ls[4] = {0.f, 0.f, 0.f, 0.f};
#pragma unroll
    for (int r = 0; r < 4; ++r) {
      float mn = fmaxf(mrow[r], pm[r]);
      fsc[r] = __expf(mrow[r] - mn);
      mrow[r] = mn;
    }
#pragma unroll
    for (int fp = 0; fp < 4; ++fp)
#pragma unroll
      for (int r = 0; r < 4; ++r) {
        float pv = __expf(sacc[fp][r] - mrow[r]);
        ls[r] += pv;
        Ps[w][lg * 4 + r][fp * 16 + lr] = f2bf(pv);
      }
#pragma unroll
    for (int r = 0; r < 4; ++r) {
      ls[r] += __shfl_xor(ls[r], 1);
      ls[r] += __shfl_xor(ls[r], 2);
      ls[r] += __shfl_xor(ls[r], 4);
      ls[r] += __shfl_xor(ls[r], 8);
      lrow[r] = lrow[r] * fsc[r] + ls[r];
    }
#pragma unroll
    for (int fn = 0; fn < 8; ++fn)
#pragma unroll
      for (int r = 0; r < 4; ++r) O[fn][r] *= fsc[r];
#pragma unroll
    for (int ks2 = 0; ks2 < 2; ++ks2) {
      s16x8 ap = *(const s16x8*)&Ps[w][lr][ks2 * 32 + lg * 8];
#pragma unroll
      for (int fn = 0; fn < 8; ++fn) {
        s16x8 bv = *(const s16x8*)&Vs[fn * 16 + lr][ks2 * 32 + lg * 8];
        O[fn] = __builtin_amdgcn_mfma_f32_16x16x32_bf16(ap, bv, O[fn], 0, 0, 0);
      }
    }
  }
  float invl[4];
#pragma unroll
  for (int r = 0; r < 4; ++r) invl[r] = 1.0f / lrow[r];
#pragma unroll
  for (int fn = 0; fn < 8; ++fn)
#pragma unroll
    for (int r = 0; r < 4; ++r) {
      size_t idx = (size_t)(b * 2048 + q0 + w * 16 + lg * 4 + r) * 2048 + h * 128 + fn * 16 + lr;
      AO[idx] = f2bf(O[fn][r] * invl[r]);
    }
}

extern "C" void kernel_launch(void* const* d_in, const int* in_sizes, int n_in,
                              void* d_out, int out_size, void* d_ws, size_t ws_size,
                              hipStream_t stream) {
  (void)in_sizes; (void)n_in; (void)out_size; (void)ws_size;
  const float* x = (const float*)d_in[0];
  const float* Wq = (const float*)d_in[1];
  const float* Wk = (const float*)d_in[2];
  const float* Wv = (const float*)d_in[3];
  const float* Wo = (const float*)d_in[4];
  const float* qw = (const float*)d_in[5];
  const float* kw = (const float*)d_in[6];
  float* out = (float*)d_out;

  char* ws = (char*)d_ws;
  size_t off = 0;
  auto alloc = [&](size_t bytes) {
    void* p = ws + off;
    off += (bytes + 255) & ~(size_t)255;
    return p;
  };
  ushort* xb = (ushort*)alloc((size_t)4096 * 2048 * 2);
  ushort* WqkvT = (ushort*)alloc((size_t)3072 * 2048 * 2);
  ushort* WoT = (ushort*)alloc((size_t)2048 * 2048 * 2);
  ushort* QKVraw = (ushort*)alloc((size_t)4096 * 3072 * 2);
  ushort* Qn = (ushort*)alloc((size_t)4096 * 2048 * 2);
  ushort* Kb = (ushort*)alloc((size_t)4096 * 512 * 2);
  ushort* Vt = (ushort*)alloc((size_t)4096 * 512 * 2);
  ushort* AO = (ushort*)alloc((size_t)4096 * 2048 * 2);
  float* rc = (float*)alloc((size_t)2048 * 64 * 4);
  float* rs = (float*)alloc((size_t)2048 * 64 * 4);

  cast_bf16_kernel<<<2048, 256, 0, stream>>>(x, xb, 4096 * 2048 / 4);
  cast_transpose_kernel<<<dim3(64, 64), 256, 0, stream>>>(Wq, WqkvT, 2048, 2048);
  cast_transpose_kernel<<<dim3(16, 64), 256, 0, stream>>>(Wk, WqkvT + (size_t)2048 * 2048, 2048, 512);
  cast_transpose_kernel<<<dim3(16, 64), 256, 0, stream>>>(Wv, WqkvT + (size_t)2560 * 2048, 2048, 512);
  cast_transpose_kernel<<<dim3(64, 64), 256, 0, stream>>>(Wo, WoT, 2048, 2048);
  rope_table_kernel<<<2048, 64, 0, stream>>>(rc, rs);
  gemm_bt_kernel<false><<<dim3(24, 32), 256, 0, stream>>>(xb, WqkvT, QKVraw, 4096, 3072, 2048);
  norm_rope_kernel<<<16384, 256, 0, stream>>>(QKVraw, qw, Qn, rc, rs, 16, 0, 2048);
  norm_rope_kernel<<<4096, 256, 0, stream>>>(QKVraw, kw, Kb, rc, rs, 4, 2048, 512);
  v_transpose_kernel<<<256, 256, 0, stream>>>(QKVraw, Vt);
  attn_kernel<<<1024, 256, 0, stream>>>(Qn, Kb, Vt, AO);
  gemm_bt_kernel<true><<<dim3(16, 32), 256, 0, stream>>>(AO, WoT, out, 4096, 2048, 2048);
}

// Round 2
// 344.347 us; speedup vs baseline: 1.0430x; 1.0430x over previous
//
#include <hip/hip_runtime.h>

typedef __attribute__((ext_vector_type(4))) float f32x4;
typedef __attribute__((ext_vector_type(8))) short s16x8;

struct alignas(8) us4 { ushort x, y, z, w; };

__device__ __forceinline__ ushort f2bf(float f) {
  unsigned u = __builtin_bit_cast(unsigned, f);
  u += 0x7fffu + ((u >> 16) & 1u);
  return (ushort)(u >> 16);
}
__device__ __forceinline__ float bf2f(ushort h) {
  unsigned u = ((unsigned)h) << 16;
  return __builtin_bit_cast(float, u);
}

__device__ __forceinline__ void gload_lds16(const ushort* g, ushort* l) {
  __builtin_amdgcn_global_load_lds((const __attribute__((address_space(1))) unsigned int*)g,
                                   (__attribute__((address_space(3))) unsigned int*)l, 16, 0, 0);
}

// ---------------- cast fp32 -> bf16 (vectorized) ----------------
__global__ __launch_bounds__(256) void cast_bf16_kernel(const float* __restrict__ in,
                                                        ushort* __restrict__ out, int n4) {
  int i = blockIdx.x * 256 + threadIdx.x;
  int stride = gridDim.x * 256;
  for (; i < n4; i += stride) {
    float4 v = reinterpret_cast<const float4*>(in)[i];
    us4 o;
    o.x = f2bf(v.x); o.y = f2bf(v.y); o.z = f2bf(v.z); o.w = f2bf(v.w);
    reinterpret_cast<us4*>(out)[i] = o;
  }
}

// ---------------- cast + transpose: in [R][C] f32 -> out [C][R] bf16 ----------------
__global__ __launch_bounds__(256) void cast_transpose_kernel(const float* __restrict__ in,
                                                             ushort* __restrict__ out,
                                                             int R, int C) {
  __shared__ float tile[32][33];
  int tx = threadIdx.x & 31, ty = threadIdx.x >> 5;
  int c0 = blockIdx.x * 32, r0 = blockIdx.y * 32;
#pragma unroll
  for (int i = 0; i < 4; ++i)
    tile[ty + i * 8][tx] = in[(size_t)(r0 + ty + i * 8) * C + c0 + tx];
  __syncthreads();
#pragma unroll
  for (int i = 0; i < 4; ++i)
    out[(size_t)(c0 + ty + i * 8) * R + r0 + tx] = f2bf(tile[tx][ty + i * 8]);
}

// ---------------- RoPE tables: cos/sin[t][j], j<64 ----------------
__global__ void rope_table_kernel(float* __restrict__ rc, float* __restrict__ rs) {
  int t = blockIdx.x, j = threadIdx.x;  // 64 threads
  float inv = expf(-(float)j * (9.210340371976184f / 64.0f));
  float ang = (float)t * inv;
  float s, c;
  sincosf(ang, &s, &c);
  rc[t * 64 + j] = c;
  rs[t * 64 + j] = s;
}

// ---------------- fused per-head RMSNorm + RoPE (+ optional output scale) -------
// one wave per (token, head) row of 128; lane l holds dims l and l+64
__global__ __launch_bounds__(256) void norm_rope_kernel(
    const ushort* __restrict__ qkv, const float* __restrict__ w,
    ushort* __restrict__ out, const float* __restrict__ rc, const float* __restrict__ rs,
    int nheads, int col_off, int out_stride, float oscale) {
  int wv = threadIdx.x >> 6, lane = threadIdx.x & 63;
  int row = blockIdx.x * 4 + wv;
  int token = row / nheads, head = row % nheads;
  int t = token & 2047;  // token % S
  const ushort* p = qkv + (size_t)token * 3072 + col_off + head * 128;
  float x1 = bf2f(p[lane]), x2 = bf2f(p[lane + 64]);
  float ss = x1 * x1 + x2 * x2;
#pragma unroll
  for (int m = 32; m > 0; m >>= 1) ss += __shfl_xor(ss, m);
  float r = rsqrtf(ss * (1.0f / 128.0f) + 1e-6f);
  float xn1 = x1 * r * w[lane], xn2 = x2 * r * w[lane + 64];
  float c = rc[t * 64 + lane], s = rs[t * 64 + lane];
  ushort* o = out + (size_t)token * out_stride + head * 128;
  o[lane] = f2bf((xn1 * c - xn2 * s) * oscale);
  o[lane + 64] = f2bf((xn2 * c + xn1 * s) * oscale);
}

// ---------------- V transpose: QKV slab -> Vt[b][kv][d][s] ----------------
__global__ __launch_bounds__(256) void v_transpose_kernel(const ushort* __restrict__ qkv,
                                                          ushort* __restrict__ vt) {
  __shared__ ushort tile[64][136];
  int bx = blockIdx.x;
  int st = bx & 31, kvh = (bx >> 5) & 3, b = bx >> 7;
  int s0 = st * 64;
  int tid = threadIdx.x;
#pragma unroll
  for (int p = 0; p < 4; ++p) {
    int idx = p * 2048 + tid * 8;
    int s = idx >> 7, d = idx & 127;
    *(s16x8*)&tile[s][d] =
        *(const s16x8*)&qkv[(size_t)(b * 2048 + s0 + s) * 3072 + 2560 + kvh * 128 + d];
  }
  __syncthreads();
#pragma unroll
  for (int p = 0; p < 4; ++p) {
    int idx = p * 2048 + tid * 8;
    int d = idx >> 6, s = idx & 63;
    s16x8 v;
#pragma unroll
    for (int u = 0; u < 8; ++u) v[u] = (short)tile[s + u][d];
    *(s16x8*)&vt[(size_t)((b * 4 + kvh) * 128 + d) * 2048 + s0 + s] = v;
  }
}

// ---------------- bf16 MFMA GEMM: C[M][N] = A[M][K] * Bt[N][K]^T ----------------
// m97 structure: global_load_lds w16, linear LDS dest, pre-swizzled source,
// XOR-swizzled ds_read (rule 21: source perm == read perm, both XOR involution)
template <bool OUTF32>
__global__ __launch_bounds__(256) void gemm_bt_kernel(const ushort* __restrict__ A,
                                                      const ushort* __restrict__ Bt,
                                                      void* __restrict__ Cp,
                                                      int M, int N, int K) {
  __shared__ ushort As[128][64];
  __shared__ ushort Bs[128][64];
  int tid = threadIdx.x;
  int lane = tid & 63, wv = tid >> 6;
  int wm = wv >> 1, wn = wv & 1;
  int lr = lane & 15, lg = lane >> 4;
  int m0 = blockIdx.y * 128, n0 = blockIdx.x * 128;
  int srow8 = lane >> 3;                  // 0..7 row within 8-row chunk
  int scol = (lane & 7) * 8;              // base ushort col of this lane's 16B
  int gcol = scol ^ (srow8 << 3);         // inverse-swizzled source col
  f32x4 acc[4][4] = {};
  for (int k0 = 0; k0 < K; k0 += 64) {
    __syncthreads();
#pragma unroll
    for (int p = 0; p < 4; ++p) {
      int r0 = wv * 32 + p * 8;           // wave stages rows [wv*32, wv*32+32)
      int grow = r0 + srow8;
      gload_lds16(&A[(size_t)(m0 + grow) * K + k0 + gcol], &As[r0][0]);
      gload_lds16(&Bt[(size_t)(n0 + grow) * K + k0 + gcol], &Bs[r0][0]);
    }
    __syncthreads();
#pragma unroll
    for (int ks = 0; ks < 2; ++ks) {
      s16x8 a[4], b[4];
#pragma unroll
      for (int i = 0; i < 4; ++i) {
        int row = wm * 64 + i * 16 + lr;
        a[i] = *(const s16x8*)&As[row][(ks * 32 + lg * 8) ^ ((row & 7) << 3)];
      }
#pragma unroll
      for (int j = 0; j < 4; ++j) {
        int row = wn * 64 + j * 16 + lr;
        b[j] = *(const s16x8*)&Bs[row][(ks * 32 + lg * 8) ^ ((row & 7) << 3)];
      }
#pragma unroll
      for (int i = 0; i < 4; ++i)
#pragma unroll
        for (int j = 0; j < 4; ++j)
          acc[i][j] = __builtin_amdgcn_mfma_f32_16x16x32_bf16(a[i], b[j], acc[i][j], 0, 0, 0);
    }
  }
#pragma unroll
  for (int i = 0; i < 4; ++i)
#pragma unroll
    for (int j = 0; j < 4; ++j) {
      int row = m0 + wm * 64 + i * 16 + lg * 4;
      int col = n0 + wn * 64 + j * 16 + lr;
#pragma unroll
      for (int r = 0; r < 4; ++r) {
        float v = acc[i][j][r];
        if (OUTF32)
          reinterpret_cast<float*>(Cp)[(size_t)(row + r) * N + col] = v;
        else
          reinterpret_cast<ushort*>(Cp)[(size_t)(row + r) * N + col] = f2bf(v);
      }
    }
}

// ---------------- causal GQA flash attention ----------------
// block: 64 q-rows, 4 waves x 16 q-rows; 64-wide K/V tiles
// Q in registers (pre-scaled by log2e/sqrt(dk)); K/V/P in XOR-swizzled LDS;
// base-2 online softmax with defer-max (THR=8)
__global__ __launch_bounds__(256, 4) void attn_kernel(const ushort* __restrict__ Q,
                                                      const ushort* __restrict__ Kn,
                                                      const ushort* __restrict__ Vt,
                                                      ushort* __restrict__ AO) {
  __shared__ ushort Ks[64][128];
  __shared__ ushort Vs[128][64];
  __shared__ ushort Ps[4][16][64];
  int bx = blockIdx.x;
  int qt = 31 - (bx & 31);  // big causal tiles launch first
  int h = (bx >> 5) & 15, b = bx >> 9;
  int kvh = h >> 2;
  int q0 = qt * 64;
  int tid = threadIdx.x, lane = tid & 63, w = tid >> 6;
  int lr = lane & 15, lg = lane >> 4;

  // Q fragments held in registers for the whole block
  s16x8 qf[4];
  {
    const ushort* qp = &Q[(size_t)(b * 2048 + q0 + w * 16 + lr) * 2048 + h * 128];
#pragma unroll
    for (int ks = 0; ks < 4; ++ks) qf[ks] = *(const s16x8*)&qp[ks * 32 + lg * 8];
  }
  f32x4 O[8] = {};
  float mrow[4] = {-1e30f, -1e30f, -1e30f, -1e30f};
  float lrow[4] = {0.f, 0.f, 0.f, 0.f};

  for (int pt = 0; pt <= qt; ++pt) {
    int p0 = pt * 64;
    __syncthreads();
#pragma unroll
    for (int p = 0; p < 4; ++p) {
      int idx = p * 2048 + tid * 8;
      int row = idx >> 7, d = idx & 127;
      *(s16x8*)&Ks[row][d ^ ((row & 7) << 3)] =
          *(const s16x8*)&Kn[(size_t)(b * 2048 + p0 + row) * 512 + kvh * 128 + d];
      int vr = idx >> 6, vp = idx & 63;
      *(s16x8*)&Vs[vr][vp ^ ((vr & 7) << 3)] =
          *(const s16x8*)&Vt[(size_t)((b * 4 + kvh) * 128 + vr) * 2048 + p0 + vp];
    }
    __syncthreads();

    f32x4 sacc[4] = {};
    __builtin_amdgcn_s_setprio(1);
#pragma unroll
    for (int ks = 0; ks < 4; ++ks) {
#pragma unroll
      for (int fp = 0; fp < 4; ++fp) {
        int kr = fp * 16 + lr;
        s16x8 bk = *(const s16x8*)&Ks[kr][(ks * 32 + lg * 8) ^ ((kr & 7) << 3)];
        sacc[fp] = __builtin_amdgcn_mfma_f32_16x16x32_bf16(qf[ks], bk, sacc[fp], 0, 0, 0);
      }
    }
    __builtin_amdgcn_s_setprio(0);
    // scores already in log2 domain (Q pre-scaled by log2e/sqrt(dk))
    float pm[4] = {-1e30f, -1e30f, -1e30f, -1e30f};
#pragma unroll
    for (int fp = 0; fp < 4; ++fp)
#pragma unroll
      for (int r = 0; r < 4; ++r) {
        float s = sacc[fp][r];
        if (pt == qt) {
          int qg = q0 + w * 16 + lg * 4 + r;
          int pg = p0 + fp * 16 + lr;
          if (pg > qg) s = -1e30f;
        }
        sacc[fp][r] = s;
        pm[r] = fmaxf(pm[r], s);
      }
#pragma unroll
    for (int r = 0; r < 4; ++r) {
      pm[r] = fmaxf(pm[r], __shfl_xor(pm[r], 1));
      pm[r] = fmaxf(pm[r], __shfl_xor(pm[r], 2));
      pm[r] = fmaxf(pm[r], __shfl_xor(pm[r], 4));
      pm[r] = fmaxf(pm[r], __shfl_xor(pm[r], 8));
    }
    // defer-max: only rescale when some row max grew by > 8 (log2 domain)
    bool need = false;
#pragma unroll
    for (int r = 0; r < 4; ++r) need |= (pm[r] > mrow[r] + 8.0f);
    if (__any((int)need)) {
      float fsc[4];
#pragma unroll
      for (int r = 0; r < 4; ++r) {
        float mn = fmaxf(mrow[r], pm[r]);
        fsc[r] = __builtin_amdgcn_exp2f(mrow[r] - mn);
        mrow[r] = mn;
        lrow[r] *= fsc[r];
      }
#pragma unroll
      for (int fn = 0; fn < 8; ++fn)
#pragma unroll
        for (int r = 0; r < 4; ++r) O[fn][r] *= fsc[r];
    }
    float ls[4] = {0.f, 0.f, 0.f, 0.f};
#pragma unroll
    for (int fp = 0; fp < 4; ++fp)
#pragma unroll
      for (int r = 0; r < 4; ++r) {
        float pv = __builtin_amdgcn_exp2f(sacc[fp][r] - mrow[r]);
        ls[r] += pv;
        int prow = lg * 4 + r;
        Ps[w][prow][(fp * 16 + lr) ^ ((prow & 7) << 3)] = f2bf(pv);
      }
#pragma unroll
    for (int r = 0; r < 4; ++r) {
      ls[r] += __shfl_xor(ls[r], 1);
      ls[r] += __shfl_xor(ls[r], 2);
      ls[r] += __shfl_xor(ls[r], 4);
      ls[r] += __shfl_xor(ls[r], 8);
      lrow[r] += ls[r];
    }
    __builtin_amdgcn_s_setprio(1);
#pragma unroll
    for (int ks2 = 0; ks2 < 2; ++ks2) {
      s16x8 ap = *(const s16x8*)&Ps[w][lr][(ks2 * 32 + lg * 8) ^ ((lr & 7) << 3)];
#pragma unroll
      for (int fn = 0; fn < 8; ++fn) {
        int vrow = fn * 16 + lr;
        s16x8 bv = *(const s16x8*)&Vs[vrow][(ks2 * 32 + lg * 8) ^ ((vrow & 7) << 3)];
        O[fn] = __builtin_amdgcn_mfma_f32_16x16x32_bf16(ap, bv, O[fn], 0, 0, 0);
      }
    }
    __builtin_amdgcn_s_setprio(0);
  }
  float invl[4];
#pragma unroll
  for (int r = 0; r < 4; ++r) invl[r] = 1.0f / lrow[r];
#pragma unroll
  for (int fn = 0; fn < 8; ++fn)
#pragma unroll
    for (int r = 0; r < 4; ++r) {
      size_t idx = (size_t)(b * 2048 + q0 + w * 16 + lg * 4 + r) * 2048 + h * 128 + fn * 16 + lr;
      AO[idx] = f2bf(O[fn][r] * invl[r]);
    }
}

extern "C" void kernel_launch(void* const* d_in, const int* in_sizes, int n_in,
                              void* d_out, int out_size, void* d_ws, size_t ws_size,
                              hipStream_t stream) {
  (void)in_sizes; (void)n_in; (void)out_size; (void)ws_size;
  const float* x = (const float*)d_in[0];
  const float* Wq = (const float*)d_in[1];
  const float* Wk = (const float*)d_in[2];
  const float* Wv = (const float*)d_in[3];
  const float* Wo = (const float*)d_in[4];
  const float* qw = (const float*)d_in[5];
  const float* kw = (const float*)d_in[6];
  float* out = (float*)d_out;

  char* ws = (char*)d_ws;
  size_t off = 0;
  auto alloc = [&](size_t bytes) {
    void* p = ws + off;
    off += (bytes + 255) & ~(size_t)255;
    return p;
  };
  ushort* xb = (ushort*)alloc((size_t)4096 * 2048 * 2);
  ushort* WqkvT = (ushort*)alloc((size_t)3072 * 2048 * 2);
  ushort* WoT = (ushort*)alloc((size_t)2048 * 2048 * 2);
  ushort* QKVraw = (ushort*)alloc((size_t)4096 * 3072 * 2);
  ushort* Qn = (ushort*)alloc((size_t)4096 * 2048 * 2);
  ushort* Kb = (ushort*)alloc((size_t)4096 * 512 * 2);
  ushort* Vt = (ushort*)alloc((size_t)4096 * 512 * 2);
  ushort* AO = (ushort*)alloc((size_t)4096 * 2048 * 2);
  float* rc = (float*)alloc((size_t)2048 * 64 * 4);
  float* rs = (float*)alloc((size_t)2048 * 64 * 4);

  // log2(e) / sqrt(128): fold softmax scale + base-2 conversion into Q
  const float QSCALE = 0.12751744f;

  cast_bf16_kernel<<<2048, 256, 0, stream>>>(x, xb, 4096 * 2048 / 4);
  cast_transpose_kernel<<<dim3(64, 64), 256, 0, stream>>>(Wq, WqkvT, 2048, 2048);
  cast_transpose_kernel<<<dim3(16, 64), 256, 0, stream>>>(Wk, WqkvT + (size_t)2048 * 2048, 2048, 512);
  cast_transpose_kernel<<<dim3(16, 64), 256, 0, stream>>>(Wv, WqkvT + (size_t)2560 * 2048, 2048, 512);
  cast_transpose_kernel<<<dim3(64, 64), 256, 0, stream>>>(Wo, WoT, 2048, 2048);
  rope_table_kernel<<<2048, 64, 0, stream>>>(rc, rs);
  gemm_bt_kernel<false><<<dim3(24, 32), 256, 0, stream>>>(xb, WqkvT, QKVraw, 4096, 3072, 2048);
  norm_rope_kernel<<<16384, 256, 0, stream>>>(QKVraw, qw, Qn, rc, rs, 16, 0, 2048, QSCALE);
  norm_rope_kernel<<<4096, 256, 0, stream>>>(QKVraw, kw, Kb, rc, rs, 4, 2048, 512, 1.0f);
  v_transpose_kernel<<<256, 256, 0, stream>>>(QKVraw, Vt);
  attn_kernel<<<1024, 256, 0, stream>>>(Qn, Kb, Vt, AO);
  gemm_bt_kernel<true><<<dim3(16, 32), 256, 0, stream>>>(AO, WoT, out, 4096, 2048, 2048);
}

// Round 3
// 256.713 us; speedup vs baseline: 1.3990x; 1.3414x over previous
//
#include <hip/hip_runtime.h>

typedef __attribute__((ext_vector_type(4))) float f32x4;
typedef __attribute__((ext_vector_type(8))) short s16x8;

struct alignas(8) us4 { ushort x, y, z, w; };

__device__ __forceinline__ ushort f2bf(float f) {
  unsigned u = __builtin_bit_cast(unsigned, f);
  u += 0x7fffu + ((u >> 16) & 1u);
  return (ushort)(u >> 16);
}
__device__ __forceinline__ float bf2f(ushort h) {
  unsigned u = ((unsigned)h) << 16;
  return __builtin_bit_cast(float, u);
}

__device__ __forceinline__ void gload_lds16(const ushort* g, ushort* l) {
  __builtin_amdgcn_global_load_lds((const __attribute__((address_space(1))) unsigned int*)g,
                                   (__attribute__((address_space(3))) unsigned int*)l, 16, 0, 0);
}

// ---------------- cast fp32 -> bf16 (vectorized) ----------------
__global__ __launch_bounds__(256) void cast_bf16_kernel(const float* __restrict__ in,
                                                        ushort* __restrict__ out, int n4) {
  int i = blockIdx.x * 256 + threadIdx.x;
  int stride = gridDim.x * 256;
  for (; i < n4; i += stride) {
    float4 v = reinterpret_cast<const float4*>(in)[i];
    us4 o;
    o.x = f2bf(v.x); o.y = f2bf(v.y); o.z = f2bf(v.z); o.w = f2bf(v.w);
    reinterpret_cast<us4*>(out)[i] = o;
  }
}

// ---------------- cast + transpose: in [R][C] f32 -> out [C][R] bf16 ----------------
__global__ __launch_bounds__(256) void cast_transpose_kernel(const float* __restrict__ in,
                                                             ushort* __restrict__ out,
                                                             int R, int C) {
  __shared__ float tile[32][33];
  int tx = threadIdx.x & 31, ty = threadIdx.x >> 5;
  int c0 = blockIdx.x * 32, r0 = blockIdx.y * 32;
#pragma unroll
  for (int i = 0; i < 4; ++i)
    tile[ty + i * 8][tx] = in[(size_t)(r0 + ty + i * 8) * C + c0 + tx];
  __syncthreads();
#pragma unroll
  for (int i = 0; i < 4; ++i)
    out[(size_t)(c0 + ty + i * 8) * R + r0 + tx] = f2bf(tile[tx][ty + i * 8]);
}

// ---------------- RoPE tables: cos/sin[t][j], j<64 ----------------
__global__ void rope_table_kernel(float* __restrict__ rc, float* __restrict__ rs) {
  int t = blockIdx.x, j = threadIdx.x;  // 64 threads
  float inv = expf(-(float)j * (9.210340371976184f / 64.0f));
  float ang = (float)t * inv;
  float s, c;
  sincosf(ang, &s, &c);
  rc[t * 64 + j] = c;
  rs[t * 64 + j] = s;
}

// ---------------- fused per-head RMSNorm + RoPE (+ optional output scale) -------
__global__ __launch_bounds__(256) void norm_rope_kernel(
    const ushort* __restrict__ qkv, const float* __restrict__ w,
    ushort* __restrict__ out, const float* __restrict__ rc, const float* __restrict__ rs,
    int nheads, int col_off, int out_stride, float oscale) {
  int wv = threadIdx.x >> 6, lane = threadIdx.x & 63;
  int row = blockIdx.x * 4 + wv;
  int token = row / nheads, head = row % nheads;
  int t = token & 2047;  // token % S
  const ushort* p = qkv + (size_t)token * 3072 + col_off + head * 128;
  float x1 = bf2f(p[lane]), x2 = bf2f(p[lane + 64]);
  float ss = x1 * x1 + x2 * x2;
#pragma unroll
  for (int m = 32; m > 0; m >>= 1) ss += __shfl_xor(ss, m);
  float r = rsqrtf(ss * (1.0f / 128.0f) + 1e-6f);
  float xn1 = x1 * r * w[lane], xn2 = x2 * r * w[lane + 64];
  float c = rc[t * 64 + lane], s = rs[t * 64 + lane];
  ushort* o = out + (size_t)token * out_stride + head * 128;
  o[lane] = f2bf((xn1 * c - xn2 * s) * oscale);
  o[lane + 64] = f2bf((xn2 * c + xn1 * s) * oscale);
}

// ---------------- V transpose: QKV slab -> Vt[b][kv][d][s] ----------------
__global__ __launch_bounds__(256) void v_transpose_kernel(const ushort* __restrict__ qkv,
                                                          ushort* __restrict__ vt) {
  __shared__ ushort tile[64][136];
  int bx = blockIdx.x;
  int st = bx & 31, kvh = (bx >> 5) & 3, b = bx >> 7;
  int s0 = st * 64;
  int tid = threadIdx.x;
#pragma unroll
  for (int p = 0; p < 4; ++p) {
    int idx = p * 2048 + tid * 8;
    int s = idx >> 7, d = idx & 127;
    *(s16x8*)&tile[s][d] =
        *(const s16x8*)&qkv[(size_t)(b * 2048 + s0 + s) * 3072 + 2560 + kvh * 128 + d];
  }
  __syncthreads();
#pragma unroll
  for (int p = 0; p < 4; ++p) {
    int idx = p * 2048 + tid * 8;
    int d = idx >> 6, s = idx & 63;
    s16x8 v;
#pragma unroll
    for (int u = 0; u < 8; ++u) v[u] = (short)tile[s + u][d];
    *(s16x8*)&vt[(size_t)((b * 4 + kvh) * 128 + d) * 2048 + s0 + s] = v;
  }
}

// ---------------- bf16 MFMA GEMM: C[M][N] = A[M][K] * Bt[N][K]^T ----------------
template <bool OUTF32>
__global__ __launch_bounds__(256) void gemm_bt_kernel(const ushort* __restrict__ A,
                                                      const ushort* __restrict__ Bt,
                                                      void* __restrict__ Cp,
                                                      int M, int N, int K) {
  __shared__ ushort As[128][64];
  __shared__ ushort Bs[128][64];
  int tid = threadIdx.x;
  int lane = tid & 63, wv = tid >> 6;
  int wm = wv >> 1, wn = wv & 1;
  int lr = lane & 15, lg = lane >> 4;
  int m0 = blockIdx.y * 128, n0 = blockIdx.x * 128;
  int srow8 = lane >> 3;                  // 0..7 row within 8-row chunk
  int scol = (lane & 7) * 8;              // base ushort col of this lane's 16B
  int gcol = scol ^ (srow8 << 3);         // inverse-swizzled source col
  f32x4 acc[4][4] = {};
  for (int k0 = 0; k0 < K; k0 += 64) {
    __syncthreads();
#pragma unroll
    for (int p = 0; p < 4; ++p) {
      int r0 = wv * 32 + p * 8;           // wave stages rows [wv*32, wv*32+32)
      int grow = r0 + srow8;
      gload_lds16(&A[(size_t)(m0 + grow) * K + k0 + gcol], &As[r0][0]);
      gload_lds16(&Bt[(size_t)(n0 + grow) * K + k0 + gcol], &Bs[r0][0]);
    }
    __syncthreads();
#pragma unroll
    for (int ks = 0; ks < 2; ++ks) {
      s16x8 a[4], b[4];
#pragma unroll
      for (int i = 0; i < 4; ++i) {
        int row = wm * 64 + i * 16 + lr;
        a[i] = *(const s16x8*)&As[row][(ks * 32 + lg * 8) ^ ((row & 7) << 3)];
      }
#pragma unroll
      for (int j = 0; j < 4; ++j) {
        int row = wn * 64 + j * 16 + lr;
        b[j] = *(const s16x8*)&Bs[row][(ks * 32 + lg * 8) ^ ((row & 7) << 3)];
      }
#pragma unroll
      for (int i = 0; i < 4; ++i)
#pragma unroll
        for (int j = 0; j < 4; ++j)
          acc[i][j] = __builtin_amdgcn_mfma_f32_16x16x32_bf16(a[i], b[j], acc[i][j], 0, 0, 0);
    }
  }
#pragma unroll
  for (int i = 0; i < 4; ++i)
#pragma unroll
    for (int j = 0; j < 4; ++j) {
      int row = m0 + wm * 64 + i * 16 + lg * 4;
      int col = n0 + wn * 64 + j * 16 + lr;
#pragma unroll
      for (int r = 0; r < 4; ++r) {
        float v = acc[i][j][r];
        if (OUTF32)
          reinterpret_cast<float*>(Cp)[(size_t)(row + r) * N + col] = v;
        else
          reinterpret_cast<ushort*>(Cp)[(size_t)(row + r) * N + col] = f2bf(v);
      }
    }
}

// ---------------- causal GQA flash attention ----------------
// block: 128 q-rows, 4 waves x 32 q-rows; 64-wide K/V tiles.
// Double-buffered K/V staged via global_load_lds (linear dest, inverse-swizzled
// source), counted vmcnt(8) + raw s_barrier: loads for t+1 in flight across
// compute of t. Q in regs (pre-scaled log2e/sqrt(dk)); base-2 online softmax
// with defer-max.
__global__ __launch_bounds__(256, 2) void attn_kernel(const ushort* __restrict__ Q,
                                                      const ushort* __restrict__ Kn,
                                                      const ushort* __restrict__ Vt,
                                                      ushort* __restrict__ AO) {
  __shared__ ushort Ks[2][64][128];   // 32 KB
  __shared__ ushort Vs[2][128][64];   // 32 KB
  __shared__ ushort Ps[4][32][64];    // 16 KB
  int bx = blockIdx.x;
  int g = bx >> 5, bh = bx & 31;
  int qt = (g < 8) ? (15 - g) : (g - 8);  // pair long+short on each CU
  int b = bh >> 4, h = bh & 15, kvh = h >> 2;
  int q0 = qt * 128;
  int nt = 2 * qt + 2;
  int tid = threadIdx.x, lane = tid & 63, w = tid >> 6;
  int lr = lane & 15, lg = lane >> 4;

  // staging geometry
  int ksrow = lane >> 4;           // K: 4 rows (256B) per 1KB chunk
  int kscol = (lane & 15) * 8;
  int vsrow = lane >> 3;           // V: 8 rows (128B) per 1KB chunk
  int vscol = (lane & 7) * 8;

  auto stage = [&](int c, int t) {
    int p0 = t * 64;
#pragma unroll
    for (int p = 0; p < 4; ++p) {
      int r0 = w * 16 + p * 4;
      int row = r0 + ksrow;
      int gc = kscol ^ ((row & 7) << 3);
      gload_lds16(&Kn[(size_t)(b * 2048 + p0 + row) * 512 + kvh * 128 + gc], &Ks[c][r0][0]);
    }
#pragma unroll
    for (int p = 0; p < 4; ++p) {
      int r0 = w * 32 + p * 8;
      int row = r0 + vsrow;
      int gc = vscol ^ ((row & 7) << 3);
      gload_lds16(&Vt[(size_t)((b * 4 + kvh) * 128 + row) * 2048 + p0 + gc], &Vs[c][r0][0]);
    }
  };

  stage(0, 0);  // prologue: tile 0 in flight

  // Q fragments in registers for the whole block (rows w*32 + qa*16 + lr)
  s16x8 qf[2][4];
#pragma unroll
  for (int qa = 0; qa < 2; ++qa) {
    const ushort* qp = &Q[(size_t)(b * 2048 + q0 + w * 32 + qa * 16 + lr) * 2048 + h * 128];
#pragma unroll
    for (int ks = 0; ks < 4; ++ks) qf[qa][ks] = *(const s16x8*)&qp[ks * 32 + lg * 8];
  }

  f32x4 O[2][8] = {};
  float mrow[2][4], lrow[2][4];
#pragma unroll
  for (int qa = 0; qa < 2; ++qa)
#pragma unroll
    for (int r = 0; r < 4; ++r) { mrow[qa][r] = -1e30f; lrow[qa][r] = 0.f; }

  for (int t = 0; t < nt; ++t) {
    int c = t & 1;
    if (t + 1 < nt) {
      stage(c ^ 1, t + 1);                               // prefetch next tile
      asm volatile("s_waitcnt vmcnt(8)" ::: "memory");   // tile t's 8 loads done
    } else {
      asm volatile("s_waitcnt vmcnt(0)" ::: "memory");
    }
    __builtin_amdgcn_s_barrier();                        // (a) tile t visible

    bool skip = (t == 2 * qt + 1) && (w < 2);            // fully-masked wave-tile
    if (!skip) {
      f32x4 sacc[2][4] = {};
      __builtin_amdgcn_s_setprio(1);
#pragma unroll
      for (int ks = 0; ks < 4; ++ks) {
        s16x8 bk[4];
#pragma unroll
        for (int fp = 0; fp < 4; ++fp) {
          int kr = fp * 16 + lr;
          bk[fp] = *(const s16x8*)&Ks[c][kr][(ks * 32 + lg * 8) ^ ((kr & 7) << 3)];
        }
#pragma unroll
        for (int qa = 0; qa < 2; ++qa)
#pragma unroll
          for (int fp = 0; fp < 4; ++fp)
            sacc[qa][fp] = __builtin_amdgcn_mfma_f32_16x16x32_bf16(qf[qa][ks], bk[fp], sacc[qa][fp], 0, 0, 0);
      }
      __builtin_amdgcn_s_setprio(0);

      // causal mask (only last two tiles can straddle the diagonal)
      if (t >= 2 * qt) {
        int p0 = t * 64;
#pragma unroll
        for (int qa = 0; qa < 2; ++qa)
#pragma unroll
          for (int fp = 0; fp < 4; ++fp)
#pragma unroll
            for (int r = 0; r < 4; ++r) {
              int qg = q0 + w * 32 + qa * 16 + lg * 4 + r;
              int pg = p0 + fp * 16 + lr;
              if (pg > qg) sacc[qa][fp][r] = -1e30f;
            }
      }

      float pm[2][4];
#pragma unroll
      for (int qa = 0; qa < 2; ++qa)
#pragma unroll
        for (int r = 0; r < 4; ++r) pm[qa][r] = -1e30f;
#pragma unroll
      for (int qa = 0; qa < 2; ++qa)
#pragma unroll
        for (int fp = 0; fp < 4; ++fp)
#pragma unroll
          for (int r = 0; r < 4; ++r) pm[qa][r] = fmaxf(pm[qa][r], sacc[qa][fp][r]);
#pragma unroll
      for (int qa = 0; qa < 2; ++qa)
#pragma unroll
        for (int r = 0; r < 4; ++r) {
          pm[qa][r] = fmaxf(pm[qa][r], __shfl_xor(pm[qa][r], 1));
          pm[qa][r] = fmaxf(pm[qa][r], __shfl_xor(pm[qa][r], 2));
          pm[qa][r] = fmaxf(pm[qa][r], __shfl_xor(pm[qa][r], 4));
          pm[qa][r] = fmaxf(pm[qa][r], __shfl_xor(pm[qa][r], 8));
        }
      // defer-max (log2 domain, THR=8)
      bool need = false;
#pragma unroll
      for (int qa = 0; qa < 2; ++qa)
#pragma unroll
        for (int r = 0; r < 4; ++r) need |= (pm[qa][r] > mrow[qa][r] + 8.0f);
      if (__any((int)need)) {
#pragma unroll
        for (int qa = 0; qa < 2; ++qa) {
          float fsc[4];
#pragma unroll
          for (int r = 0; r < 4; ++r) {
            float mn = fmaxf(mrow[qa][r], pm[qa][r]);
            fsc[r] = __builtin_amdgcn_exp2f(mrow[qa][r] - mn);
            mrow[qa][r] = mn;
            lrow[qa][r] *= fsc[r];
          }
#pragma unroll
          for (int fn = 0; fn < 8; ++fn)
#pragma unroll
            for (int r = 0; r < 4; ++r) O[qa][fn][r] *= fsc[r];
        }
      }
      float ls[2][4] = {};
#pragma unroll
      for (int qa = 0; qa < 2; ++qa)
#pragma unroll
        for (int fp = 0; fp < 4; ++fp)
#pragma unroll
          for (int r = 0; r < 4; ++r) {
            float pv = __builtin_amdgcn_exp2f(sacc[qa][fp][r] - mrow[qa][r]);
            ls[qa][r] += pv;
            int prow = qa * 16 + lg * 4 + r;
            Ps[w][prow][(fp * 16 + lr) ^ ((prow & 7) << 3)] = f2bf(pv);
          }
#pragma unroll
      for (int qa = 0; qa < 2; ++qa)
#pragma unroll
        for (int r = 0; r < 4; ++r) {
          ls[qa][r] += __shfl_xor(ls[qa][r], 1);
          ls[qa][r] += __shfl_xor(ls[qa][r], 2);
          ls[qa][r] += __shfl_xor(ls[qa][r], 4);
          ls[qa][r] += __shfl_xor(ls[qa][r], 8);
          lrow[qa][r] += ls[qa][r];
        }
      __builtin_amdgcn_s_setprio(1);
#pragma unroll
      for (int ks2 = 0; ks2 < 2; ++ks2) {
        s16x8 ap[2];
#pragma unroll
        for (int qa = 0; qa < 2; ++qa) {
          int prow = qa * 16 + lr;
          ap[qa] = *(const s16x8*)&Ps[w][prow][(ks2 * 32 + lg * 8) ^ ((prow & 7) << 3)];
        }
#pragma unroll
        for (int fn = 0; fn < 8; ++fn) {
          int vrow = fn * 16 + lr;
          s16x8 bv = *(const s16x8*)&Vs[c][vrow][(ks2 * 32 + lg * 8) ^ ((vrow & 7) << 3)];
#pragma unroll
          for (int qa = 0; qa < 2; ++qa)
            O[qa][fn] = __builtin_amdgcn_mfma_f32_16x16x32_bf16(ap[qa], bv, O[qa][fn], 0, 0, 0);
        }
      }
      __builtin_amdgcn_s_setprio(0);
    }
    __builtin_amdgcn_s_barrier();  // (b) all waves done reading buf c
  }

#pragma unroll
  for (int qa = 0; qa < 2; ++qa) {
    float invl[4];
#pragma unroll
    for (int r = 0; r < 4; ++r) invl[r] = 1.0f / lrow[qa][r];
#pragma unroll
    for (int fn = 0; fn < 8; ++fn)
#pragma unroll
      for (int r = 0; r < 4; ++r) {
        size_t idx = (size_t)(b * 2048 + q0 + w * 32 + qa * 16 + lg * 4 + r) * 2048 +
                     h * 128 + fn * 16 + lr;
        AO[idx] = f2bf(O[qa][fn][r] * invl[r]);
      }
  }
}

extern "C" void kernel_launch(void* const* d_in, const int* in_sizes, int n_in,
                              void* d_out, int out_size, void* d_ws, size_t ws_size,
                              hipStream_t stream) {
  (void)in_sizes; (void)n_in; (void)out_size; (void)ws_size;
  const float* x = (const float*)d_in[0];
  const float* Wq = (const float*)d_in[1];
  const float* Wk = (const float*)d_in[2];
  const float* Wv = (const float*)d_in[3];
  const float* Wo = (const float*)d_in[4];
  const float* qw = (const float*)d_in[5];
  const float* kw = (const float*)d_in[6];
  float* out = (float*)d_out;

  char* ws = (char*)d_ws;
  size_t off = 0;
  auto alloc = [&](size_t bytes) {
    void* p = ws + off;
    off += (bytes + 255) & ~(size_t)255;
    return p;
  };
  ushort* xb = (ushort*)alloc((size_t)4096 * 2048 * 2);
  ushort* WqkvT = (ushort*)alloc((size_t)3072 * 2048 * 2);
  ushort* WoT = (ushort*)alloc((size_t)2048 * 2048 * 2);
  ushort* QKVraw = (ushort*)alloc((size_t)4096 * 3072 * 2);
  ushort* Qn = (ushort*)alloc((size_t)4096 * 2048 * 2);
  ushort* Kb = (ushort*)alloc((size_t)4096 * 512 * 2);
  ushort* Vt = (ushort*)alloc((size_t)4096 * 512 * 2);
  ushort* AO = (ushort*)alloc((size_t)4096 * 2048 * 2);
  float* rc = (float*)alloc((size_t)2048 * 64 * 4);
  float* rs = (float*)alloc((size_t)2048 * 64 * 4);

  // log2(e) / sqrt(128): fold softmax scale + base-2 conversion into Q
  const float QSCALE = 0.12751744f;

  cast_bf16_kernel<<<2048, 256, 0, stream>>>(x, xb, 4096 * 2048 / 4);
  cast_transpose_kernel<<<dim3(64, 64), 256, 0, stream>>>(Wq, WqkvT, 2048, 2048);
  cast_transpose_kernel<<<dim3(16, 64), 256, 0, stream>>>(Wk, WqkvT + (size_t)2048 * 2048, 2048, 512);
  cast_transpose_kernel<<<dim3(16, 64), 256, 0, stream>>>(Wv, WqkvT + (size_t)2560 * 2048, 2048, 512);
  cast_transpose_kernel<<<dim3(64, 64), 256, 0, stream>>>(Wo, WoT, 2048, 2048);
  rope_table_kernel<<<2048, 64, 0, stream>>>(rc, rs);
  gemm_bt_kernel<false><<<dim3(24, 32), 256, 0, stream>>>(xb, WqkvT, QKVraw, 4096, 3072, 2048);
  norm_rope_kernel<<<16384, 256, 0, stream>>>(QKVraw, qw, Qn, rc, rs, 16, 0, 2048, QSCALE);
  norm_rope_kernel<<<4096, 256, 0, stream>>>(QKVraw, kw, Kb, rc, rs, 4, 2048, 512, 1.0f);
  v_transpose_kernel<<<256, 256, 0, stream>>>(QKVraw, Vt);
  attn_kernel<<<512, 256, 0, stream>>>(Qn, Kb, Vt, AO);
  gemm_bt_kernel<true><<<dim3(16, 32), 256, 0, stream>>>(AO, WoT, out, 4096, 2048, 2048);
}

// Round 4
// 230.154 us; speedup vs baseline: 1.5604x; 1.1154x over previous
//
#include <hip/hip_runtime.h>

typedef __attribute__((ext_vector_type(4))) float f32x4;
typedef __attribute__((ext_vector_type(8))) short s16x8;

struct alignas(8) us4 { ushort x, y, z, w; };

__device__ __forceinline__ ushort f2bf(float f) {
  unsigned u = __builtin_bit_cast(unsigned, f);
  u += 0x7fffu + ((u >> 16) & 1u);
  return (ushort)(u >> 16);
}
__device__ __forceinline__ float bf2f(ushort h) {
  unsigned u = ((unsigned)h) << 16;
  return __builtin_bit_cast(float, u);
}

__device__ __forceinline__ void gload_lds16(const ushort* g, ushort* l) {
  __builtin_amdgcn_global_load_lds((const __attribute__((address_space(1))) unsigned int*)g,
                                   (__attribute__((address_space(3))) unsigned int*)l, 16, 0, 0);
}

// ---------------- cast fp32 -> bf16 (vectorized) ----------------
__global__ __launch_bounds__(256) void cast_bf16_kernel(const float* __restrict__ in,
                                                        ushort* __restrict__ out, int n4) {
  int i = blockIdx.x * 256 + threadIdx.x;
  int stride = gridDim.x * 256;
  for (; i < n4; i += stride) {
    float4 v = reinterpret_cast<const float4*>(in)[i];
    us4 o;
    o.x = f2bf(v.x); o.y = f2bf(v.y); o.z = f2bf(v.z); o.w = f2bf(v.w);
    reinterpret_cast<us4*>(out)[i] = o;
  }
}

// ---------------- cast + transpose: in [R][C] f32 -> out [C][R] bf16 ----------------
__global__ __launch_bounds__(256) void cast_transpose_kernel(const float* __restrict__ in,
                                                             ushort* __restrict__ out,
                                                             int R, int C) {
  __shared__ float tile[32][33];
  int tx = threadIdx.x & 31, ty = threadIdx.x >> 5;
  int c0 = blockIdx.x * 32, r0 = blockIdx.y * 32;
#pragma unroll
  for (int i = 0; i < 4; ++i)
    tile[ty + i * 8][tx] = in[(size_t)(r0 + ty + i * 8) * C + c0 + tx];
  __syncthreads();
#pragma unroll
  for (int i = 0; i < 4; ++i)
    out[(size_t)(c0 + ty + i * 8) * R + r0 + tx] = f2bf(tile[tx][ty + i * 8]);
}

// ---------------- RoPE tables: cos/sin[t][j], j<64 ----------------
__global__ void rope_table_kernel(float* __restrict__ rc, float* __restrict__ rs) {
  int t = blockIdx.x, j = threadIdx.x;  // 64 threads
  float inv = expf(-(float)j * (9.210340371976184f / 64.0f));
  float ang = (float)t * inv;
  float s, c;
  sincosf(ang, &s, &c);
  rc[t * 64 + j] = c;
  rs[t * 64 + j] = s;
}

// ---------------- fused per-head RMSNorm + RoPE (+ optional output scale) -------
__global__ __launch_bounds__(256) void norm_rope_kernel(
    const ushort* __restrict__ qkv, const float* __restrict__ w,
    ushort* __restrict__ out, const float* __restrict__ rc, const float* __restrict__ rs,
    int nheads, int col_off, int out_stride, float oscale) {
  int wv = threadIdx.x >> 6, lane = threadIdx.x & 63;
  int row = blockIdx.x * 4 + wv;
  int token = row / nheads, head = row % nheads;
  int t = token & 2047;  // token % S
  const ushort* p = qkv + (size_t)token * 3072 + col_off + head * 128;
  float x1 = bf2f(p[lane]), x2 = bf2f(p[lane + 64]);
  float ss = x1 * x1 + x2 * x2;
#pragma unroll
  for (int m = 32; m > 0; m >>= 1) ss += __shfl_xor(ss, m);
  float r = rsqrtf(ss * (1.0f / 128.0f) + 1e-6f);
  float xn1 = x1 * r * w[lane], xn2 = x2 * r * w[lane + 64];
  float c = rc[t * 64 + lane], s = rs[t * 64 + lane];
  ushort* o = out + (size_t)token * out_stride + head * 128;
  o[lane] = f2bf((xn1 * c - xn2 * s) * oscale);
  o[lane + 64] = f2bf((xn2 * c + xn1 * s) * oscale);
}

// ---------------- V transpose: QKV slab -> Vt[b][kv][d][s] ----------------
__global__ __launch_bounds__(256) void v_transpose_kernel(const ushort* __restrict__ qkv,
                                                          ushort* __restrict__ vt) {
  __shared__ ushort tile[64][136];
  int bx = blockIdx.x;
  int st = bx & 31, kvh = (bx >> 5) & 3, b = bx >> 7;
  int s0 = st * 64;
  int tid = threadIdx.x;
#pragma unroll
  for (int p = 0; p < 4; ++p) {
    int idx = p * 2048 + tid * 8;
    int s = idx >> 7, d = idx & 127;
    *(s16x8*)&tile[s][d] =
        *(const s16x8*)&qkv[(size_t)(b * 2048 + s0 + s) * 3072 + 2560 + kvh * 128 + d];
  }
  __syncthreads();
#pragma unroll
  for (int p = 0; p < 4; ++p) {
    int idx = p * 2048 + tid * 8;
    int d = idx >> 6, s = idx & 63;
    s16x8 v;
#pragma unroll
    for (int u = 0; u < 8; ++u) v[u] = (short)tile[s + u][d];
    *(s16x8*)&vt[(size_t)((b * 4 + kvh) * 128 + d) * 2048 + s0 + s] = v;
  }
}

// ---------------- bf16 MFMA GEMM: C[M][N] = A[M][K] * Bt[N][K]^T ----------------
template <bool OUTF32>
__global__ __launch_bounds__(256) void gemm_bt_kernel(const ushort* __restrict__ A,
                                                      const ushort* __restrict__ Bt,
                                                      void* __restrict__ Cp,
                                                      int M, int N, int K) {
  __shared__ ushort As[128][64];
  __shared__ ushort Bs[128][64];
  int tid = threadIdx.x;
  int lane = tid & 63, wv = tid >> 6;
  int wm = wv >> 1, wn = wv & 1;
  int lr = lane & 15, lg = lane >> 4;
  int m0 = blockIdx.y * 128, n0 = blockIdx.x * 128;
  int srow8 = lane >> 3;                  // 0..7 row within 8-row chunk
  int scol = (lane & 7) * 8;              // base ushort col of this lane's 16B
  int gcol = scol ^ (srow8 << 3);         // inverse-swizzled source col
  f32x4 acc[4][4] = {};
  for (int k0 = 0; k0 < K; k0 += 64) {
    __syncthreads();
#pragma unroll
    for (int p = 0; p < 4; ++p) {
      int r0 = wv * 32 + p * 8;           // wave stages rows [wv*32, wv*32+32)
      int grow = r0 + srow8;
      gload_lds16(&A[(size_t)(m0 + grow) * K + k0 + gcol], &As[r0][0]);
      gload_lds16(&Bt[(size_t)(n0 + grow) * K + k0 + gcol], &Bs[r0][0]);
    }
    __syncthreads();
#pragma unroll
    for (int ks = 0; ks < 2; ++ks) {
      s16x8 a[4], b[4];
#pragma unroll
      for (int i = 0; i < 4; ++i) {
        int row = wm * 64 + i * 16 + lr;
        a[i] = *(const s16x8*)&As[row][(ks * 32 + lg * 8) ^ ((row & 7) << 3)];
      }
#pragma unroll
      for (int j = 0; j < 4; ++j) {
        int row = wn * 64 + j * 16 + lr;
        b[j] = *(const s16x8*)&Bs[row][(ks * 32 + lg * 8) ^ ((row & 7) << 3)];
      }
#pragma unroll
      for (int i = 0; i < 4; ++i)
#pragma unroll
        for (int j = 0; j < 4; ++j)
          acc[i][j] = __builtin_amdgcn_mfma_f32_16x16x32_bf16(a[i], b[j], acc[i][j], 0, 0, 0);
    }
  }
#pragma unroll
  for (int i = 0; i < 4; ++i)
#pragma unroll
    for (int j = 0; j < 4; ++j) {
      int row = m0 + wm * 64 + i * 16 + lg * 4;
      int col = n0 + wn * 64 + j * 16 + lr;
#pragma unroll
      for (int r = 0; r < 4; ++r) {
        float v = acc[i][j][r];
        if (OUTF32)
          reinterpret_cast<float*>(Cp)[(size_t)(row + r) * N + col] = v;
        else
          reinterpret_cast<ushort*>(Cp)[(size_t)(row + r) * N + col] = f2bf(v);
      }
    }
}

// ---------------- causal GQA flash attention ----------------
// block: 128 q-rows, 4 waves x 32 q-rows; 64-wide K/V tiles; dbuf K/V via
// global_load_lds + counted vmcnt(8). SWAPPED QK^T: sacc = mfma(K,Q) gives
// lane P^T[q=lane&15][k=16fp+4lg+r] -> in-lane row reductions (2 shfl),
// packed b64 P-writes. Base-2 online softmax, defer-max THR=8.
__global__ __launch_bounds__(256, 2) void attn_kernel(const ushort* __restrict__ Q,
                                                      const ushort* __restrict__ Kn,
                                                      const ushort* __restrict__ Vt,
                                                      ushort* __restrict__ AO) {
  __shared__ ushort Ks[2][64][128];   // 32 KB
  __shared__ ushort Vs[2][128][64];   // 32 KB
  __shared__ ushort Ps[4][32][64];    // 16 KB
  int bx = blockIdx.x;
  int g = bx >> 5, bh = bx & 31;
  int qt = (g < 8) ? (15 - g) : (g - 8);  // pair long+short on each CU
  int b = bh >> 4, h = bh & 15, kvh = h >> 2;
  int q0 = qt * 128;
  int nt = 2 * qt + 2;
  int tid = threadIdx.x, lane = tid & 63, w = tid >> 6;
  int lr = lane & 15, lg = lane >> 4;

  // staging geometry
  int ksrow = lane >> 4;           // K: 4 rows (256B) per 1KB chunk
  int kscol = (lane & 15) * 8;
  int vsrow = lane >> 3;           // V: 8 rows (128B) per 1KB chunk
  int vscol = (lane & 7) * 8;

  auto stage = [&](int c, int t) {
    int p0 = t * 64;
#pragma unroll
    for (int p = 0; p < 4; ++p) {
      int r0 = w * 16 + p * 4;
      int row = r0 + ksrow;
      int gc = kscol ^ ((row & 7) << 3);
      gload_lds16(&Kn[(size_t)(b * 2048 + p0 + row) * 512 + kvh * 128 + gc], &Ks[c][r0][0]);
    }
#pragma unroll
    for (int p = 0; p < 4; ++p) {
      int r0 = w * 32 + p * 8;
      int row = r0 + vsrow;
      int gc = vscol ^ ((row & 7) << 3);
      gload_lds16(&Vt[(size_t)((b * 4 + kvh) * 128 + row) * 2048 + p0 + gc], &Vs[c][r0][0]);
    }
  };

  stage(0, 0);  // prologue: tile 0 in flight

  // Q fragments in registers (rows w*32 + qa*16 + lr)
  s16x8 qf[2][4];
#pragma unroll
  for (int qa = 0; qa < 2; ++qa) {
    const ushort* qp = &Q[(size_t)(b * 2048 + q0 + w * 32 + qa * 16 + lr) * 2048 + h * 128];
#pragma unroll
    for (int ks = 0; ks < 4; ++ks) qf[qa][ks] = *(const s16x8*)&qp[ks * 32 + lg * 8];
  }

  f32x4 O[2][8] = {};
  float mrow[2] = {-1e30f, -1e30f};  // per-lane scalar: row q = qa*16 + (lane&15)
  float lrow[2] = {0.f, 0.f};

  for (int t = 0; t < nt; ++t) {
    int c = t & 1;
    if (t + 1 < nt) {
      stage(c ^ 1, t + 1);                               // prefetch next tile
      asm volatile("s_waitcnt vmcnt(8)" ::: "memory");   // tile t's 8 loads done
    } else {
      asm volatile("s_waitcnt vmcnt(0)" ::: "memory");
    }
    __builtin_amdgcn_s_barrier();                        // (a) tile t visible

    bool skip = (t == 2 * qt + 1) && (w < 2);            // fully-masked wave-tile
    if (!skip) {
      // SWAPPED: sacc[qa][fp] = S^T tile: lane holds q=lane&15, k=fp*16+lg*4+r
      f32x4 sacc[2][4] = {};
      __builtin_amdgcn_s_setprio(1);
#pragma unroll
      for (int ks = 0; ks < 4; ++ks) {
        s16x8 bk[4];
#pragma unroll
        for (int fp = 0; fp < 4; ++fp) {
          int kr = fp * 16 + lr;
          bk[fp] = *(const s16x8*)&Ks[c][kr][(ks * 32 + lg * 8) ^ ((kr & 7) << 3)];
        }
#pragma unroll
        for (int qa = 0; qa < 2; ++qa)
#pragma unroll
          for (int fp = 0; fp < 4; ++fp)
            sacc[qa][fp] = __builtin_amdgcn_mfma_f32_16x16x32_bf16(bk[fp], qf[qa][ks], sacc[qa][fp], 0, 0, 0);
      }
      __builtin_amdgcn_s_setprio(0);

      // causal mask (only tiles straddling the diagonal)
      if (t >= 2 * qt) {
        int p0 = t * 64;
#pragma unroll
        for (int qa = 0; qa < 2; ++qa)
#pragma unroll
          for (int fp = 0; fp < 4; ++fp)
#pragma unroll
            for (int r = 0; r < 4; ++r) {
              int qg = q0 + w * 32 + qa * 16 + lr;
              int pg = p0 + fp * 16 + lg * 4 + r;
              if (pg > qg) sacc[qa][fp][r] = -1e30f;
            }
      }

      // row max: in-lane over 16, then xor-16/32 across lg groups
      float pm[2];
#pragma unroll
      for (int qa = 0; qa < 2; ++qa) {
        float m01 = fmaxf(fmaxf(sacc[qa][0][0], sacc[qa][0][1]), fmaxf(sacc[qa][0][2], sacc[qa][0][3]));
#pragma unroll
        for (int fp = 1; fp < 4; ++fp)
          m01 = fmaxf(m01, fmaxf(fmaxf(sacc[qa][fp][0], sacc[qa][fp][1]),
                                 fmaxf(sacc[qa][fp][2], sacc[qa][fp][3])));
        m01 = fmaxf(m01, __shfl_xor(m01, 16));
        m01 = fmaxf(m01, __shfl_xor(m01, 32));
        pm[qa] = m01;
      }
      // defer-max (log2 domain, THR=8)
      bool need = (pm[0] > mrow[0] + 8.0f) | (pm[1] > mrow[1] + 8.0f);
      if (__any((int)need)) {
        float fsc[2];
#pragma unroll
        for (int qa = 0; qa < 2; ++qa) {
          float mn = fmaxf(mrow[qa], pm[qa]);
          fsc[qa] = __builtin_amdgcn_exp2f(mrow[qa] - mn);
          mrow[qa] = mn;
          lrow[qa] *= fsc[qa];
        }
        // redistribute to O layout (q = lg*4 + r)
#pragma unroll
        for (int qa = 0; qa < 2; ++qa) {
          float fo[4];
#pragma unroll
          for (int r = 0; r < 4; ++r) fo[r] = __shfl(fsc[qa], lg * 4 + r);
#pragma unroll
          for (int fn = 0; fn < 8; ++fn)
#pragma unroll
            for (int r = 0; r < 4; ++r) O[qa][fn][r] *= fo[r];
        }
      }
      // exp2 + packed P write + row sum
      float ls[2] = {0.f, 0.f};
#pragma unroll
      for (int qa = 0; qa < 2; ++qa) {
        int prow = qa * 16 + lr;
        int swz = (lr & 7) << 3;
#pragma unroll
        for (int fp = 0; fp < 4; ++fp) {
          float e0 = __builtin_amdgcn_exp2f(sacc[qa][fp][0] - mrow[qa]);
          float e1 = __builtin_amdgcn_exp2f(sacc[qa][fp][1] - mrow[qa]);
          float e2 = __builtin_amdgcn_exp2f(sacc[qa][fp][2] - mrow[qa]);
          float e3 = __builtin_amdgcn_exp2f(sacc[qa][fp][3] - mrow[qa]);
          ls[qa] += (e0 + e1) + (e2 + e3);
          unsigned lo = (unsigned)f2bf(e0) | ((unsigned)f2bf(e1) << 16);
          unsigned hi = (unsigned)f2bf(e2) | ((unsigned)f2bf(e3) << 16);
          uint2 pk; pk.x = lo; pk.y = hi;
          *reinterpret_cast<uint2*>(&Ps[w][prow][(fp * 16 + lg * 4) ^ swz]) = pk;
        }
        ls[qa] += __shfl_xor(ls[qa], 16);
        ls[qa] += __shfl_xor(ls[qa], 32);
        lrow[qa] += ls[qa];
      }
      __builtin_amdgcn_s_setprio(1);
#pragma unroll
      for (int ks2 = 0; ks2 < 2; ++ks2) {
        s16x8 ap[2];
#pragma unroll
        for (int qa = 0; qa < 2; ++qa) {
          int prow = qa * 16 + lr;
          ap[qa] = *(const s16x8*)&Ps[w][prow][(ks2 * 32 + lg * 8) ^ ((lr & 7) << 3)];
        }
#pragma unroll
        for (int fn = 0; fn < 8; ++fn) {
          int vrow = fn * 16 + lr;
          s16x8 bv = *(const s16x8*)&Vs[c][vrow][(ks2 * 32 + lg * 8) ^ ((vrow & 7) << 3)];
#pragma unroll
          for (int qa = 0; qa < 2; ++qa)
            O[qa][fn] = __builtin_amdgcn_mfma_f32_16x16x32_bf16(ap[qa], bv, O[qa][fn], 0, 0, 0);
        }
      }
      __builtin_amdgcn_s_setprio(0);
    }
    __builtin_amdgcn_s_barrier();  // (b) all waves done reading buf c
  }

  // epilogue: O rows are q = lg*4+r; lrow lives at lane&15 == q -> shfl remap
#pragma unroll
  for (int qa = 0; qa < 2; ++qa) {
    float inv = 1.0f / lrow[qa];
    float invq[4];
#pragma unroll
    for (int r = 0; r < 4; ++r) invq[r] = __shfl(inv, lg * 4 + r);
#pragma unroll
    for (int fn = 0; fn < 8; ++fn)
#pragma unroll
      for (int r = 0; r < 4; ++r) {
        size_t idx = (size_t)(b * 2048 + q0 + w * 32 + qa * 16 + lg * 4 + r) * 2048 +
                     h * 128 + fn * 16 + lr;
        AO[idx] = f2bf(O[qa][fn][r] * invq[r]);
      }
  }
}

extern "C" void kernel_launch(void* const* d_in, const int* in_sizes, int n_in,
                              void* d_out, int out_size, void* d_ws, size_t ws_size,
                              hipStream_t stream) {
  (void)in_sizes; (void)n_in; (void)out_size; (void)ws_size;
  const float* x = (const float*)d_in[0];
  const float* Wq = (const float*)d_in[1];
  const float* Wk = (const float*)d_in[2];
  const float* Wv = (const float*)d_in[3];
  const float* Wo = (const float*)d_in[4];
  const float* qw = (const float*)d_in[5];
  const float* kw = (const float*)d_in[6];
  float* out = (float*)d_out;

  char* ws = (char*)d_ws;
  size_t off = 0;
  auto alloc = [&](size_t bytes) {
    void* p = ws + off;
    off += (bytes + 255) & ~(size_t)255;
    return p;
  };
  ushort* xb = (ushort*)alloc((size_t)4096 * 2048 * 2);
  ushort* WqkvT = (ushort*)alloc((size_t)3072 * 2048 * 2);
  ushort* WoT = (ushort*)alloc((size_t)2048 * 2048 * 2);
  ushort* QKVraw = (ushort*)alloc((size_t)4096 * 3072 * 2);
  ushort* Qn = (ushort*)alloc((size_t)4096 * 2048 * 2);
  ushort* Kb = (ushort*)alloc((size_t)4096 * 512 * 2);
  ushort* Vt = (ushort*)alloc((size_t)4096 * 512 * 2);
  ushort* AO = (ushort*)alloc((size_t)4096 * 2048 * 2);
  float* rc = (float*)alloc((size_t)2048 * 64 * 4);
  float* rs = (float*)alloc((size_t)2048 * 64 * 4);

  // log2(e) / sqrt(128): fold softmax scale + base-2 conversion into Q
  const float QSCALE = 0.12751744f;

  cast_bf16_kernel<<<2048, 256, 0, stream>>>(x, xb, 4096 * 2048 / 4);
  cast_transpose_kernel<<<dim3(64, 64), 256, 0, stream>>>(Wq, WqkvT, 2048, 2048);
  cast_transpose_kernel<<<dim3(16, 64), 256, 0, stream>>>(Wk, WqkvT + (size_t)2048 * 2048, 2048, 512);
  cast_transpose_kernel<<<dim3(16, 64), 256, 0, stream>>>(Wv, WqkvT + (size_t)2560 * 2048, 2048, 512);
  cast_transpose_kernel<<<dim3(64, 64), 256, 0, stream>>>(Wo, WoT, 2048, 2048);
  rope_table_kernel<<<2048, 64, 0, stream>>>(rc, rs);
  gemm_bt_kernel<false><<<dim3(24, 32), 256, 0, stream>>>(xb, WqkvT, QKVraw, 4096, 3072, 2048);
  norm_rope_kernel<<<16384, 256, 0, stream>>>(QKVraw, qw, Qn, rc, rs, 16, 0, 2048, QSCALE);
  norm_rope_kernel<<<4096, 256, 0, stream>>>(QKVraw, kw, Kb, rc, rs, 4, 2048, 512, 1.0f);
  v_transpose_kernel<<<256, 256, 0, stream>>>(QKVraw, Vt);
  attn_kernel<<<512, 256, 0, stream>>>(Qn, Kb, Vt, AO);
  gemm_bt_kernel<true><<<dim3(16, 32), 256, 0, stream>>>(AO, WoT, out, 4096, 2048, 2048);
}

// Round 5
// 222.228 us; speedup vs baseline: 1.6161x; 1.0357x over previous
//
#include <hip/hip_runtime.h>

typedef __attribute__((ext_vector_type(4))) float f32x4;
typedef __attribute__((ext_vector_type(8))) short s16x8;

struct alignas(8) us4 { ushort x, y, z, w; };

__device__ __forceinline__ ushort f2bf(float f) {
  unsigned u = __builtin_bit_cast(unsigned, f);
  u += 0x7fffu + ((u >> 16) & 1u);
  return (ushort)(u >> 16);
}
__device__ __forceinline__ float bf2f(ushort h) {
  unsigned u = ((unsigned)h) << 16;
  return __builtin_bit_cast(float, u);
}

__device__ __forceinline__ void gload_lds16(const ushort* g, ushort* l) {
  __builtin_amdgcn_global_load_lds((const __attribute__((address_space(1))) unsigned int*)g,
                                   (__attribute__((address_space(3))) unsigned int*)l, 16, 0, 0);
}

// ---------------- cast fp32 -> bf16 (vectorized) ----------------
__global__ __launch_bounds__(256) void cast_bf16_kernel(const float* __restrict__ in,
                                                        ushort* __restrict__ out, int n4) {
  int i = blockIdx.x * 256 + threadIdx.x;
  int stride = gridDim.x * 256;
  for (; i < n4; i += stride) {
    float4 v = reinterpret_cast<const float4*>(in)[i];
    us4 o;
    o.x = f2bf(v.x); o.y = f2bf(v.y); o.z = f2bf(v.z); o.w = f2bf(v.w);
    reinterpret_cast<us4*>(out)[i] = o;
  }
}

// ---------------- cast + transpose: in [R][C] f32 -> out [C][R] bf16 ----------------
__global__ __launch_bounds__(256) void cast_transpose_kernel(const float* __restrict__ in,
                                                             ushort* __restrict__ out,
                                                             int R, int C) {
  __shared__ float tile[32][33];
  int tx = threadIdx.x & 31, ty = threadIdx.x >> 5;
  int c0 = blockIdx.x * 32, r0 = blockIdx.y * 32;
#pragma unroll
  for (int i = 0; i < 4; ++i)
    tile[ty + i * 8][tx] = in[(size_t)(r0 + ty + i * 8) * C + c0 + tx];
  __syncthreads();
#pragma unroll
  for (int i = 0; i < 4; ++i)
    out[(size_t)(c0 + ty + i * 8) * R + r0 + tx] = f2bf(tile[tx][ty + i * 8]);
}

// ---------------- RoPE tables: cos/sin[t][j], j<64 ----------------
__global__ void rope_table_kernel(float* __restrict__ rc, float* __restrict__ rs) {
  int t = blockIdx.x, j = threadIdx.x;  // 64 threads
  float inv = expf(-(float)j * (9.210340371976184f / 64.0f));
  float ang = (float)t * inv;
  float s, c;
  sincosf(ang, &s, &c);
  rc[t * 64 + j] = c;
  rs[t * 64 + j] = s;
}

// ---------------- fused per-head RMSNorm + RoPE (+ optional output scale) -------
__global__ __launch_bounds__(256) void norm_rope_kernel(
    const ushort* __restrict__ qkv, const float* __restrict__ w,
    ushort* __restrict__ out, const float* __restrict__ rc, const float* __restrict__ rs,
    int nheads, int col_off, int out_stride, float oscale) {
  int wv = threadIdx.x >> 6, lane = threadIdx.x & 63;
  int row = blockIdx.x * 4 + wv;
  int token = row / nheads, head = row % nheads;
  int t = token & 2047;  // token % S
  const ushort* p = qkv + (size_t)token * 3072 + col_off + head * 128;
  float x1 = bf2f(p[lane]), x2 = bf2f(p[lane + 64]);
  float ss = x1 * x1 + x2 * x2;
#pragma unroll
  for (int m = 32; m > 0; m >>= 1) ss += __shfl_xor(ss, m);
  float r = rsqrtf(ss * (1.0f / 128.0f) + 1e-6f);
  float xn1 = x1 * r * w[lane], xn2 = x2 * r * w[lane + 64];
  float c = rc[t * 64 + lane], s = rs[t * 64 + lane];
  ushort* o = out + (size_t)token * out_stride + head * 128;
  o[lane] = f2bf((xn1 * c - xn2 * s) * oscale);
  o[lane + 64] = f2bf((xn2 * c + xn1 * s) * oscale);
}

// ---------------- V transpose: QKV slab -> Vt[b][kv][d][s] ----------------
__global__ __launch_bounds__(256) void v_transpose_kernel(const ushort* __restrict__ qkv,
                                                          ushort* __restrict__ vt) {
  __shared__ ushort tile[64][136];
  int bx = blockIdx.x;
  int st = bx & 31, kvh = (bx >> 5) & 3, b = bx >> 7;
  int s0 = st * 64;
  int tid = threadIdx.x;
#pragma unroll
  for (int p = 0; p < 4; ++p) {
    int idx = p * 2048 + tid * 8;
    int s = idx >> 7, d = idx & 127;
    *(s16x8*)&tile[s][d] =
        *(const s16x8*)&qkv[(size_t)(b * 2048 + s0 + s) * 3072 + 2560 + kvh * 128 + d];
  }
  __syncthreads();
#pragma unroll
  for (int p = 0; p < 4; ++p) {
    int idx = p * 2048 + tid * 8;
    int d = idx >> 6, s = idx & 63;
    s16x8 v;
#pragma unroll
    for (int u = 0; u < 8; ++u) v[u] = (short)tile[s + u][d];
    *(s16x8*)&vt[(size_t)((b * 4 + kvh) * 128 + d) * 2048 + s0 + s] = v;
  }
}

// ---------------- bf16 MFMA GEMM, 256x128 tile, 3-slot pipelined ----------------
// C[M][N] = A[M][K] * Bt[N][K]^T.  8 waves (4M x 2N), BK=64.
// 3-slot LDS rotation; tile t+2 staged during tile t's compute into the slot
// tile t-1 vacated (top-of-tile barrier = vacancy proof). Counted vmcnt(6):
// never drains in the main loop (T3+T4).
template <bool OUTF32>
__global__ __launch_bounds__(512, 2) void gemm256_kernel(const ushort* __restrict__ A,
                                                         const ushort* __restrict__ Bt,
                                                         void* __restrict__ Cp,
                                                         int M, int N, int K) {
  __shared__ ushort As[3][256][64];  // 96 KB
  __shared__ ushort Bs[3][128][64];  // 48 KB
  int tid = threadIdx.x;
  int lane = tid & 63, wv = tid >> 6;  // 8 waves
  int wm = wv >> 1, wn = wv & 1;       // 4 x 2
  int lr = lane & 15, lg = lane >> 4;
  // XCD-aware bijective swizzle (nwg % 8 == 0 for all our grids)
  int nwg = gridDim.x * gridDim.y;
  int flat = blockIdx.y * gridDim.x + blockIdx.x;
  int swz = (flat & 7) * (nwg >> 3) + (flat >> 3);
  int bx = swz % gridDim.x, by = swz / gridDim.x;
  int m0 = by * 256, n0 = bx * 128;
  int srow8 = lane >> 3;
  int gcol = ((lane & 7) * 8) ^ (srow8 << 3);  // inverse-swizzled source col
  int nt = K >> 6;

  const ushort* Abase = A + (size_t)m0 * K;
  const ushort* Bbase = Bt + (size_t)n0 * K;

  auto stageA = [&](int slot, int t, int p) {
    int r0 = (wv * 4 + p) * 8;
    gload_lds16(&Abase[(size_t)(r0 + srow8) * K + t * 64 + gcol], &As[slot][r0][0]);
  };
  auto stageB = [&](int slot, int t, int p) {
    int r0 = (wv * 2 + p) * 8;
    gload_lds16(&Bbase[(size_t)(r0 + srow8) * K + t * 64 + gcol], &Bs[slot][r0][0]);
  };

  // prologue: tiles 0 and 1 in flight (12 loads/thread)
  stageA(0, 0, 0); stageA(0, 0, 1); stageB(0, 0, 0);
  stageA(0, 0, 2); stageA(0, 0, 3); stageB(0, 0, 1);
  stageA(1, 1, 0); stageA(1, 1, 1); stageB(1, 1, 0);
  stageA(1, 1, 2); stageA(1, 1, 3); stageB(1, 1, 1);

  f32x4 acc[4][4] = {};
  int arow[4], brow[4], aswz[4], bswz[4];
#pragma unroll
  for (int i = 0; i < 4; ++i) {
    arow[i] = wm * 64 + i * 16 + lr;
    aswz[i] = (arow[i] & 7) << 3;
    brow[i] = wn * 64 + i * 16 + lr;
    bswz[i] = (brow[i] & 7) << 3;
  }

  for (int t = 0; t < nt; ++t) {
    int cur = t % 3, pf = (t + 2) % 3;
    if (t + 1 < nt) {
      asm volatile("s_waitcnt vmcnt(6)" ::: "memory");  // tile t done; t+1 in flight
    } else {
      asm volatile("s_waitcnt vmcnt(0)" ::: "memory");  // last tile: drain
    }
    __builtin_amdgcn_s_barrier();  // all waves' t-loads visible; slot pf vacated
    bool do_pf = (t + 2) < nt;
    // ---- phase A: ks = 0 ----
    {
      s16x8 a[4], b[4];
#pragma unroll
      for (int i = 0; i < 4; ++i) a[i] = *(const s16x8*)&As[cur][arow[i]][(lg * 8) ^ aswz[i]];
#pragma unroll
      for (int j = 0; j < 4; ++j) b[j] = *(const s16x8*)&Bs[cur][brow[j]][(lg * 8) ^ bswz[j]];
      if (do_pf) { stageA(pf, t + 2, 0); stageA(pf, t + 2, 1); stageB(pf, t + 2, 0); }
      __builtin_amdgcn_s_setprio(1);
#pragma unroll
      for (int i = 0; i < 4; ++i)
#pragma unroll
        for (int j = 0; j < 4; ++j)
          acc[i][j] = __builtin_amdgcn_mfma_f32_16x16x32_bf16(a[i], b[j], acc[i][j], 0, 0, 0);
      __builtin_amdgcn_s_setprio(0);
    }
    // ---- phase B: ks = 1 ----
    {
      s16x8 a[4], b[4];
#pragma unroll
      for (int i = 0; i < 4; ++i) a[i] = *(const s16x8*)&As[cur][arow[i]][(32 + lg * 8) ^ aswz[i]];
#pragma unroll
      for (int j = 0; j < 4; ++j) b[j] = *(const s16x8*)&Bs[cur][brow[j]][(32 + lg * 8) ^ bswz[j]];
      if (do_pf) { stageA(pf, t + 2, 2); stageA(pf, t + 2, 3); stageB(pf, t + 2, 1); }
      __builtin_amdgcn_s_setprio(1);
#pragma unroll
      for (int i = 0; i < 4; ++i)
#pragma unroll
        for (int j = 0; j < 4; ++j)
          acc[i][j] = __builtin_amdgcn_mfma_f32_16x16x32_bf16(a[i], b[j], acc[i][j], 0, 0, 0);
      __builtin_amdgcn_s_setprio(0);
    }
  }
  // ---- epilogue: C write ----
#pragma unroll
  for (int i = 0; i < 4; ++i)
#pragma unroll
    for (int j = 0; j < 4; ++j) {
      int row = m0 + wm * 64 + i * 16 + lg * 4;
      int col = n0 + wn * 64 + j * 16 + lr;
#pragma unroll
      for (int r = 0; r < 4; ++r) {
        float v = acc[i][j][r];
        if (OUTF32)
          reinterpret_cast<float*>(Cp)[(size_t)(row + r) * N + col] = v;
        else
          reinterpret_cast<ushort*>(Cp)[(size_t)(row + r) * N + col] = f2bf(v);
      }
    }
}

// ---------------- causal GQA flash attention ----------------
// block: 128 q-rows, 4 waves x 32 q-rows; 64-wide K/V tiles; dbuf K/V via
// global_load_lds + counted vmcnt(8). SWAPPED QK^T: sacc = mfma(K,Q) gives
// lane P^T[q=lane&15][k=16fp+4lg+r] -> in-lane row reductions (2 shfl),
// packed b64 P-writes. Base-2 online softmax, defer-max THR=8.
__global__ __launch_bounds__(256, 2) void attn_kernel(const ushort* __restrict__ Q,
                                                      const ushort* __restrict__ Kn,
                                                      const ushort* __restrict__ Vt,
                                                      ushort* __restrict__ AO) {
  __shared__ ushort Ks[2][64][128];   // 32 KB
  __shared__ ushort Vs[2][128][64];   // 32 KB
  __shared__ ushort Ps[4][32][64];    // 16 KB
  int bx = blockIdx.x;
  int g = bx >> 5, bh = bx & 31;
  int qt = (g < 8) ? (15 - g) : (g - 8);  // pair long+short on each CU
  int b = bh >> 4, h = bh & 15, kvh = h >> 2;
  int q0 = qt * 128;
  int nt = 2 * qt + 2;
  int tid = threadIdx.x, lane = tid & 63, w = tid >> 6;
  int lr = lane & 15, lg = lane >> 4;

  // staging geometry
  int ksrow = lane >> 4;           // K: 4 rows (256B) per 1KB chunk
  int kscol = (lane & 15) * 8;
  int vsrow = lane >> 3;           // V: 8 rows (128B) per 1KB chunk
  int vscol = (lane & 7) * 8;

  auto stage = [&](int c, int t) {
    int p0 = t * 64;
#pragma unroll
    for (int p = 0; p < 4; ++p) {
      int r0 = w * 16 + p * 4;
      int row = r0 + ksrow;
      int gc = kscol ^ ((row & 7) << 3);
      gload_lds16(&Kn[(size_t)(b * 2048 + p0 + row) * 512 + kvh * 128 + gc], &Ks[c][r0][0]);
    }
#pragma unroll
    for (int p = 0; p < 4; ++p) {
      int r0 = w * 32 + p * 8;
      int row = r0 + vsrow;
      int gc = vscol ^ ((row & 7) << 3);
      gload_lds16(&Vt[(size_t)((b * 4 + kvh) * 128 + row) * 2048 + p0 + gc], &Vs[c][r0][0]);
    }
  };

  stage(0, 0);  // prologue: tile 0 in flight

  // Q fragments in registers (rows w*32 + qa*16 + lr)
  s16x8 qf[2][4];
#pragma unroll
  for (int qa = 0; qa < 2; ++qa) {
    const ushort* qp = &Q[(size_t)(b * 2048 + q0 + w * 32 + qa * 16 + lr) * 2048 + h * 128];
#pragma unroll
    for (int ks = 0; ks < 4; ++ks) qf[qa][ks] = *(const s16x8*)&qp[ks * 32 + lg * 8];
  }

  f32x4 O[2][8] = {};
  float mrow[2] = {-1e30f, -1e30f};  // per-lane scalar: row q = qa*16 + (lane&15)
  float lrow[2] = {0.f, 0.f};

  for (int t = 0; t < nt; ++t) {
    int c = t & 1;
    if (t + 1 < nt) {
      stage(c ^ 1, t + 1);                               // prefetch next tile
      asm volatile("s_waitcnt vmcnt(8)" ::: "memory");   // tile t's 8 loads done
    } else {
      asm volatile("s_waitcnt vmcnt(0)" ::: "memory");
    }
    __builtin_amdgcn_s_barrier();                        // (a) tile t visible

    bool skip = (t == 2 * qt + 1) && (w < 2);            // fully-masked wave-tile
    if (!skip) {
      // SWAPPED: sacc[qa][fp] = S^T tile: lane holds q=lane&15, k=fp*16+lg*4+r
      f32x4 sacc[2][4] = {};
      __builtin_amdgcn_s_setprio(1);
#pragma unroll
      for (int ks = 0; ks < 4; ++ks) {
        s16x8 bk[4];
#pragma unroll
        for (int fp = 0; fp < 4; ++fp) {
          int kr = fp * 16 + lr;
          bk[fp] = *(const s16x8*)&Ks[c][kr][(ks * 32 + lg * 8) ^ ((kr & 7) << 3)];
        }
#pragma unroll
        for (int qa = 0; qa < 2; ++qa)
#pragma unroll
          for (int fp = 0; fp < 4; ++fp)
            sacc[qa][fp] = __builtin_amdgcn_mfma_f32_16x16x32_bf16(bk[fp], qf[qa][ks], sacc[qa][fp], 0, 0, 0);
      }
      __builtin_amdgcn_s_setprio(0);

      // causal mask (only tiles straddling the diagonal)
      if (t >= 2 * qt) {
        int p0 = t * 64;
#pragma unroll
        for (int qa = 0; qa < 2; ++qa)
#pragma unroll
          for (int fp = 0; fp < 4; ++fp)
#pragma unroll
            for (int r = 0; r < 4; ++r) {
              int qg = q0 + w * 32 + qa * 16 + lr;
              int pg = p0 + fp * 16 + lg * 4 + r;
              if (pg > qg) sacc[qa][fp][r] = -1e30f;
            }
      }

      // row max: in-lane over 16, then xor-16/32 across lg groups
      float pm[2];
#pragma unroll
      for (int qa = 0; qa < 2; ++qa) {
        float m01 = fmaxf(fmaxf(sacc[qa][0][0], sacc[qa][0][1]), fmaxf(sacc[qa][0][2], sacc[qa][0][3]));
#pragma unroll
        for (int fp = 1; fp < 4; ++fp)
          m01 = fmaxf(m01, fmaxf(fmaxf(sacc[qa][fp][0], sacc[qa][fp][1]),
                                 fmaxf(sacc[qa][fp][2], sacc[qa][fp][3])));
        m01 = fmaxf(m01, __shfl_xor(m01, 16));
        m01 = fmaxf(m01, __shfl_xor(m01, 32));
        pm[qa] = m01;
      }
      // defer-max (log2 domain, THR=8)
      bool need = (pm[0] > mrow[0] + 8.0f) | (pm[1] > mrow[1] + 8.0f);
      if (__any((int)need)) {
        float fsc[2];
#pragma unroll
        for (int qa = 0; qa < 2; ++qa) {
          float mn = fmaxf(mrow[qa], pm[qa]);
          fsc[qa] = __builtin_amdgcn_exp2f(mrow[qa] - mn);
          mrow[qa] = mn;
          lrow[qa] *= fsc[qa];
        }
        // redistribute to O layout (q = lg*4 + r)
#pragma unroll
        for (int qa = 0; qa < 2; ++qa) {
          float fo[4];
#pragma unroll
          for (int r = 0; r < 4; ++r) fo[r] = __shfl(fsc[qa], lg * 4 + r);
#pragma unroll
          for (int fn = 0; fn < 8; ++fn)
#pragma unroll
            for (int r = 0; r < 4; ++r) O[qa][fn][r] *= fo[r];
        }
      }
      // exp2 + packed P write + row sum
      float ls[2] = {0.f, 0.f};
#pragma unroll
      for (int qa = 0; qa < 2; ++qa) {
        int prow = qa * 16 + lr;
        int swz = (lr & 7) << 3;
#pragma unroll
        for (int fp = 0; fp < 4; ++fp) {
          float e0 = __builtin_amdgcn_exp2f(sacc[qa][fp][0] - mrow[qa]);
          float e1 = __builtin_amdgcn_exp2f(sacc[qa][fp][1] - mrow[qa]);
          float e2 = __builtin_amdgcn_exp2f(sacc[qa][fp][2] - mrow[qa]);
          float e3 = __builtin_amdgcn_exp2f(sacc[qa][fp][3] - mrow[qa]);
          ls[qa] += (e0 + e1) + (e2 + e3);
          unsigned lo = (unsigned)f2bf(e0) | ((unsigned)f2bf(e1) << 16);
          unsigned hi = (unsigned)f2bf(e2) | ((unsigned)f2bf(e3) << 16);
          uint2 pk; pk.x = lo; pk.y = hi;
          *reinterpret_cast<uint2*>(&Ps[w][prow][(fp * 16 + lg * 4) ^ swz]) = pk;
        }
        ls[qa] += __shfl_xor(ls[qa], 16);
        ls[qa] += __shfl_xor(ls[qa], 32);
        lrow[qa] += ls[qa];
      }
      __builtin_amdgcn_s_setprio(1);
#pragma unroll
      for (int ks2 = 0; ks2 < 2; ++ks2) {
        s16x8 ap[2];
#pragma unroll
        for (int qa = 0; qa < 2; ++qa) {
          int prow = qa * 16 + lr;
          ap[qa] = *(const s16x8*)&Ps[w][prow][(ks2 * 32 + lg * 8) ^ ((lr & 7) << 3)];
        }
#pragma unroll
        for (int fn = 0; fn < 8; ++fn) {
          int vrow = fn * 16 + lr;
          s16x8 bv = *(const s16x8*)&Vs[c][vrow][(ks2 * 32 + lg * 8) ^ ((vrow & 7) << 3)];
#pragma unroll
          for (int qa = 0; qa < 2; ++qa)
            O[qa][fn] = __builtin_amdgcn_mfma_f32_16x16x32_bf16(ap[qa], bv, O[qa][fn], 0, 0, 0);
        }
      }
      __builtin_amdgcn_s_setprio(0);
    }
    __builtin_amdgcn_s_barrier();  // (b) all waves done reading buf c
  }

  // epilogue: O rows are q = lg*4+r; lrow lives at lane&15 == q -> shfl remap
#pragma unroll
  for (int qa = 0; qa < 2; ++qa) {
    float inv = 1.0f / lrow[qa];
    float invq[4];
#pragma unroll
    for (int r = 0; r < 4; ++r) invq[r] = __shfl(inv, lg * 4 + r);
#pragma unroll
    for (int fn = 0; fn < 8; ++fn)
#pragma unroll
      for (int r = 0; r < 4; ++r) {
        size_t idx = (size_t)(b * 2048 + q0 + w * 32 + qa * 16 + lg * 4 + r) * 2048 +
                     h * 128 + fn * 16 + lr;
        AO[idx] = f2bf(O[qa][fn][r] * invq[r]);
      }
  }
}

extern "C" void kernel_launch(void* const* d_in, const int* in_sizes, int n_in,
                              void* d_out, int out_size, void* d_ws, size_t ws_size,
                              hipStream_t stream) {
  (void)in_sizes; (void)n_in; (void)out_size; (void)ws_size;
  const float* x = (const float*)d_in[0];
  const float* Wq = (const float*)d_in[1];
  const float* Wk = (const float*)d_in[2];
  const float* Wv = (const float*)d_in[3];
  const float* Wo = (const float*)d_in[4];
  const float* qw = (const float*)d_in[5];
  const float* kw = (const float*)d_in[6];
  float* out = (float*)d_out;

  char* ws = (char*)d_ws;
  size_t off = 0;
  auto alloc = [&](size_t bytes) {
    void* p = ws + off;
    off += (bytes + 255) & ~(size_t)255;
    return p;
  };
  ushort* xb = (ushort*)alloc((size_t)4096 * 2048 * 2);
  ushort* WqkvT = (ushort*)alloc((size_t)3072 * 2048 * 2);
  ushort* WoT = (ushort*)alloc((size_t)2048 * 2048 * 2);
  ushort* QKVraw = (ushort*)alloc((size_t)4096 * 3072 * 2);
  ushort* Qn = (ushort*)alloc((size_t)4096 * 2048 * 2);
  ushort* Kb = (ushort*)alloc((size_t)4096 * 512 * 2);
  ushort* Vt = (ushort*)alloc((size_t)4096 * 512 * 2);
  ushort* AO = (ushort*)alloc((size_t)4096 * 2048 * 2);
  float* rc = (float*)alloc((size_t)2048 * 64 * 4);
  float* rs = (float*)alloc((size_t)2048 * 64 * 4);

  // log2(e) / sqrt(128): fold softmax scale + base-2 conversion into Q
  const float QSCALE = 0.12751744f;

  cast_bf16_kernel<<<2048, 256, 0, stream>>>(x, xb, 4096 * 2048 / 4);
  cast_transpose_kernel<<<dim3(64, 64), 256, 0, stream>>>(Wq, WqkvT, 2048, 2048);
  cast_transpose_kernel<<<dim3(16, 64), 256, 0, stream>>>(Wk, WqkvT + (size_t)2048 * 2048, 2048, 512);
  cast_transpose_kernel<<<dim3(16, 64), 256, 0, stream>>>(Wv, WqkvT + (size_t)2560 * 2048, 2048, 512);
  cast_transpose_kernel<<<dim3(64, 64), 256, 0, stream>>>(Wo, WoT, 2048, 2048);
  rope_table_kernel<<<2048, 64, 0, stream>>>(rc, rs);
  gemm256_kernel<false><<<dim3(24, 16), 512, 0, stream>>>(xb, WqkvT, QKVraw, 4096, 3072, 2048);
  norm_rope_kernel<<<16384, 256, 0, stream>>>(QKVraw, qw, Qn, rc, rs, 16, 0, 2048, QSCALE);
  norm_rope_kernel<<<4096, 256, 0, stream>>>(QKVraw, kw, Kb, rc, rs, 4, 2048, 512, 1.0f);
  v_transpose_kernel<<<256, 256, 0, stream>>>(QKVraw, Vt);
  attn_kernel<<<512, 256, 0, stream>>>(Qn, Kb, Vt, AO);
  gemm256_kernel<true><<<dim3(16, 16), 512, 0, stream>>>(AO, WoT, out, 4096, 2048, 2048);
}

// Round 6
// 209.596 us; speedup vs baseline: 1.7135x; 1.0603x over previous
//
#include <hip/hip_runtime.h>

typedef __attribute__((ext_vector_type(4))) float f32x4;
typedef __attribute__((ext_vector_type(8))) short s16x8;

struct alignas(8) us4 { ushort x, y, z, w; };

__device__ __forceinline__ ushort f2bf(float f) {
  unsigned u = __builtin_bit_cast(unsigned, f);
  u += 0x7fffu + ((u >> 16) & 1u);
  return (ushort)(u >> 16);
}
__device__ __forceinline__ float bf2f(ushort h) {
  unsigned u = ((unsigned)h) << 16;
  return __builtin_bit_cast(float, u);
}

__device__ __forceinline__ void gload_lds16(const ushort* g, ushort* l) {
  __builtin_amdgcn_global_load_lds((const __attribute__((address_space(1))) unsigned int*)g,
                                   (__attribute__((address_space(3))) unsigned int*)l, 16, 0, 0);
}

// ---------------- cast fp32 -> bf16 (vectorized) ----------------
__global__ __launch_bounds__(256) void cast_bf16_kernel(const float* __restrict__ in,
                                                        ushort* __restrict__ out, int n4) {
  int i = blockIdx.x * 256 + threadIdx.x;
  int stride = gridDim.x * 256;
  for (; i < n4; i += stride) {
    float4 v = reinterpret_cast<const float4*>(in)[i];
    us4 o;
    o.x = f2bf(v.x); o.y = f2bf(v.y); o.z = f2bf(v.z); o.w = f2bf(v.w);
    reinterpret_cast<us4*>(out)[i] = o;
  }
}

// ---------------- all 4 weight transposes in one launch (z-indexed) ----------------
__global__ __launch_bounds__(256) void wtrans_kernel(const float* __restrict__ Wq,
                                                     const float* __restrict__ Wk,
                                                     const float* __restrict__ Wv,
                                                     const float* __restrict__ Wo,
                                                     ushort* __restrict__ WqkvT,
                                                     ushort* __restrict__ WoT) {
  __shared__ float tile[32][33];
  int z = blockIdx.z;
  const float* src;
  ushort* dst;
  int C;
  if (z == 0) { src = Wq; dst = WqkvT; C = 2048; }
  else if (z == 1) { src = Wk; dst = WqkvT + (size_t)2048 * 2048; C = 512; }
  else if (z == 2) { src = Wv; dst = WqkvT + (size_t)2560 * 2048; C = 512; }
  else { src = Wo; dst = WoT; C = 2048; }
  int c0 = blockIdx.x * 32, r0 = blockIdx.y * 32;
  if (c0 >= C) return;
  int tx = threadIdx.x & 31, ty = threadIdx.x >> 5;
#pragma unroll
  for (int i = 0; i < 4; ++i)
    tile[ty + i * 8][tx] = src[(size_t)(r0 + ty + i * 8) * C + c0 + tx];
  __syncthreads();
#pragma unroll
  for (int i = 0; i < 4; ++i)
    dst[(size_t)(c0 + ty + i * 8) * 2048 + r0 + tx] = f2bf(tile[tx][ty + i * 8]);
}

// ---------------- RoPE tables: cos/sin[t][j], j<64 ----------------
__global__ void rope_table_kernel(float* __restrict__ rc, float* __restrict__ rs) {
  int t = blockIdx.x, j = threadIdx.x;  // 64 threads
  float inv = expf(-(float)j * (9.210340371976184f / 64.0f));
  float ang = (float)t * inv;
  float s, c;
  sincosf(ang, &s, &c);
  rc[t * 64 + j] = c;
  rs[t * 64 + j] = s;
}

// ---------------- fused per-head RMSNorm + RoPE (K only now) ----------------
__global__ __launch_bounds__(256) void norm_rope_kernel(
    const ushort* __restrict__ qkv, const float* __restrict__ w,
    ushort* __restrict__ out, const float* __restrict__ rc, const float* __restrict__ rs,
    int nheads, int col_off, int out_stride, float oscale) {
  int wv = threadIdx.x >> 6, lane = threadIdx.x & 63;
  int row = blockIdx.x * 4 + wv;
  int token = row / nheads, head = row % nheads;
  int t = token & 2047;  // token % S
  const ushort* p = qkv + (size_t)token * 3072 + col_off + head * 128;
  float x1 = bf2f(p[lane]), x2 = bf2f(p[lane + 64]);
  float ss = x1 * x1 + x2 * x2;
#pragma unroll
  for (int m = 32; m > 0; m >>= 1) ss += __shfl_xor(ss, m);
  float r = rsqrtf(ss * (1.0f / 128.0f) + 1e-6f);
  float xn1 = x1 * r * w[lane], xn2 = x2 * r * w[lane + 64];
  float c = rc[t * 64 + lane], s = rs[t * 64 + lane];
  ushort* o = out + (size_t)token * out_stride + head * 128;
  o[lane] = f2bf((xn1 * c - xn2 * s) * oscale);
  o[lane + 64] = f2bf((xn2 * c + xn1 * s) * oscale);
}

// ---------------- V transpose: QKV slab -> Vt[b][kv][d][s] ----------------
__global__ __launch_bounds__(256) void v_transpose_kernel(const ushort* __restrict__ qkv,
                                                          ushort* __restrict__ vt) {
  __shared__ ushort tile[64][136];
  int bx = blockIdx.x;
  int st = bx & 31, kvh = (bx >> 5) & 3, b = bx >> 7;
  int s0 = st * 64;
  int tid = threadIdx.x;
#pragma unroll
  for (int p = 0; p < 4; ++p) {
    int idx = p * 2048 + tid * 8;
    int s = idx >> 7, d = idx & 127;
    *(s16x8*)&tile[s][d] =
        *(const s16x8*)&qkv[(size_t)(b * 2048 + s0 + s) * 3072 + 2560 + kvh * 128 + d];
  }
  __syncthreads();
#pragma unroll
  for (int p = 0; p < 4; ++p) {
    int idx = p * 2048 + tid * 8;
    int d = idx >> 6, s = idx & 63;
    s16x8 v;
#pragma unroll
    for (int u = 0; u < 8; ++u) v[u] = (short)tile[s + u][d];
    *(s16x8*)&vt[(size_t)((b * 4 + kvh) * 128 + d) * 2048 + s0 + s] = v;
  }
}

// ---------------- bf16 MFMA GEMM, 256x128 tile, 3-slot pipelined ----------------
template <bool OUTF32>
__global__ __launch_bounds__(512, 2) void gemm256_kernel(const ushort* __restrict__ A,
                                                         const ushort* __restrict__ Bt,
                                                         void* __restrict__ Cp,
                                                         int M, int N, int K) {
  __shared__ ushort As[3][256][64];  // 96 KB
  __shared__ ushort Bs[3][128][64];  // 48 KB
  int tid = threadIdx.x;
  int lane = tid & 63, wv = tid >> 6;  // 8 waves
  int wm = wv >> 1, wn = wv & 1;       // 4 x 2
  int lr = lane & 15, lg = lane >> 4;
  int nwg = gridDim.x * gridDim.y;
  int flat = blockIdx.y * gridDim.x + blockIdx.x;
  int swz = (flat & 7) * (nwg >> 3) + (flat >> 3);
  int bx = swz % gridDim.x, by = swz / gridDim.x;
  int m0 = by * 256, n0 = bx * 128;
  int srow8 = lane >> 3;
  int gcol = ((lane & 7) * 8) ^ (srow8 << 3);
  int nt = K >> 6;

  const ushort* Abase = A + (size_t)m0 * K;
  const ushort* Bbase = Bt + (size_t)n0 * K;

  auto stageA = [&](int slot, int t, int p) {
    int r0 = (wv * 4 + p) * 8;
    gload_lds16(&Abase[(size_t)(r0 + srow8) * K + t * 64 + gcol], &As[slot][r0][0]);
  };
  auto stageB = [&](int slot, int t, int p) {
    int r0 = (wv * 2 + p) * 8;
    gload_lds16(&Bbase[(size_t)(r0 + srow8) * K + t * 64 + gcol], &Bs[slot][r0][0]);
  };

  stageA(0, 0, 0); stageA(0, 0, 1); stageB(0, 0, 0);
  stageA(0, 0, 2); stageA(0, 0, 3); stageB(0, 0, 1);
  stageA(1, 1, 0); stageA(1, 1, 1); stageB(1, 1, 0);
  stageA(1, 1, 2); stageA(1, 1, 3); stageB(1, 1, 1);

  f32x4 acc[4][4] = {};
  int arow[4], brow[4], aswz[4], bswz[4];
#pragma unroll
  for (int i = 0; i < 4; ++i) {
    arow[i] = wm * 64 + i * 16 + lr;
    aswz[i] = (arow[i] & 7) << 3;
    brow[i] = wn * 64 + i * 16 + lr;
    bswz[i] = (brow[i] & 7) << 3;
  }

  for (int t = 0; t < nt; ++t) {
    int cur = t % 3, pf = (t + 2) % 3;
    if (t + 1 < nt) {
      asm volatile("s_waitcnt vmcnt(6)" ::: "memory");
    } else {
      asm volatile("s_waitcnt vmcnt(0)" ::: "memory");
    }
    __builtin_amdgcn_s_barrier();
    bool do_pf = (t + 2) < nt;
    {
      s16x8 a[4], b[4];
#pragma unroll
      for (int i = 0; i < 4; ++i) a[i] = *(const s16x8*)&As[cur][arow[i]][(lg * 8) ^ aswz[i]];
#pragma unroll
      for (int j = 0; j < 4; ++j) b[j] = *(const s16x8*)&Bs[cur][brow[j]][(lg * 8) ^ bswz[j]];
      if (do_pf) { stageA(pf, t + 2, 0); stageA(pf, t + 2, 1); stageB(pf, t + 2, 0); }
      __builtin_amdgcn_s_setprio(1);
#pragma unroll
      for (int i = 0; i < 4; ++i)
#pragma unroll
        for (int j = 0; j < 4; ++j)
          acc[i][j] = __builtin_amdgcn_mfma_f32_16x16x32_bf16(a[i], b[j], acc[i][j], 0, 0, 0);
      __builtin_amdgcn_s_setprio(0);
    }
    {
      s16x8 a[4], b[4];
#pragma unroll
      for (int i = 0; i < 4; ++i) a[i] = *(const s16x8*)&As[cur][arow[i]][(32 + lg * 8) ^ aswz[i]];
#pragma unroll
      for (int j = 0; j < 4; ++j) b[j] = *(const s16x8*)&Bs[cur][brow[j]][(32 + lg * 8) ^ bswz[j]];
      if (do_pf) { stageA(pf, t + 2, 2); stageA(pf, t + 2, 3); stageB(pf, t + 2, 1); }
      __builtin_amdgcn_s_setprio(1);
#pragma unroll
      for (int i = 0; i < 4; ++i)
#pragma unroll
        for (int j = 0; j < 4; ++j)
          acc[i][j] = __builtin_amdgcn_mfma_f32_16x16x32_bf16(a[i], b[j], acc[i][j], 0, 0, 0);
      __builtin_amdgcn_s_setprio(0);
    }
  }
#pragma unroll
  for (int i = 0; i < 4; ++i)
#pragma unroll
    for (int j = 0; j < 4; ++j) {
      int row = m0 + wm * 64 + i * 16 + lg * 4;
      int col = n0 + wn * 64 + j * 16 + lr;
#pragma unroll
      for (int r = 0; r < 4; ++r) {
        float v = acc[i][j][r];
        if (OUTF32)
          reinterpret_cast<float*>(Cp)[(size_t)(row + r) * N + col] = v;
        else
          reinterpret_cast<ushort*>(Cp)[(size_t)(row + r) * N + col] = f2bf(v);
      }
    }
}

// ---------------- causal GQA flash attention, software-pipelined ----------------
// 128 q-rows/block, 4 waves x 32 q; 64-wide K/V tiles. Per iter t:
//   vmcnt(0); barrier; issue V(t)+K(t+2); QK(t+1) [MFMA] || softmax(t) [VALU];
//   vmcnt(K-outstanding); barrier; PV(t).
// K: 3-slot LDS rotation; V: single buffer staged late. Q norm+rope+scale
// fused in-register. Swapped QK^T; base-2 online softmax; defer-max THR=8.
__global__ __launch_bounds__(256, 2) void attn_kernel(const ushort* __restrict__ QKV,
                                                      const ushort* __restrict__ Kn,
                                                      const ushort* __restrict__ Vt,
                                                      ushort* __restrict__ AO,
                                                      const float* __restrict__ rc,
                                                      const float* __restrict__ rs,
                                                      const float* __restrict__ qw) {
  __shared__ ushort Ks[3][64][128];   // 48 KB
  __shared__ ushort Vs[128][64];      // 16 KB
  __shared__ ushort Ps[4][32][64];    // 16 KB
  int bxi = blockIdx.x;
  int g = bxi >> 5, bh = bxi & 31;
  int qt = (g < 8) ? (15 - g) : (g - 8);  // pair long+short
  int b = bh >> 4, h = bh & 15, kvh = h >> 2;
  int q0 = qt * 128;
  int nt = 2 * qt + 2;  // always even
  int tid = threadIdx.x, lane = tid & 63, w = tid >> 6;
  int lr = lane & 15, lg = lane >> 4;

  int ksrow = lane >> 4, kscol = (lane & 15) * 8;
  int vsrow = lane >> 3, vscol = (lane & 7) * 8;

  // ---- Q build: inline RMSNorm + RoPE + QSCALE ----
  const float QSCALE = 0.12751744f;  // log2e / sqrt(128)
  s16x8 qf[2][4];
#pragma unroll
  for (int qa = 0; qa < 2; ++qa) {
    int t_tok = q0 + w * 32 + qa * 16 + lr;
    const ushort* qp = QKV + (size_t)(b * 2048 + t_tok) * 3072 + h * 128;
    float xv[4][8];
    float ss = 0.f;
#pragma unroll
    for (int ks = 0; ks < 4; ++ks) {
      s16x8 raw = *(const s16x8*)&qp[ks * 32 + lg * 8];
#pragma unroll
      for (int j = 0; j < 8; ++j) {
        float x = bf2f((ushort)raw[j]);
        xv[ks][j] = x;
        ss += x * x;
      }
    }
    ss += __shfl_xor(ss, 16);
    ss += __shfl_xor(ss, 32);
    float rms = rsqrtf(ss * (1.0f / 128.0f) + 1e-6f);
#pragma unroll
    for (int ks = 0; ks < 2; ++ks) {
      int dbase = ks * 32 + lg * 8;
      float cc[8], sn[8], w1[8], w2[8];
      *(float4*)&cc[0] = *(const float4*)&rc[(size_t)t_tok * 64 + dbase];
      *(float4*)&cc[4] = *(const float4*)&rc[(size_t)t_tok * 64 + dbase + 4];
      *(float4*)&sn[0] = *(const float4*)&rs[(size_t)t_tok * 64 + dbase];
      *(float4*)&sn[4] = *(const float4*)&rs[(size_t)t_tok * 64 + dbase + 4];
      *(float4*)&w1[0] = *(const float4*)&qw[dbase];
      *(float4*)&w1[4] = *(const float4*)&qw[dbase + 4];
      *(float4*)&w2[0] = *(const float4*)&qw[dbase + 64];
      *(float4*)&w2[4] = *(const float4*)&qw[dbase + 68];
      s16x8 o1, o2;
#pragma unroll
      for (int j = 0; j < 8; ++j) {
        float x1 = xv[ks][j] * rms * w1[j];
        float x2 = xv[ks + 2][j] * rms * w2[j];
        o1[j] = (short)f2bf((x1 * cc[j] - x2 * sn[j]) * QSCALE);
        o2[j] = (short)f2bf((x2 * cc[j] + x1 * sn[j]) * QSCALE);
      }
      qf[qa][ks] = o1;
      qf[qa][ks + 2] = o2;
    }
  }
  // fence: Q's ordinary loads fully drained before counted gload_lds stream
  asm volatile("s_waitcnt vmcnt(0)" ::: "memory");

  auto stageK = [&](int slot, int t) {
    int p0 = t * 64;
#pragma unroll
    for (int p = 0; p < 4; ++p) {
      int r0 = w * 16 + p * 4;
      int row = r0 + ksrow;
      int gc = kscol ^ ((row & 7) << 3);
      gload_lds16(&Kn[(size_t)(b * 2048 + p0 + row) * 512 + kvh * 128 + gc], &Ks[slot][r0][0]);
    }
  };
  auto stageV = [&](int t) {
    int p0 = t * 64;
#pragma unroll
    for (int p = 0; p < 4; ++p) {
      int r0 = w * 32 + p * 8;
      int row = r0 + vsrow;
      int gc = vscol ^ ((row & 7) << 3);
      gload_lds16(&Vt[(size_t)((b * 4 + kvh) * 128 + row) * 2048 + p0 + gc], &Vs[r0][0]);
    }
  };

  // prologue: K(0), K(1) in flight; QK(0)
  stageK(0, 0);
  stageK(1, 1);
  asm volatile("s_waitcnt vmcnt(4)" ::: "memory");  // K(0) landed
  __builtin_amdgcn_s_barrier();

  f32x4 sacc0[2][4] = {}, sacc1[2][4];
  __builtin_amdgcn_s_setprio(1);
#pragma unroll
  for (int ks = 0; ks < 4; ++ks) {
    s16x8 bk[4];
#pragma unroll
    for (int fp = 0; fp < 4; ++fp) {
      int kr = fp * 16 + lr;
      bk[fp] = *(const s16x8*)&Ks[0][kr][(ks * 32 + lg * 8) ^ ((kr & 7) << 3)];
    }
#pragma unroll
    for (int qa = 0; qa < 2; ++qa)
#pragma unroll
      for (int fp = 0; fp < 4; ++fp)
        sacc0[qa][fp] = __builtin_amdgcn_mfma_f32_16x16x32_bf16(bk[fp], qf[qa][ks], sacc0[qa][fp], 0, 0, 0);
  }
  __builtin_amdgcn_s_setprio(0);

  f32x4 O[2][8] = {};
  float mrow[2] = {-1e30f, -1e30f}, lrow[2] = {0.f, 0.f};

#define ATTN_ITER(T, CUR, NXT)                                                        \
  {                                                                                   \
    const int t_ = (T);                                                               \
    asm volatile("s_waitcnt vmcnt(0)" ::: "memory");                                  \
    __builtin_amdgcn_s_barrier();                                                     \
    stageV(t_);                                                                       \
    const bool pfK_ = (t_ + 2) < nt;                                                  \
    if (pfK_) stageK((t_ + 2) % 3, t_ + 2);                                           \
    if (t_ + 1 < nt) {                                                                \
      int sl_ = (t_ + 1) % 3;                                                         \
      _Pragma("unroll") for (int qa = 0; qa < 2; ++qa)                                \
          _Pragma("unroll") for (int fp = 0; fp < 4; ++fp)                            \
              NXT[qa][fp] = (f32x4){0.f, 0.f, 0.f, 0.f};                              \
      __builtin_amdgcn_s_setprio(1);                                                  \
      _Pragma("unroll") for (int ks = 0; ks < 4; ++ks) {                              \
        s16x8 bk[4];                                                                  \
        _Pragma("unroll") for (int fp = 0; fp < 4; ++fp) {                            \
          int kr = fp * 16 + lr;                                                      \
          bk[fp] = *(const s16x8*)&Ks[sl_][kr][(ks * 32 + lg * 8) ^ ((kr & 7) << 3)]; \
        }                                                                             \
        _Pragma("unroll") for (int qa = 0; qa < 2; ++qa)                              \
            _Pragma("unroll") for (int fp = 0; fp < 4; ++fp)                          \
                NXT[qa][fp] = __builtin_amdgcn_mfma_f32_16x16x32_bf16(                \
                    bk[fp], qf[qa][ks], NXT[qa][fp], 0, 0, 0);                        \
      }                                                                               \
      __builtin_amdgcn_s_setprio(0);                                                  \
    }                                                                                 \
    if (t_ >= 2 * qt) {                                                               \
      int p0_ = t_ * 64;                                                              \
      _Pragma("unroll") for (int qa = 0; qa < 2; ++qa)                                \
          _Pragma("unroll") for (int fp = 0; fp < 4; ++fp)                            \
              _Pragma("unroll") for (int r = 0; r < 4; ++r) {                         \
        int qg = q0 + w * 32 + qa * 16 + lr;                                          \
        int pg = p0_ + fp * 16 + lg * 4 + r;                                          \
        if (pg > qg) CUR[qa][fp][r] = -1e30f;                                         \
      }                                                                               \
    }                                                                                 \
    float pm_[2];                                                                     \
    _Pragma("unroll") for (int qa = 0; qa < 2; ++qa) {                                \
      float m01 = fmaxf(fmaxf(CUR[qa][0][0], CUR[qa][0][1]),                          \
                        fmaxf(CUR[qa][0][2], CUR[qa][0][3]));                         \
      _Pragma("unroll") for (int fp = 1; fp < 4; ++fp)                                \
          m01 = fmaxf(m01, fmaxf(fmaxf(CUR[qa][fp][0], CUR[qa][fp][1]),               \
                                 fmaxf(CUR[qa][fp][2], CUR[qa][fp][3])));             \
      m01 = fmaxf(m01, __shfl_xor(m01, 16));                                          \
      m01 = fmaxf(m01, __shfl_xor(m01, 32));                                          \
      pm_[qa] = m01;                                                                  \
    }                                                                                 \
    bool need_ = (pm_[0] > mrow[0] + 8.0f) | (pm_[1] > mrow[1] + 8.0f);               \
    if (__any((int)need_)) {                                                          \
      float fsc_[2];                                                                  \
      _Pragma("unroll") for (int qa = 0; qa < 2; ++qa) {                              \
        float mn = fmaxf(mrow[qa], pm_[qa]);                                          \
        fsc_[qa] = __builtin_amdgcn_exp2f(mrow[qa] - mn);                             \
        mrow[qa] = mn;                                                                \
        lrow[qa] *= fsc_[qa];                                                         \
      }                                                                               \
      _Pragma("unroll") for (int qa = 0; qa < 2; ++qa) {                              \
        float fo_[4];                                                                 \
        _Pragma("unroll") for (int r = 0; r < 4; ++r)                                 \
            fo_[r] = __shfl(fsc_[qa], lg * 4 + r);                                    \
        _Pragma("unroll") for (int fn = 0; fn < 8; ++fn)                              \
            _Pragma("unroll") for (int r = 0; r < 4; ++r) O[qa][fn][r] *= fo_[r];     \
      }                                                                               \
    }                                                                                 \
    _Pragma("unroll") for (int qa = 0; qa < 2; ++qa) {                                \
      float ls_ = 0.f;                                                                \
      int prow = qa * 16 + lr;                                                        \
      int swz_ = (lr & 7) << 3;                                                       \
      _Pragma("unroll") for (int fp = 0; fp < 4; ++fp) {                              \
        float e0 = __builtin_amdgcn_exp2f(CUR[qa][fp][0] - mrow[qa]);                 \
        float e1 = __builtin_amdgcn_exp2f(CUR[qa][fp][1] - mrow[qa]);                 \
        float e2 = __builtin_amdgcn_exp2f(CUR[qa][fp][2] - mrow[qa]);                 \
        float e3 = __builtin_amdgcn_exp2f(CUR[qa][fp][3] - mrow[qa]);                 \
        ls_ += (e0 + e1) + (e2 + e3);                                                 \
        unsigned lo = (unsigned)f2bf(e0) | ((unsigned)f2bf(e1) << 16);                \
        unsigned hi = (unsigned)f2bf(e2) | ((unsigned)f2bf(e3) << 16);                \
        uint2 pk; pk.x = lo; pk.y = hi;                                               \
        *reinterpret_cast<uint2*>(&Ps[w][prow][(fp * 16 + lg * 4) ^ swz_]) = pk;      \
      }                                                                               \
      ls_ += __shfl_xor(ls_, 16);                                                     \
      ls_ += __shfl_xor(ls_, 32);                                                     \
      lrow[qa] += ls_;                                                                \
    }                                                                                 \
    if (pfK_) { asm volatile("s_waitcnt vmcnt(4)" ::: "memory"); }                    \
    else      { asm volatile("s_waitcnt vmcnt(0)" ::: "memory"); }                    \
    __builtin_amdgcn_s_barrier();                                                     \
    __builtin_amdgcn_s_setprio(1);                                                    \
    _Pragma("unroll") for (int ks2 = 0; ks2 < 2; ++ks2) {                             \
      s16x8 ap[2];                                                                    \
      _Pragma("unroll") for (int qa = 0; qa < 2; ++qa) {                              \
        int prow = qa * 16 + lr;                                                      \
        ap[qa] = *(const s16x8*)&Ps[w][prow][(ks2 * 32 + lg * 8) ^ ((lr & 7) << 3)];  \
      }                                                                               \
      _Pragma("unroll") for (int fn = 0; fn < 8; ++fn) {                              \
        int vrow = fn * 16 + lr;                                                      \
        s16x8 bv = *(const s16x8*)&Vs[vrow][(ks2 * 32 + lg * 8) ^ ((vrow & 7) << 3)]; \
        _Pragma("unroll") for (int qa = 0; qa < 2; ++qa)                              \
            O[qa][fn] = __builtin_amdgcn_mfma_f32_16x16x32_bf16(ap[qa], bv,           \
                                                                O[qa][fn], 0, 0, 0);  \
      }                                                                               \
    }                                                                                 \
    __builtin_amdgcn_s_setprio(0);                                                    \
  }

  for (int t = 0; t < nt; t += 2) {
    ATTN_ITER(t, sacc0, sacc1);
    ATTN_ITER(t + 1, sacc1, sacc0);
  }
#undef ATTN_ITER

  // epilogue: O rows are q = lg*4+r; lrow lives at lane&15 == q -> shfl remap
#pragma unroll
  for (int qa = 0; qa < 2; ++qa) {
    float inv = 1.0f / lrow[qa];
    float invq[4];
#pragma unroll
    for (int r = 0; r < 4; ++r) invq[r] = __shfl(inv, lg * 4 + r);
#pragma unroll
    for (int fn = 0; fn < 8; ++fn)
#pragma unroll
      for (int r = 0; r < 4; ++r) {
        size_t idx = (size_t)(b * 2048 + q0 + w * 32 + qa * 16 + lg * 4 + r) * 2048 +
                     h * 128 + fn * 16 + lr;
        AO[idx] = f2bf(O[qa][fn][r] * invq[r]);
      }
  }
}

extern "C" void kernel_launch(void* const* d_in, const int* in_sizes, int n_in,
                              void* d_out, int out_size, void* d_ws, size_t ws_size,
                              hipStream_t stream) {
  (void)in_sizes; (void)n_in; (void)out_size; (void)ws_size;
  const float* x = (const float*)d_in[0];
  const float* Wq = (const float*)d_in[1];
  const float* Wk = (const float*)d_in[2];
  const float* Wv = (const float*)d_in[3];
  const float* Wo = (const float*)d_in[4];
  const float* qw = (const float*)d_in[5];
  const float* kw = (const float*)d_in[6];
  float* out = (float*)d_out;

  char* ws = (char*)d_ws;
  size_t off = 0;
  auto alloc = [&](size_t bytes) {
    void* p = ws + off;
    off += (bytes + 255) & ~(size_t)255;
    return p;
  };
  ushort* xb = (ushort*)alloc((size_t)4096 * 2048 * 2);
  ushort* WqkvT = (ushort*)alloc((size_t)3072 * 2048 * 2);
  ushort* WoT = (ushort*)alloc((size_t)2048 * 2048 * 2);
  ushort* QKVraw = (ushort*)alloc((size_t)4096 * 3072 * 2);
  ushort* Kb = (ushort*)alloc((size_t)4096 * 512 * 2);
  ushort* Vt = (ushort*)alloc((size_t)4096 * 512 * 2);
  ushort* AO = (ushort*)alloc((size_t)4096 * 2048 * 2);
  float* rc = (float*)alloc((size_t)2048 * 64 * 4);
  float* rs = (float*)alloc((size_t)2048 * 64 * 4);

  cast_bf16_kernel<<<2048, 256, 0, stream>>>(x, xb, 4096 * 2048 / 4);
  wtrans_kernel<<<dim3(64, 64, 4), 256, 0, stream>>>(Wq, Wk, Wv, Wo, WqkvT, WoT);
  rope_table_kernel<<<2048, 64, 0, stream>>>(rc, rs);
  gemm256_kernel<false><<<dim3(24, 16), 512, 0, stream>>>(xb, WqkvT, QKVraw, 4096, 3072, 2048);
  norm_rope_kernel<<<4096, 256, 0, stream>>>(QKVraw, kw, Kb, rc, rs, 4, 2048, 512, 1.0f);
  v_transpose_kernel<<<256, 256, 0, stream>>>(QKVraw, Vt);
  attn_kernel<<<512, 256, 0, stream>>>(QKVraw, Kb, Vt, AO, rc, rs, qw);
  gemm256_kernel<true><<<dim3(16, 16), 512, 0, stream>>>(AO, WoT, out, 4096, 2048, 2048);
}

// Round 7
// 208.748 us; speedup vs baseline: 1.7204x; 1.0041x over previous
//
#include <hip/hip_runtime.h>

typedef __attribute__((ext_vector_type(4))) float f32x4;
typedef __attribute__((ext_vector_type(8))) short s16x8;

struct alignas(8) us4 { ushort x, y, z, w; };

__device__ __forceinline__ ushort f2bf(float f) {
  unsigned u = __builtin_bit_cast(unsigned, f);
  u += 0x7fffu + ((u >> 16) & 1u);
  return (ushort)(u >> 16);
}
__device__ __forceinline__ float bf2f(ushort h) {
  unsigned u = ((unsigned)h) << 16;
  return __builtin_bit_cast(float, u);
}

__device__ __forceinline__ void gload_lds16(const ushort* g, ushort* l) {
  __builtin_amdgcn_global_load_lds((const __attribute__((address_space(1))) unsigned int*)g,
                                   (__attribute__((address_space(3))) unsigned int*)l, 16, 0, 0);
}

// ---------------- cast fp32 -> bf16 (vectorized) ----------------
__global__ __launch_bounds__(256) void cast_bf16_kernel(const float* __restrict__ in,
                                                        ushort* __restrict__ out, int n4) {
  int i = blockIdx.x * 256 + threadIdx.x;
  int stride = gridDim.x * 256;
  for (; i < n4; i += stride) {
    float4 v = reinterpret_cast<const float4*>(in)[i];
    us4 o;
    o.x = f2bf(v.x); o.y = f2bf(v.y); o.z = f2bf(v.z); o.w = f2bf(v.w);
    reinterpret_cast<us4*>(out)[i] = o;
  }
}

// ---------------- all 4 weight transposes in one launch (z-indexed) ----------------
__global__ __launch_bounds__(256) void wtrans_kernel(const float* __restrict__ Wq,
                                                     const float* __restrict__ Wk,
                                                     const float* __restrict__ Wv,
                                                     const float* __restrict__ Wo,
                                                     ushort* __restrict__ WqkvT,
                                                     ushort* __restrict__ WoT) {
  __shared__ float tile[32][33];
  int z = blockIdx.z;
  const float* src;
  ushort* dst;
  int C;
  if (z == 0) { src = Wq; dst = WqkvT; C = 2048; }
  else if (z == 1) { src = Wk; dst = WqkvT + (size_t)2048 * 2048; C = 512; }
  else if (z == 2) { src = Wv; dst = WqkvT + (size_t)2560 * 2048; C = 512; }
  else { src = Wo; dst = WoT; C = 2048; }
  int c0 = blockIdx.x * 32, r0 = blockIdx.y * 32;
  if (c0 >= C) return;
  int tx = threadIdx.x & 31, ty = threadIdx.x >> 5;
#pragma unroll
  for (int i = 0; i < 4; ++i)
    tile[ty + i * 8][tx] = src[(size_t)(r0 + ty + i * 8) * C + c0 + tx];
  __syncthreads();
#pragma unroll
  for (int i = 0; i < 4; ++i)
    dst[(size_t)(c0 + ty + i * 8) * 2048 + r0 + tx] = f2bf(tile[tx][ty + i * 8]);
}

// ---------------- RoPE tables: cos/sin[t][j], j<64 ----------------
__global__ void rope_table_kernel(float* __restrict__ rc, float* __restrict__ rs) {
  int t = blockIdx.x, j = threadIdx.x;  // 64 threads
  float inv = expf(-(float)j * (9.210340371976184f / 64.0f));
  float ang = (float)t * inv;
  float s, c;
  sincosf(ang, &s, &c);
  rc[t * 64 + j] = c;
  rs[t * 64 + j] = s;
}

// ---------------- fused per-head RMSNorm + RoPE (K only) ----------------
__global__ __launch_bounds__(256) void norm_rope_kernel(
    const ushort* __restrict__ qkv, const float* __restrict__ w,
    ushort* __restrict__ out, const float* __restrict__ rc, const float* __restrict__ rs,
    int nheads, int col_off, int out_stride, float oscale) {
  int wv = threadIdx.x >> 6, lane = threadIdx.x & 63;
  int row = blockIdx.x * 4 + wv;
  int token = row / nheads, head = row % nheads;
  int t = token & 2047;  // token % S
  const ushort* p = qkv + (size_t)token * 3072 + col_off + head * 128;
  float x1 = bf2f(p[lane]), x2 = bf2f(p[lane + 64]);
  float ss = x1 * x1 + x2 * x2;
#pragma unroll
  for (int m = 32; m > 0; m >>= 1) ss += __shfl_xor(ss, m);
  float r = rsqrtf(ss * (1.0f / 128.0f) + 1e-6f);
  float xn1 = x1 * r * w[lane], xn2 = x2 * r * w[lane + 64];
  float c = rc[t * 64 + lane], s = rs[t * 64 + lane];
  ushort* o = out + (size_t)token * out_stride + head * 128;
  o[lane] = f2bf((xn1 * c - xn2 * s) * oscale);
  o[lane + 64] = f2bf((xn2 * c + xn1 * s) * oscale);
}

// ---------------- V transpose: QKV slab -> Vt[b][kv][d][s] ----------------
__global__ __launch_bounds__(256) void v_transpose_kernel(const ushort* __restrict__ qkv,
                                                          ushort* __restrict__ vt) {
  __shared__ ushort tile[64][136];
  int bx = blockIdx.x;
  int st = bx & 31, kvh = (bx >> 5) & 3, b = bx >> 7;
  int s0 = st * 64;
  int tid = threadIdx.x;
#pragma unroll
  for (int p = 0; p < 4; ++p) {
    int idx = p * 2048 + tid * 8;
    int s = idx >> 7, d = idx & 127;
    *(s16x8*)&tile[s][d] =
        *(const s16x8*)&qkv[(size_t)(b * 2048 + s0 + s) * 3072 + 2560 + kvh * 128 + d];
  }
  __syncthreads();
#pragma unroll
  for (int p = 0; p < 4; ++p) {
    int idx = p * 2048 + tid * 8;
    int d = idx >> 6, s = idx & 63;
    s16x8 v;
#pragma unroll
    for (int u = 0; u < 8; ++u) v[u] = (short)tile[s + u][d];
    *(s16x8*)&vt[(size_t)((b * 4 + kvh) * 128 + d) * 2048 + s0 + s] = v;
  }
}

// ---------------- bf16 MFMA GEMM, 256x128 tile, 3-slot pipelined ----------------
template <bool OUTF32>
__global__ __launch_bounds__(512, 2) void gemm256_kernel(const ushort* __restrict__ A,
                                                         const ushort* __restrict__ Bt,
                                                         void* __restrict__ Cp,
                                                         int M, int N, int K) {
  __shared__ ushort As[3][256][64];  // 96 KB
  __shared__ ushort Bs[3][128][64];  // 48 KB
  int tid = threadIdx.x;
  int lane = tid & 63, wv = tid >> 6;  // 8 waves
  int wm = wv >> 1, wn = wv & 1;       // 4 x 2
  int lr = lane & 15, lg = lane >> 4;
  int nwg = gridDim.x * gridDim.y;
  int flat = blockIdx.y * gridDim.x + blockIdx.x;
  int swz = (flat & 7) * (nwg >> 3) + (flat >> 3);
  int bx = swz % gridDim.x, by = swz / gridDim.x;
  int m0 = by * 256, n0 = bx * 128;
  int srow8 = lane >> 3;
  int gcol = ((lane & 7) * 8) ^ (srow8 << 3);
  int nt = K >> 6;

  const ushort* Abase = A + (size_t)m0 * K;
  const ushort* Bbase = Bt + (size_t)n0 * K;

  auto stageA = [&](int slot, int t, int p) {
    int r0 = (wv * 4 + p) * 8;
    gload_lds16(&Abase[(size_t)(r0 + srow8) * K + t * 64 + gcol], &As[slot][r0][0]);
  };
  auto stageB = [&](int slot, int t, int p) {
    int r0 = (wv * 2 + p) * 8;
    gload_lds16(&Bbase[(size_t)(r0 + srow8) * K + t * 64 + gcol], &Bs[slot][r0][0]);
  };

  stageA(0, 0, 0); stageA(0, 0, 1); stageB(0, 0, 0);
  stageA(0, 0, 2); stageA(0, 0, 3); stageB(0, 0, 1);
  stageA(1, 1, 0); stageA(1, 1, 1); stageB(1, 1, 0);
  stageA(1, 1, 2); stageA(1, 1, 3); stageB(1, 1, 1);

  f32x4 acc[4][4] = {};
  int arow[4], brow[4], aswz[4], bswz[4];
#pragma unroll
  for (int i = 0; i < 4; ++i) {
    arow[i] = wm * 64 + i * 16 + lr;
    aswz[i] = (arow[i] & 7) << 3;
    brow[i] = wn * 64 + i * 16 + lr;
    bswz[i] = (brow[i] & 7) << 3;
  }

  for (int t = 0; t < nt; ++t) {
    int cur = t % 3, pf = (t + 2) % 3;
    if (t + 1 < nt) {
      asm volatile("s_waitcnt vmcnt(6)" ::: "memory");
    } else {
      asm volatile("s_waitcnt vmcnt(0)" ::: "memory");
    }
    __builtin_amdgcn_s_barrier();
    bool do_pf = (t + 2) < nt;
    {
      s16x8 a[4], b[4];
#pragma unroll
      for (int i = 0; i < 4; ++i) a[i] = *(const s16x8*)&As[cur][arow[i]][(lg * 8) ^ aswz[i]];
#pragma unroll
      for (int j = 0; j < 4; ++j) b[j] = *(const s16x8*)&Bs[cur][brow[j]][(lg * 8) ^ bswz[j]];
      if (do_pf) { stageA(pf, t + 2, 0); stageA(pf, t + 2, 1); stageB(pf, t + 2, 0); }
      __builtin_amdgcn_s_setprio(1);
#pragma unroll
      for (int i = 0; i < 4; ++i)
#pragma unroll
        for (int j = 0; j < 4; ++j)
          acc[i][j] = __builtin_amdgcn_mfma_f32_16x16x32_bf16(a[i], b[j], acc[i][j], 0, 0, 0);
      __builtin_amdgcn_s_setprio(0);
    }
    {
      s16x8 a[4], b[4];
#pragma unroll
      for (int i = 0; i < 4; ++i) a[i] = *(const s16x8*)&As[cur][arow[i]][(32 + lg * 8) ^ aswz[i]];
#pragma unroll
      for (int j = 0; j < 4; ++j) b[j] = *(const s16x8*)&Bs[cur][brow[j]][(32 + lg * 8) ^ bswz[j]];
      if (do_pf) { stageA(pf, t + 2, 2); stageA(pf, t + 2, 3); stageB(pf, t + 2, 1); }
      __builtin_amdgcn_s_setprio(1);
#pragma unroll
      for (int i = 0; i < 4; ++i)
#pragma unroll
        for (int j = 0; j < 4; ++j)
          acc[i][j] = __builtin_amdgcn_mfma_f32_16x16x32_bf16(a[i], b[j], acc[i][j], 0, 0, 0);
      __builtin_amdgcn_s_setprio(0);
    }
  }
#pragma unroll
  for (int i = 0; i < 4; ++i)
#pragma unroll
    for (int j = 0; j < 4; ++j) {
      int row = m0 + wm * 64 + i * 16 + lg * 4;
      int col = n0 + wn * 64 + j * 16 + lr;
#pragma unroll
      for (int r = 0; r < 4; ++r) {
        float v = acc[i][j][r];
        if (OUTF32)
          reinterpret_cast<float*>(Cp)[(size_t)(row + r) * N + col] = v;
        else
          reinterpret_cast<ushort*>(Cp)[(size_t)(row + r) * N + col] = f2bf(v);
      }
    }
}

// ---------------- causal GQA flash attention ----------------
// ROUND-5 PROVEN LOOP (dbuf K/V, counted vmcnt(8), 2 barriers/tile) +
// ROUND-6 FUSION (in-register Q RMSNorm+RoPE+scale).
// 128 q-rows/block, 4 waves x 32 q; 64-wide K/V tiles. Swapped QK^T:
// lane holds P^T[q=lane&15][k=fp*16+lg*4+r] -> in-lane row reduce (2 shfl),
// packed b64 P-writes. Base-2 online softmax, defer-max THR=8.
__global__ __launch_bounds__(256, 2) void attn_kernel(const ushort* __restrict__ QKV,
                                                      const ushort* __restrict__ Kn,
                                                      const ushort* __restrict__ Vt,
                                                      ushort* __restrict__ AO,
                                                      const float* __restrict__ rc,
                                                      const float* __restrict__ rs,
                                                      const float* __restrict__ qw) {
  __shared__ ushort Ks[2][64][128];   // 32 KB
  __shared__ ushort Vs[2][128][64];   // 32 KB
  __shared__ ushort Ps[4][32][64];    // 16 KB
  int bxi = blockIdx.x;
  int g = bxi >> 5, bh = bxi & 31;
  int qt = (g < 8) ? (15 - g) : (g - 8);  // pair long+short on each CU
  int b = bh >> 4, h = bh & 15, kvh = h >> 2;
  int q0 = qt * 128;
  int nt = 2 * qt + 2;
  int tid = threadIdx.x, lane = tid & 63, w = tid >> 6;
  int lr = lane & 15, lg = lane >> 4;

  int ksrow = lane >> 4, kscol = (lane & 15) * 8;
  int vsrow = lane >> 3, vscol = (lane & 7) * 8;

  // ---- Q build: inline RMSNorm + RoPE + QSCALE (fused, round-6) ----
  const float QSCALE = 0.12751744f;  // log2e / sqrt(128)
  s16x8 qf[2][4];
#pragma unroll
  for (int qa = 0; qa < 2; ++qa) {
    int t_tok = q0 + w * 32 + qa * 16 + lr;
    const ushort* qp = QKV + (size_t)(b * 2048 + t_tok) * 3072 + h * 128;
    float xv[4][8];
    float ss = 0.f;
#pragma unroll
    for (int ks = 0; ks < 4; ++ks) {
      s16x8 raw = *(const s16x8*)&qp[ks * 32 + lg * 8];
#pragma unroll
      for (int j = 0; j < 8; ++j) {
        float x = bf2f((ushort)raw[j]);
        xv[ks][j] = x;
        ss += x * x;
      }
    }
    ss += __shfl_xor(ss, 16);
    ss += __shfl_xor(ss, 32);
    float rms = rsqrtf(ss * (1.0f / 128.0f) + 1e-6f);
#pragma unroll
    for (int ks = 0; ks < 2; ++ks) {
      int dbase = ks * 32 + lg * 8;
      float cc[8], sn[8], w1[8], w2[8];
      *(float4*)&cc[0] = *(const float4*)&rc[(size_t)t_tok * 64 + dbase];
      *(float4*)&cc[4] = *(const float4*)&rc[(size_t)t_tok * 64 + dbase + 4];
      *(float4*)&sn[0] = *(const float4*)&rs[(size_t)t_tok * 64 + dbase];
      *(float4*)&sn[4] = *(const float4*)&rs[(size_t)t_tok * 64 + dbase + 4];
      *(float4*)&w1[0] = *(const float4*)&qw[dbase];
      *(float4*)&w1[4] = *(const float4*)&qw[dbase + 4];
      *(float4*)&w2[0] = *(const float4*)&qw[dbase + 64];
      *(float4*)&w2[4] = *(const float4*)&qw[dbase + 68];
      s16x8 o1, o2;
#pragma unroll
      for (int j = 0; j < 8; ++j) {
        float x1 = xv[ks][j] * rms * w1[j];
        float x2 = xv[ks + 2][j] * rms * w2[j];
        o1[j] = (short)f2bf((x1 * cc[j] - x2 * sn[j]) * QSCALE);
        o2[j] = (short)f2bf((x2 * cc[j] + x1 * sn[j]) * QSCALE);
      }
      qf[qa][ks] = o1;
      qf[qa][ks + 2] = o2;
    }
  }
  // fence: Q's ordinary loads fully drained before the counted gload_lds stream
  asm volatile("s_waitcnt vmcnt(0)" ::: "memory");

  auto stage = [&](int c, int t) {
    int p0 = t * 64;
#pragma unroll
    for (int p = 0; p < 4; ++p) {
      int r0 = w * 16 + p * 4;
      int row = r0 + ksrow;
      int gc = kscol ^ ((row & 7) << 3);
      gload_lds16(&Kn[(size_t)(b * 2048 + p0 + row) * 512 + kvh * 128 + gc], &Ks[c][r0][0]);
    }
#pragma unroll
    for (int p = 0; p < 4; ++p) {
      int r0 = w * 32 + p * 8;
      int row = r0 + vsrow;
      int gc = vscol ^ ((row & 7) << 3);
      gload_lds16(&Vt[(size_t)((b * 4 + kvh) * 128 + row) * 2048 + p0 + gc], &Vs[c][r0][0]);
    }
  };

  stage(0, 0);  // prologue: tile 0 in flight

  f32x4 O[2][8] = {};
  float mrow[2] = {-1e30f, -1e30f};  // per-lane scalar: row q = qa*16 + (lane&15)
  float lrow[2] = {0.f, 0.f};

  for (int t = 0; t < nt; ++t) {
    int c = t & 1;
    if (t + 1 < nt) {
      stage(c ^ 1, t + 1);                               // prefetch next tile
      asm volatile("s_waitcnt vmcnt(8)" ::: "memory");   // tile t's 8 loads done
    } else {
      asm volatile("s_waitcnt vmcnt(0)" ::: "memory");
    }
    __builtin_amdgcn_s_barrier();                        // (a) tile t visible

    bool skip = (t == 2 * qt + 1) && (w < 2);            // fully-masked wave-tile
    if (!skip) {
      // SWAPPED: sacc[qa][fp] = S^T tile: lane holds q=lane&15, k=fp*16+lg*4+r
      f32x4 sacc[2][4] = {};
      __builtin_amdgcn_s_setprio(1);
#pragma unroll
      for (int ks = 0; ks < 4; ++ks) {
        s16x8 bk[4];
#pragma unroll
        for (int fp = 0; fp < 4; ++fp) {
          int kr = fp * 16 + lr;
          bk[fp] = *(const s16x8*)&Ks[c][kr][(ks * 32 + lg * 8) ^ ((kr & 7) << 3)];
        }
#pragma unroll
        for (int qa = 0; qa < 2; ++qa)
#pragma unroll
          for (int fp = 0; fp < 4; ++fp)
            sacc[qa][fp] = __builtin_amdgcn_mfma_f32_16x16x32_bf16(bk[fp], qf[qa][ks], sacc[qa][fp], 0, 0, 0);
      }
      __builtin_amdgcn_s_setprio(0);

      // causal mask (only tiles straddling the diagonal)
      if (t >= 2 * qt) {
        int p0 = t * 64;
#pragma unroll
        for (int qa = 0; qa < 2; ++qa)
#pragma unroll
          for (int fp = 0; fp < 4; ++fp)
#pragma unroll
            for (int r = 0; r < 4; ++r) {
              int qg = q0 + w * 32 + qa * 16 + lr;
              int pg = p0 + fp * 16 + lg * 4 + r;
              if (pg > qg) sacc[qa][fp][r] = -1e30f;
            }
      }

      // row max: in-lane over 16, then xor-16/32 across lg groups
      float pm[2];
#pragma unroll
      for (int qa = 0; qa < 2; ++qa) {
        float m01 = fmaxf(fmaxf(sacc[qa][0][0], sacc[qa][0][1]), fmaxf(sacc[qa][0][2], sacc[qa][0][3]));
#pragma unroll
        for (int fp = 1; fp < 4; ++fp)
          m01 = fmaxf(m01, fmaxf(fmaxf(sacc[qa][fp][0], sacc[qa][fp][1]),
                                 fmaxf(sacc[qa][fp][2], sacc[qa][fp][3])));
        m01 = fmaxf(m01, __shfl_xor(m01, 16));
        m01 = fmaxf(m01, __shfl_xor(m01, 32));
        pm[qa] = m01;
      }
      // defer-max (log2 domain, THR=8)
      bool need = (pm[0] > mrow[0] + 8.0f) | (pm[1] > mrow[1] + 8.0f);
      if (__any((int)need)) {
        float fsc[2];
#pragma unroll
        for (int qa = 0; qa < 2; ++qa) {
          float mn = fmaxf(mrow[qa], pm[qa]);
          fsc[qa] = __builtin_amdgcn_exp2f(mrow[qa] - mn);
          mrow[qa] = mn;
          lrow[qa] *= fsc[qa];
        }
        // redistribute to O layout (q = lg*4 + r)
#pragma unroll
        for (int qa = 0; qa < 2; ++qa) {
          float fo[4];
#pragma unroll
          for (int r = 0; r < 4; ++r) fo[r] = __shfl(fsc[qa], lg * 4 + r);
#pragma unroll
          for (int fn = 0; fn < 8; ++fn)
#pragma unroll
            for (int r = 0; r < 4; ++r) O[qa][fn][r] *= fo[r];
        }
      }
      // exp2 + packed P write + row sum
      float ls[2] = {0.f, 0.f};
#pragma unroll
      for (int qa = 0; qa < 2; ++qa) {
        int prow = qa * 16 + lr;
        int swz = (lr & 7) << 3;
#pragma unroll
        for (int fp = 0; fp < 4; ++fp) {
          float e0 = __builtin_amdgcn_exp2f(sacc[qa][fp][0] - mrow[qa]);
          float e1 = __builtin_amdgcn_exp2f(sacc[qa][fp][1] - mrow[qa]);
          float e2 = __builtin_amdgcn_exp2f(sacc[qa][fp][2] - mrow[qa]);
          float e3 = __builtin_amdgcn_exp2f(sacc[qa][fp][3] - mrow[qa]);
          ls[qa] += (e0 + e1) + (e2 + e3);
          unsigned lo = (unsigned)f2bf(e0) | ((unsigned)f2bf(e1) << 16);
          unsigned hi = (unsigned)f2bf(e2) | ((unsigned)f2bf(e3) << 16);
          uint2 pk; pk.x = lo; pk.y = hi;
          *reinterpret_cast<uint2*>(&Ps[w][prow][(fp * 16 + lg * 4) ^ swz]) = pk;
        }
        ls[qa] += __shfl_xor(ls[qa], 16);
        ls[qa] += __shfl_xor(ls[qa], 32);
        lrow[qa] += ls[qa];
      }
      __builtin_amdgcn_s_setprio(1);
#pragma unroll
      for (int ks2 = 0; ks2 < 2; ++ks2) {
        s16x8 ap[2];
#pragma unroll
        for (int qa = 0; qa < 2; ++qa) {
          int prow = qa * 16 + lr;
          ap[qa] = *(const s16x8*)&Ps[w][prow][(ks2 * 32 + lg * 8) ^ ((lr & 7) << 3)];
        }
#pragma unroll
        for (int fn = 0; fn < 8; ++fn) {
          int vrow = fn * 16 + lr;
          s16x8 bv = *(const s16x8*)&Vs[c][vrow][(ks2 * 32 + lg * 8) ^ ((vrow & 7) << 3)];
#pragma unroll
          for (int qa = 0; qa < 2; ++qa)
            O[qa][fn] = __builtin_amdgcn_mfma_f32_16x16x32_bf16(ap[qa], bv, O[qa][fn], 0, 0, 0);
        }
      }
      __builtin_amdgcn_s_setprio(0);
    }
    __builtin_amdgcn_s_barrier();  // (b) all waves done reading buf c
  }

  // epilogue: O rows are q = lg*4+r; lrow lives at lane&15 == q -> shfl remap
#pragma unroll
  for (int qa = 0; qa < 2; ++qa) {
    float inv = 1.0f / lrow[qa];
    float invq[4];
#pragma unroll
    for (int r = 0; r < 4; ++r) invq[r] = __shfl(inv, lg * 4 + r);
#pragma unroll
    for (int fn = 0; fn < 8; ++fn)
#pragma unroll
      for (int r = 0; r < 4; ++r) {
        size_t idx = (size_t)(b * 2048 + q0 + w * 32 + qa * 16 + lg * 4 + r) * 2048 +
                     h * 128 + fn * 16 + lr;
        AO[idx] = f2bf(O[qa][fn][r] * invq[r]);
      }
  }
}

extern "C" void kernel_launch(void* const* d_in, const int* in_sizes, int n_in,
                              void* d_out, int out_size, void* d_ws, size_t ws_size,
                              hipStream_t stream) {
  (void)in_sizes; (void)n_in; (void)out_size; (void)ws_size;
  const float* x = (const float*)d_in[0];
  const float* Wq = (const float*)d_in[1];
  const float* Wk = (const float*)d_in[2];
  const float* Wv = (const float*)d_in[3];
  const float* Wo = (const float*)d_in[4];
  const float* qw = (const float*)d_in[5];
  const float* kw = (const float*)d_in[6];
  float* out = (float*)d_out;

  char* ws = (char*)d_ws;
  size_t off = 0;
  auto alloc = [&](size_t bytes) {
    void* p = ws + off;
    off += (bytes + 255) & ~(size_t)255;
    return p;
  };
  ushort* xb = (ushort*)alloc((size_t)4096 * 2048 * 2);
  ushort* WqkvT = (ushort*)alloc((size_t)3072 * 2048 * 2);
  ushort* WoT = (ushort*)alloc((size_t)2048 * 2048 * 2);
  ushort* QKVraw = (ushort*)alloc((size_t)4096 * 3072 * 2);
  ushort* Kb = (ushort*)alloc((size_t)4096 * 512 * 2);
  ushort* Vt = (ushort*)alloc((size_t)4096 * 512 * 2);
  ushort* AO = (ushort*)alloc((size_t)4096 * 2048 * 2);
  float* rc = (float*)alloc((size_t)2048 * 64 * 4);
  float* rs = (float*)alloc((size_t)2048 * 64 * 4);

  cast_bf16_kernel<<<2048, 256, 0, stream>>>(x, xb, 4096 * 2048 / 4);
  wtrans_kernel<<<dim3(64, 64, 4), 256, 0, stream>>>(Wq, Wk, Wv, Wo, WqkvT, WoT);
  rope_table_kernel<<<2048, 64, 0, stream>>>(rc, rs);
  gemm256_kernel<false><<<dim3(24, 16), 512, 0, stream>>>(xb, WqkvT, QKVraw, 4096, 3072, 2048);
  norm_rope_kernel<<<4096, 256, 0, stream>>>(QKVraw, kw, Kb, rc, rs, 4, 2048, 512, 1.0f);
  v_transpose_kernel<<<256, 256, 0, stream>>>(QKVraw, Vt);
  attn_kernel<<<512, 256, 0, stream>>>(QKVraw, Kb, Vt, AO, rc, rs, qw);
  gemm256_kernel<true><<<dim3(16, 16), 512, 0, stream>>>(AO, WoT, out, 4096, 2048, 2048);
}

// Round 8
// 202.521 us; speedup vs baseline: 1.7733x; 1.0307x over previous
//
#include <hip/hip_runtime.h>

typedef __attribute__((ext_vector_type(4))) float f32x4;
typedef __attribute__((ext_vector_type(8))) short s16x8;

struct alignas(8) us4 { ushort x, y, z, w; };

__device__ __forceinline__ ushort f2bf(float f) {
  unsigned u = __builtin_bit_cast(unsigned, f);
  u += 0x7fffu + ((u >> 16) & 1u);
  return (ushort)(u >> 16);
}
__device__ __forceinline__ float bf2f(ushort h) {
  unsigned u = ((unsigned)h) << 16;
  return __builtin_bit_cast(float, u);
}

__device__ __forceinline__ void gload_lds16(const ushort* g, ushort* l) {
  __builtin_amdgcn_global_load_lds((const __attribute__((address_space(1))) unsigned int*)g,
                                   (__attribute__((address_space(3))) unsigned int*)l, 16, 0, 0);
}

// ---------------- merged preprocessing: cast + 4 weight transposes + rope tables --
// bid [0,2048): cast x->bf16; [2048,2560): rope tables (4 t/block);
// [2560,12800): 32x32 transpose tiles for Wq/Wk/Wv/Wo.
__global__ __launch_bounds__(256) void preproc_kernel(
    const float* __restrict__ x, const float* __restrict__ Wq, const float* __restrict__ Wk,
    const float* __restrict__ Wv, const float* __restrict__ Wo,
    ushort* __restrict__ xb, ushort* __restrict__ WqkvT, ushort* __restrict__ WoT,
    float* __restrict__ rc, float* __restrict__ rs) {
  __shared__ float tile[32][33];
  int bid = blockIdx.x, tid = threadIdx.x;
  if (bid < 2048) {
    const int n4 = 4096 * 2048 / 4;
    for (int i = bid * 256 + tid; i < n4; i += 2048 * 256) {
      float4 v = reinterpret_cast<const float4*>(x)[i];
      us4 o;
      o.x = f2bf(v.x); o.y = f2bf(v.y); o.z = f2bf(v.z); o.w = f2bf(v.w);
      reinterpret_cast<us4*>(xb)[i] = o;
    }
  } else if (bid < 2560) {
    int t = (bid - 2048) * 4 + (tid >> 6), j = tid & 63;
    float inv = expf(-(float)j * (9.210340371976184f / 64.0f));
    float ang = (float)t * inv;
    float s, c;
    sincosf(ang, &s, &c);
    rc[t * 64 + j] = c;
    rs[t * 64 + j] = s;
  } else {
    int wid = bid - 2560;
    const float* src;
    ushort* dst;
    int C, bx, by;
    if (wid < 4096) { src = Wq; dst = WqkvT; C = 2048; bx = wid & 63; by = wid >> 6; }
    else if (wid < 5120) { int w2 = wid - 4096; src = Wk; dst = WqkvT + (size_t)2048 * 2048; C = 512; bx = w2 & 15; by = w2 >> 4; }
    else if (wid < 6144) { int w2 = wid - 5120; src = Wv; dst = WqkvT + (size_t)2560 * 2048; C = 512; bx = w2 & 15; by = w2 >> 4; }
    else { int w2 = wid - 6144; src = Wo; dst = WoT; C = 2048; bx = w2 & 63; by = w2 >> 6; }
    int c0 = bx * 32, r0 = by * 32;
    int tx = tid & 31, ty = tid >> 5;
#pragma unroll
    for (int i = 0; i < 4; ++i)
      tile[ty + i * 8][tx] = src[(size_t)(r0 + ty + i * 8) * C + c0 + tx];
    __syncthreads();
#pragma unroll
    for (int i = 0; i < 4; ++i)
      dst[(size_t)(c0 + ty + i * 8) * 2048 + r0 + tx] = f2bf(tile[tx][ty + i * 8]);
  }
}

// ---------------- merged post-QKV: K RMSNorm+RoPE and V transpose ----------------
// bid [0,4096): K norm+rope (4 rows/block); [4096,4352): V transpose tiles.
__global__ __launch_bounds__(256) void postqkv_kernel(
    const ushort* __restrict__ qkv, const float* __restrict__ kw,
    ushort* __restrict__ Kb, ushort* __restrict__ vt,
    const float* __restrict__ rc, const float* __restrict__ rs) {
  __shared__ ushort tile[64][136];
  int bid = blockIdx.x, tid = threadIdx.x;
  if (bid < 4096) {
    int wv = tid >> 6, lane = tid & 63;
    int row = bid * 4 + wv;
    int token = row >> 2, head = row & 3;
    const ushort* p = qkv + (size_t)token * 3072 + 2048 + head * 128;
    float x1 = bf2f(p[lane]), x2 = bf2f(p[lane + 64]);
    float ss = x1 * x1 + x2 * x2;
#pragma unroll
    for (int m = 32; m > 0; m >>= 1) ss += __shfl_xor(ss, m);
    float r = rsqrtf(ss * (1.0f / 128.0f) + 1e-6f);
    float xn1 = x1 * r * kw[lane], xn2 = x2 * r * kw[lane + 64];
    int t = token & 2047;
    float c = rc[t * 64 + lane], s = rs[t * 64 + lane];
    ushort* o = Kb + (size_t)token * 512 + head * 128;
    o[lane] = f2bf(xn1 * c - xn2 * s);
    o[lane + 64] = f2bf(xn2 * c + xn1 * s);
  } else {
    int bx = bid - 4096;
    int st = bx & 31, kvh = (bx >> 5) & 3, b = bx >> 7;
    int s0 = st * 64;
#pragma unroll
    for (int p = 0; p < 4; ++p) {
      int idx = p * 2048 + tid * 8;
      int s = idx >> 7, d = idx & 127;
      *(s16x8*)&tile[s][d] =
          *(const s16x8*)&qkv[(size_t)(b * 2048 + s0 + s) * 3072 + 2560 + kvh * 128 + d];
    }
    __syncthreads();
#pragma unroll
    for (int p = 0; p < 4; ++p) {
      int idx = p * 2048 + tid * 8;
      int d = idx >> 6, s = idx & 63;
      s16x8 v;
#pragma unroll
      for (int u = 0; u < 8; ++u) v[u] = (short)tile[s + u][d];
      *(s16x8*)&vt[(size_t)((b * 4 + kvh) * 128 + d) * 2048 + s0 + s] = v;
    }
  }
}

// ---------------- bf16 MFMA GEMM, 256x128 tile, 3-slot pipelined ----------------
template <bool OUTF32>
__global__ __launch_bounds__(512, 2) void gemm256_kernel(const ushort* __restrict__ A,
                                                         const ushort* __restrict__ Bt,
                                                         void* __restrict__ Cp,
                                                         int M, int N, int K) {
  __shared__ ushort As[3][256][64];  // 96 KB
  __shared__ ushort Bs[3][128][64];  // 48 KB
  int tid = threadIdx.x;
  int lane = tid & 63, wv = tid >> 6;  // 8 waves
  int wm = wv >> 1, wn = wv & 1;       // 4 x 2
  int lr = lane & 15, lg = lane >> 4;
  int nwg = gridDim.x * gridDim.y;
  int flat = blockIdx.y * gridDim.x + blockIdx.x;
  int swz = (flat & 7) * (nwg >> 3) + (flat >> 3);
  int bx = swz % gridDim.x, by = swz / gridDim.x;
  int m0 = by * 256, n0 = bx * 128;
  int srow8 = lane >> 3;
  int gcol = ((lane & 7) * 8) ^ (srow8 << 3);
  int nt = K >> 6;

  const ushort* Abase = A + (size_t)m0 * K;
  const ushort* Bbase = Bt + (size_t)n0 * K;

  auto stageA = [&](int slot, int t, int p) {
    int r0 = (wv * 4 + p) * 8;
    gload_lds16(&Abase[(size_t)(r0 + srow8) * K + t * 64 + gcol], &As[slot][r0][0]);
  };
  auto stageB = [&](int slot, int t, int p) {
    int r0 = (wv * 2 + p) * 8;
    gload_lds16(&Bbase[(size_t)(r0 + srow8) * K + t * 64 + gcol], &Bs[slot][r0][0]);
  };

  stageA(0, 0, 0); stageA(0, 0, 1); stageB(0, 0, 0);
  stageA(0, 0, 2); stageA(0, 0, 3); stageB(0, 0, 1);
  stageA(1, 1, 0); stageA(1, 1, 1); stageB(1, 1, 0);
  stageA(1, 1, 2); stageA(1, 1, 3); stageB(1, 1, 1);

  f32x4 acc[4][4] = {};
  int arow[4], brow[4], aswz[4], bswz[4];
#pragma unroll
  for (int i = 0; i < 4; ++i) {
    arow[i] = wm * 64 + i * 16 + lr;
    aswz[i] = (arow[i] & 7) << 3;
    brow[i] = wn * 64 + i * 16 + lr;
    bswz[i] = (brow[i] & 7) << 3;
  }

  for (int t = 0; t < nt; ++t) {
    int cur = t % 3, pf = (t + 2) % 3;
    if (t + 1 < nt) {
      asm volatile("s_waitcnt vmcnt(6)" ::: "memory");
    } else {
      asm volatile("s_waitcnt vmcnt(0)" ::: "memory");
    }
    __builtin_amdgcn_s_barrier();
    bool do_pf = (t + 2) < nt;
    {
      s16x8 a[4], b[4];
#pragma unroll
      for (int i = 0; i < 4; ++i) a[i] = *(const s16x8*)&As[cur][arow[i]][(lg * 8) ^ aswz[i]];
#pragma unroll
      for (int j = 0; j < 4; ++j) b[j] = *(const s16x8*)&Bs[cur][brow[j]][(lg * 8) ^ bswz[j]];
      if (do_pf) { stageA(pf, t + 2, 0); stageA(pf, t + 2, 1); stageB(pf, t + 2, 0); }
      __builtin_amdgcn_s_setprio(1);
#pragma unroll
      for (int i = 0; i < 4; ++i)
#pragma unroll
        for (int j = 0; j < 4; ++j)
          acc[i][j] = __builtin_amdgcn_mfma_f32_16x16x32_bf16(a[i], b[j], acc[i][j], 0, 0, 0);
      __builtin_amdgcn_s_setprio(0);
    }
    {
      s16x8 a[4], b[4];
#pragma unroll
      for (int i = 0; i < 4; ++i) a[i] = *(const s16x8*)&As[cur][arow[i]][(32 + lg * 8) ^ aswz[i]];
#pragma unroll
      for (int j = 0; j < 4; ++j) b[j] = *(const s16x8*)&Bs[cur][brow[j]][(32 + lg * 8) ^ bswz[j]];
      if (do_pf) { stageA(pf, t + 2, 2); stageA(pf, t + 2, 3); stageB(pf, t + 2, 1); }
      __builtin_amdgcn_s_setprio(1);
#pragma unroll
      for (int i = 0; i < 4; ++i)
#pragma unroll
        for (int j = 0; j < 4; ++j)
          acc[i][j] = __builtin_amdgcn_mfma_f32_16x16x32_bf16(a[i], b[j], acc[i][j], 0, 0, 0);
      __builtin_amdgcn_s_setprio(0);
    }
  }
#pragma unroll
  for (int i = 0; i < 4; ++i)
#pragma unroll
    for (int j = 0; j < 4; ++j) {
      int row = m0 + wm * 64 + i * 16 + lg * 4;
      int col = n0 + wn * 64 + j * 16 + lr;
#pragma unroll
      for (int r = 0; r < 4; ++r) {
        float v = acc[i][j][r];
        if (OUTF32)
          reinterpret_cast<float*>(Cp)[(size_t)(row + r) * N + col] = v;
        else
          reinterpret_cast<ushort*>(Cp)[(size_t)(row + r) * N + col] = f2bf(v);
      }
    }
}

// ---------------- causal GQA flash attention ----------------
// r5 loop (dbuf K/V, counted vmcnt(8), 2 barriers/tile) + fused Q build with
// r5 prologue order: stage(0,0) issued BEFORE the Q-build so tile-0 staging
// latency hides under Q's norm/rope arithmetic; no manual drain (the loop's
// vmcnt(8) retires stage-0 — oldest in the in-order vmcnt stream).
__global__ __launch_bounds__(256, 2) void attn_kernel(const ushort* __restrict__ QKV,
                                                      const ushort* __restrict__ Kn,
                                                      const ushort* __restrict__ Vt,
                                                      ushort* __restrict__ AO,
                                                      const float* __restrict__ rc,
                                                      const float* __restrict__ rs,
                                                      const float* __restrict__ qw) {
  __shared__ ushort Ks[2][64][128];   // 32 KB
  __shared__ ushort Vs[2][128][64];   // 32 KB
  __shared__ ushort Ps[4][32][64];    // 16 KB
  int bxi = blockIdx.x;
  int g = bxi >> 5, bh = bxi & 31;
  int qt = (g < 8) ? (15 - g) : (g - 8);  // pair long+short on each CU
  int b = bh >> 4, h = bh & 15, kvh = h >> 2;
  int q0 = qt * 128;
  int nt = 2 * qt + 2;
  int tid = threadIdx.x, lane = tid & 63, w = tid >> 6;
  int lr = lane & 15, lg = lane >> 4;

  int ksrow = lane >> 4, kscol = (lane & 15) * 8;
  int vsrow = lane >> 3, vscol = (lane & 7) * 8;

  auto stage = [&](int c, int t) {
    int p0 = t * 64;
#pragma unroll
    for (int p = 0; p < 4; ++p) {
      int r0 = w * 16 + p * 4;
      int row = r0 + ksrow;
      int gc = kscol ^ ((row & 7) << 3);
      gload_lds16(&Kn[(size_t)(b * 2048 + p0 + row) * 512 + kvh * 128 + gc], &Ks[c][r0][0]);
    }
#pragma unroll
    for (int p = 0; p < 4; ++p) {
      int r0 = w * 32 + p * 8;
      int row = r0 + vsrow;
      int gc = vscol ^ ((row & 7) << 3);
      gload_lds16(&Vt[(size_t)((b * 4 + kvh) * 128 + row) * 2048 + p0 + gc], &Vs[c][r0][0]);
    }
  };

  stage(0, 0);  // tile 0 in flight — overlaps the Q-build below

  // ---- Q build: inline RMSNorm + RoPE + QSCALE ----
  const float QSCALE = 0.12751744f;  // log2e / sqrt(128)
  s16x8 qf[2][4];
#pragma unroll
  for (int qa = 0; qa < 2; ++qa) {
    int t_tok = q0 + w * 32 + qa * 16 + lr;
    const ushort* qp = QKV + (size_t)(b * 2048 + t_tok) * 3072 + h * 128;
    float xv[4][8];
    float ss = 0.f;
#pragma unroll
    for (int ks = 0; ks < 4; ++ks) {
      s16x8 raw = *(const s16x8*)&qp[ks * 32 + lg * 8];
#pragma unroll
      for (int j = 0; j < 8; ++j) {
        float x = bf2f((ushort)raw[j]);
        xv[ks][j] = x;
        ss += x * x;
      }
    }
    ss += __shfl_xor(ss, 16);
    ss += __shfl_xor(ss, 32);
    float rms = rsqrtf(ss * (1.0f / 128.0f) + 1e-6f);
#pragma unroll
    for (int ks = 0; ks < 2; ++ks) {
      int dbase = ks * 32 + lg * 8;
      float cc[8], sn[8], w1[8], w2[8];
      *(float4*)&cc[0] = *(const float4*)&rc[(size_t)t_tok * 64 + dbase];
      *(float4*)&cc[4] = *(const float4*)&rc[(size_t)t_tok * 64 + dbase + 4];
      *(float4*)&sn[0] = *(const float4*)&rs[(size_t)t_tok * 64 + dbase];
      *(float4*)&sn[4] = *(const float4*)&rs[(size_t)t_tok * 64 + dbase + 4];
      *(float4*)&w1[0] = *(const float4*)&qw[dbase];
      *(float4*)&w1[4] = *(const float4*)&qw[dbase + 4];
      *(float4*)&w2[0] = *(const float4*)&qw[dbase + 64];
      *(float4*)&w2[4] = *(const float4*)&qw[dbase + 68];
      s16x8 o1, o2;
#pragma unroll
      for (int j = 0; j < 8; ++j) {
        float x1 = xv[ks][j] * rms * w1[j];
        float x2 = xv[ks + 2][j] * rms * w2[j];
        o1[j] = (short)f2bf((x1 * cc[j] - x2 * sn[j]) * QSCALE);
        o2[j] = (short)f2bf((x2 * cc[j] + x1 * sn[j]) * QSCALE);
      }
      qf[qa][ks] = o1;
      qf[qa][ks + 2] = o2;
    }
  }

  f32x4 O[2][8] = {};
  float mrow[2] = {-1e30f, -1e30f};  // per-lane scalar: row q = qa*16 + (lane&15)
  float lrow[2] = {0.f, 0.f};

  for (int t = 0; t < nt; ++t) {
    int c = t & 1;
    if (t + 1 < nt) {
      stage(c ^ 1, t + 1);                               // prefetch next tile
      asm volatile("s_waitcnt vmcnt(8)" ::: "memory");   // tile t's 8 loads done
    } else {
      asm volatile("s_waitcnt vmcnt(0)" ::: "memory");
    }
    __builtin_amdgcn_s_barrier();                        // (a) tile t visible

    bool skip = (t == 2 * qt + 1) && (w < 2);            // fully-masked wave-tile
    if (!skip) {
      // SWAPPED: sacc[qa][fp] = S^T tile: lane holds q=lane&15, k=fp*16+lg*4+r
      f32x4 sacc[2][4] = {};
      __builtin_amdgcn_s_setprio(1);
#pragma unroll
      for (int ks = 0; ks < 4; ++ks) {
        s16x8 bk[4];
#pragma unroll
        for (int fp = 0; fp < 4; ++fp) {
          int kr = fp * 16 + lr;
          bk[fp] = *(const s16x8*)&Ks[c][kr][(ks * 32 + lg * 8) ^ ((kr & 7) << 3)];
        }
#pragma unroll
        for (int qa = 0; qa < 2; ++qa)
#pragma unroll
          for (int fp = 0; fp < 4; ++fp)
            sacc[qa][fp] = __builtin_amdgcn_mfma_f32_16x16x32_bf16(bk[fp], qf[qa][ks], sacc[qa][fp], 0, 0, 0);
      }
      __builtin_amdgcn_s_setprio(0);

      // causal mask (only tiles straddling the diagonal)
      if (t >= 2 * qt) {
        int p0 = t * 64;
#pragma unroll
        for (int qa = 0; qa < 2; ++qa)
#pragma unroll
          for (int fp = 0; fp < 4; ++fp)
#pragma unroll
            for (int r = 0; r < 4; ++r) {
              int qg = q0 + w * 32 + qa * 16 + lr;
              int pg = p0 + fp * 16 + lg * 4 + r;
              if (pg > qg) sacc[qa][fp][r] = -1e30f;
            }
      }

      // row max: in-lane over 16, then xor-16/32 across lg groups
      float pm[2];
#pragma unroll
      for (int qa = 0; qa < 2; ++qa) {
        float m01 = fmaxf(fmaxf(sacc[qa][0][0], sacc[qa][0][1]), fmaxf(sacc[qa][0][2], sacc[qa][0][3]));
#pragma unroll
        for (int fp = 1; fp < 4; ++fp)
          m01 = fmaxf(m01, fmaxf(fmaxf(sacc[qa][fp][0], sacc[qa][fp][1]),
                                 fmaxf(sacc[qa][fp][2], sacc[qa][fp][3])));
        m01 = fmaxf(m01, __shfl_xor(m01, 16));
        m01 = fmaxf(m01, __shfl_xor(m01, 32));
        pm[qa] = m01;
      }
      // defer-max (log2 domain, THR=8)
      bool need = (pm[0] > mrow[0] + 8.0f) | (pm[1] > mrow[1] + 8.0f);
      if (__any((int)need)) {
        float fsc[2];
#pragma unroll
        for (int qa = 0; qa < 2; ++qa) {
          float mn = fmaxf(mrow[qa], pm[qa]);
          fsc[qa] = __builtin_amdgcn_exp2f(mrow[qa] - mn);
          mrow[qa] = mn;
          lrow[qa] *= fsc[qa];
        }
        // redistribute to O layout (q = lg*4 + r)
#pragma unroll
        for (int qa = 0; qa < 2; ++qa) {
          float fo[4];
#pragma unroll
          for (int r = 0; r < 4; ++r) fo[r] = __shfl(fsc[qa], lg * 4 + r);
#pragma unroll
          for (int fn = 0; fn < 8; ++fn)
#pragma unroll
            for (int r = 0; r < 4; ++r) O[qa][fn][r] *= fo[r];
        }
      }
      // exp2 + packed P write + row sum
      float ls[2] = {0.f, 0.f};
#pragma unroll
      for (int qa = 0; qa < 2; ++qa) {
        int prow = qa * 16 + lr;
        int swz = (lr & 7) << 3;
#pragma unroll
        for (int fp = 0; fp < 4; ++fp) {
          float e0 = __builtin_amdgcn_exp2f(sacc[qa][fp][0] - mrow[qa]);
          float e1 = __builtin_amdgcn_exp2f(sacc[qa][fp][1] - mrow[qa]);
          float e2 = __builtin_amdgcn_exp2f(sacc[qa][fp][2] - mrow[qa]);
          float e3 = __builtin_amdgcn_exp2f(sacc[qa][fp][3] - mrow[qa]);
          ls[qa] += (e0 + e1) + (e2 + e3);
          unsigned lo = (unsigned)f2bf(e0) | ((unsigned)f2bf(e1) << 16);
          unsigned hi = (unsigned)f2bf(e2) | ((unsigned)f2bf(e3) << 16);
          uint2 pk; pk.x = lo; pk.y = hi;
          *reinterpret_cast<uint2*>(&Ps[w][prow][(fp * 16 + lg * 4) ^ swz]) = pk;
        }
        ls[qa] += __shfl_xor(ls[qa], 16);
        ls[qa] += __shfl_xor(ls[qa], 32);
        lrow[qa] += ls[qa];
      }
      __builtin_amdgcn_s_setprio(1);
#pragma unroll
      for (int ks2 = 0; ks2 < 2; ++ks2) {
        s16x8 ap[2];
#pragma unroll
        for (int qa = 0; qa < 2; ++qa) {
          int prow = qa * 16 + lr;
          ap[qa] = *(const s16x8*)&Ps[w][prow][(ks2 * 32 + lg * 8) ^ ((lr & 7) << 3)];
        }
#pragma unroll
        for (int fn = 0; fn < 8; ++fn) {
          int vrow = fn * 16 + lr;
          s16x8 bv = *(const s16x8*)&Vs[c][vrow][(ks2 * 32 + lg * 8) ^ ((vrow & 7) << 3)];
#pragma unroll
          for (int qa = 0; qa < 2; ++qa)
            O[qa][fn] = __builtin_amdgcn_mfma_f32_16x16x32_bf16(ap[qa], bv, O[qa][fn], 0, 0, 0);
        }
      }
      __builtin_amdgcn_s_setprio(0);
    }
    __builtin_amdgcn_s_barrier();  // (b) all waves done reading buf c
  }

  // epilogue: O rows are q = lg*4+r; lrow lives at lane&15 == q -> shfl remap
#pragma unroll
  for (int qa = 0; qa < 2; ++qa) {
    float inv = 1.0f / lrow[qa];
    float invq[4];
#pragma unroll
    for (int r = 0; r < 4; ++r) invq[r] = __shfl(inv, lg * 4 + r);
#pragma unroll
    for (int fn = 0; fn < 8; ++fn)
#pragma unroll
      for (int r = 0; r < 4; ++r) {
        size_t idx = (size_t)(b * 2048 + q0 + w * 32 + qa * 16 + lg * 4 + r) * 2048 +
                     h * 128 + fn * 16 + lr;
        AO[idx] = f2bf(O[qa][fn][r] * invq[r]);
      }
  }
}

extern "C" void kernel_launch(void* const* d_in, const int* in_sizes, int n_in,
                              void* d_out, int out_size, void* d_ws, size_t ws_size,
                              hipStream_t stream) {
  (void)in_sizes; (void)n_in; (void)out_size; (void)ws_size;
  const float* x = (const float*)d_in[0];
  const float* Wq = (const float*)d_in[1];
  const float* Wk = (const float*)d_in[2];
  const float* Wv = (const float*)d_in[3];
  const float* Wo = (const float*)d_in[4];
  const float* qw = (const float*)d_in[5];
  const float* kw = (const float*)d_in[6];
  float* out = (float*)d_out;

  char* ws = (char*)d_ws;
  size_t off = 0;
  auto alloc = [&](size_t bytes) {
    void* p = ws + off;
    off += (bytes + 255) & ~(size_t)255;
    return p;
  };
  ushort* xb = (ushort*)alloc((size_t)4096 * 2048 * 2);
  ushort* WqkvT = (ushort*)alloc((size_t)3072 * 2048 * 2);
  ushort* WoT = (ushort*)alloc((size_t)2048 * 2048 * 2);
  ushort* QKVraw = (ushort*)alloc((size_t)4096 * 3072 * 2);
  ushort* Kb = (ushort*)alloc((size_t)4096 * 512 * 2);
  ushort* Vt = (ushort*)alloc((size_t)4096 * 512 * 2);
  ushort* AO = (ushort*)alloc((size_t)4096 * 2048 * 2);
  float* rc = (float*)alloc((size_t)2048 * 64 * 4);
  float* rs = (float*)alloc((size_t)2048 * 64 * 4);

  preproc_kernel<<<12800, 256, 0, stream>>>(x, Wq, Wk, Wv, Wo, xb, WqkvT, WoT, rc, rs);
  gemm256_kernel<false><<<dim3(24, 16), 512, 0, stream>>>(xb, WqkvT, QKVraw, 4096, 3072, 2048);
  postqkv_kernel<<<4352, 256, 0, stream>>>(QKVraw, kw, Kb, Vt, rc, rs);
  attn_kernel<<<512, 256, 0, stream>>>(QKVraw, Kb, Vt, AO, rc, rs, qw);
  gemm256_kernel<true><<<dim3(16, 16), 512, 0, stream>>>(AO, WoT, out, 4096, 2048, 2048);
}

// Round 9
// 198.599 us; speedup vs baseline: 1.8084x; 1.0198x over previous
//
#include <hip/hip_runtime.h>

typedef __attribute__((ext_vector_type(4))) float f32x4;
typedef __attribute__((ext_vector_type(8))) short s16x8;

struct alignas(8) us4 { ushort x, y, z, w; };

__device__ __forceinline__ ushort f2bf(float f) {
  unsigned u = __builtin_bit_cast(unsigned, f);
  u += 0x7fffu + ((u >> 16) & 1u);
  return (ushort)(u >> 16);
}
__device__ __forceinline__ float bf2f(ushort h) {
  unsigned u = ((unsigned)h) << 16;
  return __builtin_bit_cast(float, u);
}

__device__ __forceinline__ void gload_lds16(const ushort* g, ushort* l) {
  __builtin_amdgcn_global_load_lds((const __attribute__((address_space(1))) unsigned int*)g,
                                   (__attribute__((address_space(3))) unsigned int*)l, 16, 0, 0);
}

// ---------------- merged preprocessing: cast + 4 weight transposes + rope tables --
__global__ __launch_bounds__(256) void preproc_kernel(
    const float* __restrict__ x, const float* __restrict__ Wq, const float* __restrict__ Wk,
    const float* __restrict__ Wv, const float* __restrict__ Wo,
    ushort* __restrict__ xb, ushort* __restrict__ WqkvT, ushort* __restrict__ WoT,
    float* __restrict__ rc, float* __restrict__ rs) {
  __shared__ float tile[32][33];
  int bid = blockIdx.x, tid = threadIdx.x;
  if (bid < 2048) {
    const int n4 = 4096 * 2048 / 4;
    for (int i = bid * 256 + tid; i < n4; i += 2048 * 256) {
      float4 v = reinterpret_cast<const float4*>(x)[i];
      us4 o;
      o.x = f2bf(v.x); o.y = f2bf(v.y); o.z = f2bf(v.z); o.w = f2bf(v.w);
      reinterpret_cast<us4*>(xb)[i] = o;
    }
  } else if (bid < 2560) {
    int t = (bid - 2048) * 4 + (tid >> 6), j = tid & 63;
    float inv = expf(-(float)j * (9.210340371976184f / 64.0f));
    float ang = (float)t * inv;
    float s, c;
    sincosf(ang, &s, &c);
    rc[t * 64 + j] = c;
    rs[t * 64 + j] = s;
  } else {
    int wid = bid - 2560;
    const float* src;
    ushort* dst;
    int C, bx, by;
    if (wid < 4096) { src = Wq; dst = WqkvT; C = 2048; bx = wid & 63; by = wid >> 6; }
    else if (wid < 5120) { int w2 = wid - 4096; src = Wk; dst = WqkvT + (size_t)2048 * 2048; C = 512; bx = w2 & 15; by = w2 >> 4; }
    else if (wid < 6144) { int w2 = wid - 5120; src = Wv; dst = WqkvT + (size_t)2560 * 2048; C = 512; bx = w2 & 15; by = w2 >> 4; }
    else { int w2 = wid - 6144; src = Wo; dst = WoT; C = 2048; bx = w2 & 63; by = w2 >> 6; }
    int c0 = bx * 32, r0 = by * 32;
    int tx = tid & 31, ty = tid >> 5;
#pragma unroll
    for (int i = 0; i < 4; ++i)
      tile[ty + i * 8][tx] = src[(size_t)(r0 + ty + i * 8) * C + c0 + tx];
    __syncthreads();
#pragma unroll
    for (int i = 0; i < 4; ++i)
      dst[(size_t)(c0 + ty + i * 8) * 2048 + r0 + tx] = f2bf(tile[tx][ty + i * 8]);
  }
}

// ---------------- merged post-QKV: K RMSNorm+RoPE and V transpose ----------------
__global__ __launch_bounds__(256) void postqkv_kernel(
    const ushort* __restrict__ qkv, const float* __restrict__ kw,
    ushort* __restrict__ Kb, ushort* __restrict__ vt,
    const float* __restrict__ rc, const float* __restrict__ rs) {
  __shared__ ushort tile[64][136];
  int bid = blockIdx.x, tid = threadIdx.x;
  if (bid < 4096) {
    int wv = tid >> 6, lane = tid & 63;
    int row = bid * 4 + wv;
    int token = row >> 2, head = row & 3;
    const ushort* p = qkv + (size_t)token * 3072 + 2048 + head * 128;
    float x1 = bf2f(p[lane]), x2 = bf2f(p[lane + 64]);
    float ss = x1 * x1 + x2 * x2;
#pragma unroll
    for (int m = 32; m > 0; m >>= 1) ss += __shfl_xor(ss, m);
    float r = rsqrtf(ss * (1.0f / 128.0f) + 1e-6f);
    float xn1 = x1 * r * kw[lane], xn2 = x2 * r * kw[lane + 64];
    int t = token & 2047;
    float c = rc[t * 64 + lane], s = rs[t * 64 + lane];
    ushort* o = Kb + (size_t)token * 512 + head * 128;
    o[lane] = f2bf(xn1 * c - xn2 * s);
    o[lane + 64] = f2bf(xn2 * c + xn1 * s);
  } else {
    int bx = bid - 4096;
    int st = bx & 31, kvh = (bx >> 5) & 3, b = bx >> 7;
    int s0 = st * 64;
#pragma unroll
    for (int p = 0; p < 4; ++p) {
      int idx = p * 2048 + tid * 8;
      int s = idx >> 7, d = idx & 127;
      *(s16x8*)&tile[s][d] =
          *(const s16x8*)&qkv[(size_t)(b * 2048 + s0 + s) * 3072 + 2560 + kvh * 128 + d];
    }
    __syncthreads();
#pragma unroll
    for (int p = 0; p < 4; ++p) {
      int idx = p * 2048 + tid * 8;
      int d = idx >> 6, s = idx & 63;
      s16x8 v;
#pragma unroll
      for (int u = 0; u < 8; ++u) v[u] = (short)tile[s + u][d];
      *(s16x8*)&vt[(size_t)((b * 4 + kvh) * 128 + d) * 2048 + s0 + s] = v;
    }
  }
}

// ---------------- bf16 MFMA GEMM, 256x128 tile, 3-slot pipelined ----------------
template <bool OUTF32>
__global__ __launch_bounds__(512, 2) void gemm256_kernel(const ushort* __restrict__ A,
                                                         const ushort* __restrict__ Bt,
                                                         void* __restrict__ Cp,
                                                         int M, int N, int K) {
  __shared__ ushort As[3][256][64];  // 96 KB
  __shared__ ushort Bs[3][128][64];  // 48 KB
  int tid = threadIdx.x;
  int lane = tid & 63, wv = tid >> 6;  // 8 waves
  int wm = wv >> 1, wn = wv & 1;       // 4 x 2
  int lr = lane & 15, lg = lane >> 4;
  int nwg = gridDim.x * gridDim.y;
  int flat = blockIdx.y * gridDim.x + blockIdx.x;
  int swz = (flat & 7) * (nwg >> 3) + (flat >> 3);
  int bx = swz % gridDim.x, by = swz / gridDim.x;
  int m0 = by * 256, n0 = bx * 128;
  int srow8 = lane >> 3;
  int gcol = ((lane & 7) * 8) ^ (srow8 << 3);
  int nt = K >> 6;

  const ushort* Abase = A + (size_t)m0 * K;
  const ushort* Bbase = Bt + (size_t)n0 * K;

  auto stageA = [&](int slot, int t, int p) {
    int r0 = (wv * 4 + p) * 8;
    gload_lds16(&Abase[(size_t)(r0 + srow8) * K + t * 64 + gcol], &As[slot][r0][0]);
  };
  auto stageB = [&](int slot, int t, int p) {
    int r0 = (wv * 2 + p) * 8;
    gload_lds16(&Bbase[(size_t)(r0 + srow8) * K + t * 64 + gcol], &Bs[slot][r0][0]);
  };

  stageA(0, 0, 0); stageA(0, 0, 1); stageB(0, 0, 0);
  stageA(0, 0, 2); stageA(0, 0, 3); stageB(0, 0, 1);
  stageA(1, 1, 0); stageA(1, 1, 1); stageB(1, 1, 0);
  stageA(1, 1, 2); stageA(1, 1, 3); stageB(1, 1, 1);

  f32x4 acc[4][4] = {};
  int arow[4], brow[4], aswz[4], bswz[4];
#pragma unroll
  for (int i = 0; i < 4; ++i) {
    arow[i] = wm * 64 + i * 16 + lr;
    aswz[i] = (arow[i] & 7) << 3;
    brow[i] = wn * 64 + i * 16 + lr;
    bswz[i] = (brow[i] & 7) << 3;
  }

  for (int t = 0; t < nt; ++t) {
    int cur = t % 3, pf = (t + 2) % 3;
    if (t + 1 < nt) {
      asm volatile("s_waitcnt vmcnt(6)" ::: "memory");
    } else {
      asm volatile("s_waitcnt vmcnt(0)" ::: "memory");
    }
    __builtin_amdgcn_s_barrier();
    bool do_pf = (t + 2) < nt;
    {
      s16x8 a[4], b[4];
#pragma unroll
      for (int i = 0; i < 4; ++i) a[i] = *(const s16x8*)&As[cur][arow[i]][(lg * 8) ^ aswz[i]];
#pragma unroll
      for (int j = 0; j < 4; ++j) b[j] = *(const s16x8*)&Bs[cur][brow[j]][(lg * 8) ^ bswz[j]];
      if (do_pf) { stageA(pf, t + 2, 0); stageA(pf, t + 2, 1); stageB(pf, t + 2, 0); }
      __builtin_amdgcn_s_setprio(1);
#pragma unroll
      for (int i = 0; i < 4; ++i)
#pragma unroll
        for (int j = 0; j < 4; ++j)
          acc[i][j] = __builtin_amdgcn_mfma_f32_16x16x32_bf16(a[i], b[j], acc[i][j], 0, 0, 0);
      __builtin_amdgcn_s_setprio(0);
    }
    {
      s16x8 a[4], b[4];
#pragma unroll
      for (int i = 0; i < 4; ++i) a[i] = *(const s16x8*)&As[cur][arow[i]][(32 + lg * 8) ^ aswz[i]];
#pragma unroll
      for (int j = 0; j < 4; ++j) b[j] = *(const s16x8*)&Bs[cur][brow[j]][(32 + lg * 8) ^ bswz[j]];
      if (do_pf) { stageA(pf, t + 2, 2); stageA(pf, t + 2, 3); stageB(pf, t + 2, 1); }
      __builtin_amdgcn_s_setprio(1);
#pragma unroll
      for (int i = 0; i < 4; ++i)
#pragma unroll
        for (int j = 0; j < 4; ++j)
          acc[i][j] = __builtin_amdgcn_mfma_f32_16x16x32_bf16(a[i], b[j], acc[i][j], 0, 0, 0);
      __builtin_amdgcn_s_setprio(0);
    }
  }
#pragma unroll
  for (int i = 0; i < 4; ++i)
#pragma unroll
    for (int j = 0; j < 4; ++j) {
      int row = m0 + wm * 64 + i * 16 + lg * 4;
      int col = n0 + wn * 64 + j * 16 + lr;
#pragma unroll
      for (int r = 0; r < 4; ++r) {
        float v = acc[i][j][r];
        if (OUTF32)
          reinterpret_cast<float*>(Cp)[(size_t)(row + r) * N + col] = v;
        else
          reinterpret_cast<ushort*>(Cp)[(size_t)(row + r) * N + col] = f2bf(v);
      }
    }
}

// ---------------- causal GQA flash attention ----------------
// r5 loop (dbuf K/V, counted vmcnt(8), 2 barriers/tile) + fused Q build.
// Softmax reductions restructured: per-lane partial lrow (epilogue-only sum
// reduction) + defer gate on IN-LANE max (pm_full>thr iff any-lane pml>thr,
// so trigger semantics identical) — 8 shfl/tile -> 0 steady-state.
__global__ __launch_bounds__(256, 2) void attn_kernel(const ushort* __restrict__ QKV,
                                                      const ushort* __restrict__ Kn,
                                                      const ushort* __restrict__ Vt,
                                                      ushort* __restrict__ AO,
                                                      const float* __restrict__ rc,
                                                      const float* __restrict__ rs,
                                                      const float* __restrict__ qw) {
  __shared__ ushort Ks[2][64][128];   // 32 KB
  __shared__ ushort Vs[2][128][64];   // 32 KB
  __shared__ ushort Ps[4][32][64];    // 16 KB
  int bxi = blockIdx.x;
  int g = bxi >> 5, bh = bxi & 31;
  int qt = (g < 8) ? (15 - g) : (g - 8);  // pair long+short on each CU
  int b = bh >> 4, h = bh & 15, kvh = h >> 2;
  int q0 = qt * 128;
  int nt = 2 * qt + 2;
  int tid = threadIdx.x, lane = tid & 63, w = tid >> 6;
  int lr = lane & 15, lg = lane >> 4;

  int ksrow = lane >> 4, kscol = (lane & 15) * 8;
  int vsrow = lane >> 3, vscol = (lane & 7) * 8;

  auto stage = [&](int c, int t) {
    int p0 = t * 64;
#pragma unroll
    for (int p = 0; p < 4; ++p) {
      int r0 = w * 16 + p * 4;
      int row = r0 + ksrow;
      int gc = kscol ^ ((row & 7) << 3);
      gload_lds16(&Kn[(size_t)(b * 2048 + p0 + row) * 512 + kvh * 128 + gc], &Ks[c][r0][0]);
    }
#pragma unroll
    for (int p = 0; p < 4; ++p) {
      int r0 = w * 32 + p * 8;
      int row = r0 + vsrow;
      int gc = vscol ^ ((row & 7) << 3);
      gload_lds16(&Vt[(size_t)((b * 4 + kvh) * 128 + row) * 2048 + p0 + gc], &Vs[c][r0][0]);
    }
  };

  stage(0, 0);  // tile 0 in flight — overlaps the Q-build below

  // ---- Q build: inline RMSNorm + RoPE + QSCALE ----
  const float QSCALE = 0.12751744f;  // log2e / sqrt(128)
  s16x8 qf[2][4];
#pragma unroll
  for (int qa = 0; qa < 2; ++qa) {
    int t_tok = q0 + w * 32 + qa * 16 + lr;
    const ushort* qp = QKV + (size_t)(b * 2048 + t_tok) * 3072 + h * 128;
    float xv[4][8];
    float ss = 0.f;
#pragma unroll
    for (int ks = 0; ks < 4; ++ks) {
      s16x8 raw = *(const s16x8*)&qp[ks * 32 + lg * 8];
#pragma unroll
      for (int j = 0; j < 8; ++j) {
        float x = bf2f((ushort)raw[j]);
        xv[ks][j] = x;
        ss += x * x;
      }
    }
    ss += __shfl_xor(ss, 16);
    ss += __shfl_xor(ss, 32);
    float rms = rsqrtf(ss * (1.0f / 128.0f) + 1e-6f);
#pragma unroll
    for (int ks = 0; ks < 2; ++ks) {
      int dbase = ks * 32 + lg * 8;
      float cc[8], sn[8], w1[8], w2[8];
      *(float4*)&cc[0] = *(const float4*)&rc[(size_t)t_tok * 64 + dbase];
      *(float4*)&cc[4] = *(const float4*)&rc[(size_t)t_tok * 64 + dbase + 4];
      *(float4*)&sn[0] = *(const float4*)&rs[(size_t)t_tok * 64 + dbase];
      *(float4*)&sn[4] = *(const float4*)&rs[(size_t)t_tok * 64 + dbase + 4];
      *(float4*)&w1[0] = *(const float4*)&qw[dbase];
      *(float4*)&w1[4] = *(const float4*)&qw[dbase + 4];
      *(float4*)&w2[0] = *(const float4*)&qw[dbase + 64];
      *(float4*)&w2[4] = *(const float4*)&qw[dbase + 68];
      s16x8 o1, o2;
#pragma unroll
      for (int j = 0; j < 8; ++j) {
        float x1 = xv[ks][j] * rms * w1[j];
        float x2 = xv[ks + 2][j] * rms * w2[j];
        o1[j] = (short)f2bf((x1 * cc[j] - x2 * sn[j]) * QSCALE);
        o2[j] = (short)f2bf((x2 * cc[j] + x1 * sn[j]) * QSCALE);
      }
      qf[qa][ks] = o1;
      qf[qa][ks + 2] = o2;
    }
  }

  f32x4 O[2][8] = {};
  float mrow[2] = {-1e30f, -1e30f};  // wave-row-uniform running max (log2 domain)
  float lrow[2] = {0.f, 0.f};        // PER-LANE PARTIAL sum over this lane's k-slice

  for (int t = 0; t < nt; ++t) {
    int c = t & 1;
    if (t + 1 < nt) {
      stage(c ^ 1, t + 1);                               // prefetch next tile
      asm volatile("s_waitcnt vmcnt(8)" ::: "memory");   // tile t's 8 loads done
    } else {
      asm volatile("s_waitcnt vmcnt(0)" ::: "memory");
    }
    __builtin_amdgcn_s_barrier();                        // (a) tile t visible

    bool skip = (t == 2 * qt + 1) && (w < 2);            // fully-masked wave-tile
    if (!skip) {
      // SWAPPED: sacc[qa][fp] = S^T tile: lane holds q=lane&15, k=fp*16+lg*4+r
      f32x4 sacc[2][4] = {};
      __builtin_amdgcn_s_setprio(1);
#pragma unroll
      for (int ks = 0; ks < 4; ++ks) {
        s16x8 bk[4];
#pragma unroll
        for (int fp = 0; fp < 4; ++fp) {
          int kr = fp * 16 + lr;
          bk[fp] = *(const s16x8*)&Ks[c][kr][(ks * 32 + lg * 8) ^ ((kr & 7) << 3)];
        }
#pragma unroll
        for (int qa = 0; qa < 2; ++qa)
#pragma unroll
          for (int fp = 0; fp < 4; ++fp)
            sacc[qa][fp] = __builtin_amdgcn_mfma_f32_16x16x32_bf16(bk[fp], qf[qa][ks], sacc[qa][fp], 0, 0, 0);
      }
      __builtin_amdgcn_s_setprio(0);

      // causal mask (only tiles straddling the diagonal)
      if (t >= 2 * qt) {
        int p0 = t * 64;
#pragma unroll
        for (int qa = 0; qa < 2; ++qa)
#pragma unroll
          for (int fp = 0; fp < 4; ++fp)
#pragma unroll
            for (int r = 0; r < 4; ++r) {
              int qg = q0 + w * 32 + qa * 16 + lr;
              int pg = p0 + fp * 16 + lg * 4 + r;
              if (pg > qg) sacc[qa][fp][r] = -1e30f;
            }
      }

      // in-lane row max (16 values, tree)
      float pml[2];
#pragma unroll
      for (int qa = 0; qa < 2; ++qa) {
        float m0 = fmaxf(fmaxf(sacc[qa][0][0], sacc[qa][0][1]), fmaxf(sacc[qa][0][2], sacc[qa][0][3]));
        float m1 = fmaxf(fmaxf(sacc[qa][1][0], sacc[qa][1][1]), fmaxf(sacc[qa][1][2], sacc[qa][1][3]));
        float m2 = fmaxf(fmaxf(sacc[qa][2][0], sacc[qa][2][1]), fmaxf(sacc[qa][2][2], sacc[qa][2][3]));
        float m3 = fmaxf(fmaxf(sacc[qa][3][0], sacc[qa][3][1]), fmaxf(sacc[qa][3][2], sacc[qa][3][3]));
        pml[qa] = fmaxf(fmaxf(m0, m1), fmaxf(m2, m3));
      }
      // defer gate on in-lane max: pm_full > thr  <=>  any lane's pml > thr
      bool need = (pml[0] > mrow[0] + 8.0f) | (pml[1] > mrow[1] + 8.0f);
      if (__any((int)need)) {
        float fsc[2];
#pragma unroll
        for (int qa = 0; qa < 2; ++qa) {
          float pm = fmaxf(pml[qa], __shfl_xor(pml[qa], 16));
          pm = fmaxf(pm, __shfl_xor(pm, 32));
          float mn = fmaxf(mrow[qa], pm);
          fsc[qa] = __builtin_amdgcn_exp2f(mrow[qa] - mn);
          mrow[qa] = mn;
          lrow[qa] *= fsc[qa];
        }
        // redistribute to O layout (q = lg*4 + r)
#pragma unroll
        for (int qa = 0; qa < 2; ++qa) {
          float fo[4];
#pragma unroll
          for (int r = 0; r < 4; ++r) fo[r] = __shfl(fsc[qa], lg * 4 + r);
#pragma unroll
          for (int fn = 0; fn < 8; ++fn)
#pragma unroll
            for (int r = 0; r < 4; ++r) O[qa][fn][r] *= fo[r];
        }
      }
      // exp2 + packed P write + PER-LANE partial sum (no cross-lane shfls here)
#pragma unroll
      for (int qa = 0; qa < 2; ++qa) {
        float ls = 0.f;
        int prow = qa * 16 + lr;
        int swz = (lr & 7) << 3;
#pragma unroll
        for (int fp = 0; fp < 4; ++fp) {
          float e0 = __builtin_amdgcn_exp2f(sacc[qa][fp][0] - mrow[qa]);
          float e1 = __builtin_amdgcn_exp2f(sacc[qa][fp][1] - mrow[qa]);
          float e2 = __builtin_amdgcn_exp2f(sacc[qa][fp][2] - mrow[qa]);
          float e3 = __builtin_amdgcn_exp2f(sacc[qa][fp][3] - mrow[qa]);
          ls += (e0 + e1) + (e2 + e3);
          unsigned lo = (unsigned)f2bf(e0) | ((unsigned)f2bf(e1) << 16);
          unsigned hi = (unsigned)f2bf(e2) | ((unsigned)f2bf(e3) << 16);
          uint2 pk; pk.x = lo; pk.y = hi;
          *reinterpret_cast<uint2*>(&Ps[w][prow][(fp * 16 + lg * 4) ^ swz]) = pk;
        }
        lrow[qa] += ls;
      }
      __builtin_amdgcn_s_setprio(1);
#pragma unroll
      for (int ks2 = 0; ks2 < 2; ++ks2) {
        s16x8 ap[2];
#pragma unroll
        for (int qa = 0; qa < 2; ++qa) {
          int prow = qa * 16 + lr;
          ap[qa] = *(const s16x8*)&Ps[w][prow][(ks2 * 32 + lg * 8) ^ ((lr & 7) << 3)];
        }
#pragma unroll
        for (int fn = 0; fn < 8; ++fn) {
          int vrow = fn * 16 + lr;
          s16x8 bv = *(const s16x8*)&Vs[c][vrow][(ks2 * 32 + lg * 8) ^ ((vrow & 7) << 3)];
#pragma unroll
          for (int qa = 0; qa < 2; ++qa)
            O[qa][fn] = __builtin_amdgcn_mfma_f32_16x16x32_bf16(ap[qa], bv, O[qa][fn], 0, 0, 0);
        }
      }
      __builtin_amdgcn_s_setprio(0);
    }
    __builtin_amdgcn_s_barrier();  // (b) all waves done reading buf c
  }

  // epilogue: finish the deferred cross-lane lrow reduction (once per block)
#pragma unroll
  for (int qa = 0; qa < 2; ++qa) {
    lrow[qa] += __shfl_xor(lrow[qa], 16);
    lrow[qa] += __shfl_xor(lrow[qa], 32);
  }
  // O rows are q = lg*4+r; lrow lives at lane&15 == q -> shfl remap
#pragma unroll
  for (int qa = 0; qa < 2; ++qa) {
    float inv = 1.0f / lrow[qa];
    float invq[4];
#pragma unroll
    for (int r = 0; r < 4; ++r) invq[r] = __shfl(inv, lg * 4 + r);
#pragma unroll
    for (int fn = 0; fn < 8; ++fn)
#pragma unroll
      for (int r = 0; r < 4; ++r) {
        size_t idx = (size_t)(b * 2048 + q0 + w * 32 + qa * 16 + lg * 4 + r) * 2048 +
                     h * 128 + fn * 16 + lr;
        AO[idx] = f2bf(O[qa][fn][r] * invq[r]);
      }
  }
}

extern "C" void kernel_launch(void* const* d_in, const int* in_sizes, int n_in,
                              void* d_out, int out_size, void* d_ws, size_t ws_size,
                              hipStream_t stream) {
  (void)in_sizes; (void)n_in; (void)out_size; (void)ws_size;
  const float* x = (const float*)d_in[0];
  const float* Wq = (const float*)d_in[1];
  const float* Wk = (const float*)d_in[2];
  const float* Wv = (const float*)d_in[3];
  const float* Wo = (const float*)d_in[4];
  const float* qw = (const float*)d_in[5];
  const float* kw = (const float*)d_in[6];
  float* out = (float*)d_out;

  char* ws = (char*)d_ws;
  size_t off = 0;
  auto alloc = [&](size_t bytes) {
    void* p = ws + off;
    off += (bytes + 255) & ~(size_t)255;
    return p;
  };
  ushort* xb = (ushort*)alloc((size_t)4096 * 2048 * 2);
  ushort* WqkvT = (ushort*)alloc((size_t)3072 * 2048 * 2);
  ushort* WoT = (ushort*)alloc((size_t)2048 * 2048 * 2);
  ushort* QKVraw = (ushort*)alloc((size_t)4096 * 3072 * 2);
  ushort* Kb = (ushort*)alloc((size_t)4096 * 512 * 2);
  ushort* Vt = (ushort*)alloc((size_t)4096 * 512 * 2);
  ushort* AO = (ushort*)alloc((size_t)4096 * 2048 * 2);
  float* rc = (float*)alloc((size_t)2048 * 64 * 4);
  float* rs = (float*)alloc((size_t)2048 * 64 * 4);

  preproc_kernel<<<12800, 256, 0, stream>>>(x, Wq, Wk, Wv, Wo, xb, WqkvT, WoT, rc, rs);
  gemm256_kernel<false><<<dim3(24, 16), 512, 0, stream>>>(xb, WqkvT, QKVraw, 4096, 3072, 2048);
  postqkv_kernel<<<4352, 256, 0, stream>>>(QKVraw, kw, Kb, Vt, rc, rs);
  attn_kernel<<<512, 256, 0, stream>>>(QKVraw, Kb, Vt, AO, rc, rs, qw);
  gemm256_kernel<true><<<dim3(16, 16), 512, 0, stream>>>(AO, WoT, out, 4096, 2048, 2048);
}